// Round 5
// baseline (383.512 us; speedup 1.0000x reference)
//
#include <hip/hip_runtime.h>
#include <hip/hip_bf16.h>

#define BB 128
#define SS 128
#define EE 1024
#define NQ 8
#define DD 256
#define LL 4
#define MM (BB*SS)

typedef unsigned short bf16s;
typedef __attribute__((ext_vector_type(8))) short bf16x8;
typedef __attribute__((ext_vector_type(4))) float f32x4;

#define AS1 __attribute__((address_space(1)))
#define AS3 __attribute__((address_space(3)))

__device__ __forceinline__ unsigned short f2bf(float x) {
    unsigned u = __float_as_uint(x);
    u += 0x7fffu + ((u >> 16) & 1u);
    return (unsigned short)(u >> 16);
}

// ---------------------------------------------------------------------------
// fp32 RxC -> bf16 CxR transpose-convert (weights)
// ---------------------------------------------------------------------------
__global__ __launch_bounds__(256) void transpose_conv_kernel(
    const float* __restrict__ in, bf16s* __restrict__ out, int R, int C)
{
    __shared__ float t[32][33];
    int bx = blockIdx.x * 32, by = blockIdx.y * 32;
    int lx = threadIdx.x & 31, ly = threadIdx.x >> 5;
#pragma unroll
    for (int i = 0; i < 32; i += 8)
        t[ly + i][lx] = in[(size_t)(by + ly + i) * C + bx + lx];
    __syncthreads();
#pragma unroll
    for (int i = 0; i < 32; i += 8)
        out[(size_t)(bx + ly + i) * R + by + lx] = f2bf(t[lx][ly + i]);
}

// ---------------------------------------------------------------------------
// fp32 -> bf16 straight convert (Wv), float4 vectorized
// ---------------------------------------------------------------------------
__global__ __launch_bounds__(256) void cvt_kernel(
    const float* __restrict__ in, bf16s* __restrict__ out)
{
    int g = blockIdx.x * 256 + threadIdx.x;      // float4 index
    f32x4 x = ((const f32x4*)in)[g];
    ushort4 o;
    o.x = f2bf(x[0]); o.y = f2bf(x[1]); o.z = f2bf(x[2]); o.w = f2bf(x[3]);
    ((ushort4*)out)[g] = o;
}

// ---------------------------------------------------------------------------
// bvo[e] = sum_k bv[k]*Wo[k][e] + bo[e]   (exact bias fold through Wo)
// 16 blocks x 64 e-cols; 4 k-lanes per col, LDS reduce.
// ---------------------------------------------------------------------------
__global__ __launch_bounds__(256) void bvo_kernel(
    const float* __restrict__ bv, const float* __restrict__ Wo,
    const float* __restrict__ bo, float* __restrict__ bvo)
{
    __shared__ float part[4][64];
    int el = threadIdx.x & 63, kl = threadIdx.x >> 6;
    int e = blockIdx.x * 64 + el;
    float acc = 0.f;
    for (int k = kl; k < EE; k += 4)
        acc += bv[k] * Wo[(size_t)k * EE + e];
    part[kl][el] = acc;
    __syncthreads();
    if (kl == 0)
        bvo[e] = part[0][el] + part[1][el] + part[2][el] + part[3][el] + bo[e];
}

// ---------------------------------------------------------------------------
// Wi[1024][8] -> Wit[8][1024] fp32 (tiny; enables coalesced encode loads)
// ---------------------------------------------------------------------------
__global__ __launch_bounds__(256) void wtrans_kernel(
    const float* __restrict__ Wi, float* __restrict__ Wit)
{
    int g = blockIdx.x * 256 + threadIdx.x;   // 0..8191
    int k = g >> 3, j = g & 7;
    Wit[j * 1024 + k] = Wi[g];
}

// ---------------------------------------------------------------------------
// encode: qin = X@Wi+bi; product state v (bf16); Xb = bf16(X) side-product.
// One wave per sample row. float4-vectorized (16B/lane) global loads.
// ---------------------------------------------------------------------------
__global__ __launch_bounds__(256) void encode_kernel(
    const float* __restrict__ X, const float* __restrict__ Wit,
    const float* __restrict__ bi,
    bf16s* __restrict__ Xb, bf16s* __restrict__ v)
{
    const int lane = threadIdx.x & 63;
    const int wid  = threadIdx.x >> 6;
    const int row  = blockIdx.x * 4 + wid;

    const f32x4* xr4 = (const f32x4*)(X + (size_t)row * EE);
    ushort4* xbr4 = (ushort4*)(Xb + (size_t)row * EE);

    float acc[NQ];
#pragma unroll
    for (int j = 0; j < NQ; j++) acc[j] = 0.f;

#pragma unroll
    for (int t = 0; t < 4; t++) {
        int k4 = t * 64 + lane;          // float4 index within the row
        f32x4 x = xr4[k4];
        ushort4 xb;
        xb.x = f2bf(x[0]); xb.y = f2bf(x[1]);
        xb.z = f2bf(x[2]); xb.w = f2bf(x[3]);
        xbr4[k4] = xb;
#pragma unroll
        for (int j = 0; j < NQ; j++) {
            f32x4 w = ((const f32x4*)(Wit + j * 1024))[k4];
            acc[j] += x[0]*w[0] + x[1]*w[1] + x[2]*w[2] + x[3]*w[3];
        }
    }
    float qin[NQ];
#pragma unroll
    for (int j = 0; j < NQ; j++) {
        float s = acc[j];
#pragma unroll
        for (int off = 32; off >= 1; off >>= 1) s += __shfl_xor(s, off, 64);
        qin[j] = s + bi[j];
    }

    // product state: amp[idx] = prod_b (bit_b(idx) ? sin : cos)(qin[7-b]/2)
    float cs[NQ], sn[NQ];
#pragma unroll
    for (int q = 0; q < NQ; q++) __sincosf(0.5f * qin[q], &sn[q], &cs[q]);

    float common = 1.f;
#pragma unroll
    for (int b = 2; b < 8; b++) {
        int q = 7 - b;
        common *= ((lane >> (b - 2)) & 1) ? sn[q] : cs[q];
    }
    // cc bit0 -> qubit 7, bit1 -> qubit 6
    float a0 = common * cs[6] * cs[7];
    float a1 = common * cs[6] * sn[7];
    float a2 = common * sn[6] * cs[7];
    float a3 = common * sn[6] * sn[7];
    ushort4 vo;
    vo.x = f2bf(a0); vo.y = f2bf(a1); vo.z = f2bf(a2); vo.w = f2bf(a3);
    ((ushort4*)(v + (size_t)row * DD))[lane] = vo;
}

// ---------------------------------------------------------------------------
// ubuild: simulate the theta-circuit on all 256 basis states -> Ubt bf16.
// Ubt[n][j] (n<256: U_re[n][j]; n>=256: U_im[n-256][j]), j = basis column.
// ---------------------------------------------------------------------------
__global__ __launch_bounds__(256) void ubuild_kernel(
    const float* __restrict__ theta, bf16s* __restrict__ Ubt)
{
    const int lane = threadIdx.x & 63;
    const int wid  = threadIdx.x >> 6;
    const int col  = blockIdx.x * 4 + wid;   // 0..255

    float sr[4], si[4];
#pragma unroll
    for (int c = 0; c < 4; c++) { sr[c] = 0.f; si[c] = 0.f; }
    if (lane == (col >> 2)) sr[col & 3] = 1.f;

    auto apply_ry = [&](int b, float th) {
        float s, c;
        __sincosf(0.5f * th, &s, &c);
        if (b >= 2) {
            int lb = b - 2;
            int bit = (lane >> lb) & 1;
            float sgn = bit ? s : -s;
#pragma unroll
            for (int cc = 0; cc < 4; cc++) {
                float pr = __shfl_xor(sr[cc], 1 << lb, 64);
                float pi = __shfl_xor(si[cc], 1 << lb, 64);
                sr[cc] = c * sr[cc] + sgn * pr;
                si[cc] = c * si[cc] + sgn * pi;
            }
        } else {
            int m = 1 << b;
            float tr[4], ti[4];
#pragma unroll
            for (int cc = 0; cc < 4; cc++) { tr[cc] = sr[cc]; ti[cc] = si[cc]; }
#pragma unroll
            for (int cc = 0; cc < 4; cc++) {
                int bit = (cc >> b) & 1;
                float sgn = bit ? s : -s;
                sr[cc] = c * tr[cc] + sgn * tr[cc ^ m];
                si[cc] = c * ti[cc] + sgn * ti[cc ^ m];
            }
        }
    };
    auto apply_rz = [&](int b, float th) {
        float sz, cr;
        __sincosf(0.5f * th, &sz, &cr);
#pragma unroll
        for (int cc = 0; cc < 4; cc++) {
            int bit = (b >= 2) ? ((lane >> (b - 2)) & 1) : ((cc >> b) & 1);
            float ci = bit ? sz : -sz;
            float r = sr[cc], i = si[cc];
            sr[cc] = r * cr - i * ci;
            si[cc] = r * ci + i * cr;
        }
    };
    auto apply_cnot = [&](int bc, int bt) {
        float pr[4], pi[4];
        if (bt >= 2) {
            int m = 1 << (bt - 2);
#pragma unroll
            for (int cc = 0; cc < 4; cc++) {
                pr[cc] = __shfl_xor(sr[cc], m, 64);
                pi[cc] = __shfl_xor(si[cc], m, 64);
            }
        } else {
            int m = 1 << bt;
#pragma unroll
            for (int cc = 0; cc < 4; cc++) {
                pr[cc] = sr[cc ^ m];
                pi[cc] = si[cc ^ m];
            }
        }
#pragma unroll
        for (int cc = 0; cc < 4; cc++) {
            int ctrl = (bc >= 2) ? ((lane >> (bc - 2)) & 1) : ((cc >> bc) & 1);
            sr[cc] = ctrl ? pr[cc] : sr[cc];
            si[cc] = ctrl ? pi[cc] : si[cc];
        }
    };

#pragma unroll
    for (int l = 0; l < LL; l++) {
#pragma unroll
        for (int q = 0; q < NQ; q++) {
            apply_ry(7 - q, theta[(l * NQ + q) * 2 + 0]);
            apply_rz(7 - q, theta[(l * NQ + q) * 2 + 1]);
        }
#pragma unroll
        for (int q = 0; q < NQ; q++) {
            int t = (q + 1) & 7;
            apply_cnot(7 - q, 7 - t);
        }
    }

#pragma unroll
    for (int cc = 0; cc < 4; cc++) {
        int i = lane * 4 + cc;
        Ubt[(size_t)i * DD + col]         = f2bf(sr[cc]);
        Ubt[(size_t)(i + DD) * DD + col]  = f2bf(si[cc]);
    }
}

// ---------------------------------------------------------------------------
// psi_gemm: C[s][n] = v[s][:] . Ubt[n][:]  (M=16384, N=512, K=256)
// 2-phase double-buffered pipeline. Epilogue writes P1/P2.
// ---------------------------------------------------------------------------
__global__ __launch_bounds__(256) void psi_gemm_kernel(
    const bf16s* __restrict__ A, const bf16s* __restrict__ Bt,
    bf16s* __restrict__ P1, bf16s* __restrict__ P2)
{
    __shared__ bf16s As[2][128 * 32];
    __shared__ bf16s Bs[2][128 * 32];

    const int tid  = threadIdx.x;
    const int wave = tid >> 6, lane = tid & 63;
    const int quad = lane >> 4, lr = lane & 15;
    const int wm = (wave >> 1) * 64, wn = (wave & 1) * 64;
    const int m0 = blockIdx.x * 128, n0 = blockIdx.y * 128;
    const int K = DD, N = 2 * DD;

    f32x4 acc[4][4];
#pragma unroll
    for (int i = 0; i < 4; i++)
#pragma unroll
        for (int j = 0; j < 4; j++) acc[i][j] = (f32x4){0.f, 0.f, 0.f, 0.f};

    auto stage = [&](int buf, int kt) {
#pragma unroll
        for (int j = 0; j < 2; j++) {
            int ch = j * 256 + tid;
            int row = ch >> 2, kc = (ch & 3) * 8;
            __builtin_amdgcn_global_load_lds(
                (AS1 const void*)(A + (size_t)(m0 + row) * K + kt + kc),
                (AS3 void*)(As[buf] + (size_t)(j * 256 + wave * 64) * 8), 16, 0, 0);
            __builtin_amdgcn_global_load_lds(
                (AS1 const void*)(Bt + (size_t)(n0 + row) * K + kt + kc),
                (AS3 void*)(Bs[buf] + (size_t)(j * 256 + wave * 64) * 8), 16, 0, 0);
        }
    };
    auto compute = [&](int buf) {
        bf16x8 af[4], bfr[4];
#pragma unroll
        for (int i = 0; i < 4; i++)
            af[i] = *(const bf16x8*)(As[buf] + (wm + i * 16 + lr) * 32 + quad * 8);
#pragma unroll
        for (int j = 0; j < 4; j++)
            bfr[j] = *(const bf16x8*)(Bs[buf] + (wn + j * 16 + lr) * 32 + quad * 8);
#pragma unroll
        for (int i = 0; i < 4; i++)
#pragma unroll
            for (int j = 0; j < 4; j++)
                acc[i][j] = __builtin_amdgcn_mfma_f32_16x16x32_bf16(
                    af[i], bfr[j], acc[i][j], 0, 0, 0);
    };

    const int nt = K >> 5;   // 8 (even)
    stage(0, 0);
    __syncthreads();
    for (int t = 0; t < nt - 2; t += 2) {
        stage(1, (t + 1) << 5);
        compute(0);
        __syncthreads();
        stage(0, (t + 2) << 5);
        compute(1);
        __syncthreads();
    }
    stage(1, (nt - 1) << 5);
    compute(0);
    __syncthreads();
    compute(1);

#pragma unroll
    for (int i = 0; i < 4; i++) {
        int row0 = m0 + wm + i * 16 + quad * 4;
#pragma unroll
        for (int j = 0; j < 4; j++) {
            int col = n0 + wn + j * 16 + lr;
            int c2  = (col < DD) ? (col + DD) : (col - DD);
            float sgn = (col < DD) ? -1.f : 1.f;
#pragma unroll
            for (int r = 0; r < 4; r++) {
                float val = acc[i][j][r];
                P1[(size_t)(row0 + r) * N + col] = f2bf(val);
                P2[(size_t)(row0 + r) * N + c2] = f2bf(sgn * val);
            }
        }
    }
}

// ---------------------------------------------------------------------------
// MFMA bf16 GEMM: C[M][N] = A[M][K] @ Bt[N][K]^T (+bias[col]).
// 2-phase double-buffered pipeline. 1D grid with bijective XCD chunking.
// Work order: w = (z * nm + m) * nn + n.
// ---------------------------------------------------------------------------
template<bool OUT_BF16>
__global__ __launch_bounds__(256) void mfma_gemm(
    const bf16s* __restrict__ A, const bf16s* __restrict__ Bt,
    const float* __restrict__ bias, void* __restrict__ Cv,
    int M, int N, int K, int nm, int nn,
    long long sA, long long sB, long long sC)
{
    __shared__ bf16s As[2][128 * 32];
    __shared__ bf16s Bs[2][128 * 32];

    const int tid  = threadIdx.x;
    const int wave = tid >> 6, lane = tid & 63;
    const int quad = lane >> 4, lr = lane & 15;
    const int wm = (wave >> 1) * 64, wn = (wave & 1) * 64;

    // bijective XCD chunk swizzle (m204): xcd k -> work chunk k
    const int nwg = gridDim.x;
    const int q = nwg >> 3, r = nwg & 7;
    const int xcd = blockIdx.x & 7, idx = blockIdx.x >> 3;
    const int w = (xcd < r ? xcd * (q + 1) : r * (q + 1) + (xcd - r) * q) + idx;
    const int n_t = w % nn;
    const int m_t = (w / nn) % nm;
    const int z   = w / (nn * nm);
    const int m0 = m_t * 128, n0 = n_t * 128;

    A  += (size_t)z * sA;
    Bt += (size_t)z * sB;

    f32x4 acc[4][4];
#pragma unroll
    for (int i = 0; i < 4; i++)
#pragma unroll
        for (int j = 0; j < 4; j++) acc[i][j] = (f32x4){0.f, 0.f, 0.f, 0.f};

    auto stage = [&](int buf, int kt) {
#pragma unroll
        for (int j = 0; j < 2; j++) {
            int ch = j * 256 + tid;
            int row = ch >> 2, kc = (ch & 3) * 8;
            __builtin_amdgcn_global_load_lds(
                (AS1 const void*)(A + (size_t)(m0 + row) * K + kt + kc),
                (AS3 void*)(As[buf] + (size_t)(j * 256 + wave * 64) * 8), 16, 0, 0);
            __builtin_amdgcn_global_load_lds(
                (AS1 const void*)(Bt + (size_t)(n0 + row) * K + kt + kc),
                (AS3 void*)(Bs[buf] + (size_t)(j * 256 + wave * 64) * 8), 16, 0, 0);
        }
    };
    auto compute = [&](int buf) {
        bf16x8 af[4], bfr[4];
#pragma unroll
        for (int i = 0; i < 4; i++)
            af[i] = *(const bf16x8*)(As[buf] + (wm + i * 16 + lr) * 32 + quad * 8);
#pragma unroll
        for (int j = 0; j < 4; j++)
            bfr[j] = *(const bf16x8*)(Bs[buf] + (wn + j * 16 + lr) * 32 + quad * 8);
#pragma unroll
        for (int i = 0; i < 4; i++)
#pragma unroll
            for (int j = 0; j < 4; j++)
                acc[i][j] = __builtin_amdgcn_mfma_f32_16x16x32_bf16(
                    af[i], bfr[j], acc[i][j], 0, 0, 0);
    };

    const int nt = K >> 5;   // all call sites: even, >= 4
    stage(0, 0);
    __syncthreads();
    for (int t = 0; t < nt - 2; t += 2) {
        stage(1, (t + 1) << 5);
        compute(0);
        __syncthreads();
        stage(0, (t + 2) << 5);
        compute(1);
        __syncthreads();
    }
    stage(1, (nt - 1) << 5);
    compute(0);
    __syncthreads();
    compute(1);

    float* Cf = (float*)Cv + (size_t)z * sC;
    bf16s* Cb = (bf16s*)Cv + (size_t)z * sC;
#pragma unroll
    for (int i = 0; i < 4; i++) {
        int row0 = m0 + wm + i * 16 + quad * 4;
#pragma unroll
        for (int j = 0; j < 4; j++) {
            int col = n0 + wn + j * 16 + lr;
            float bb = bias ? bias[col] : 0.f;
#pragma unroll
            for (int r = 0; r < 4; r++) {
                float v = acc[i][j][r] + bb;
                if (OUT_BF16) Cb[(size_t)(row0 + r) * N + col] = f2bf(v);
                else          Cf[(size_t)(row0 + r) * N + col] = v;
            }
        }
    }
}

// ---------------------------------------------------------------------------
// attn: MFMA Gram + fused softmax. 2-phase double-buffered pipeline.
// ---------------------------------------------------------------------------
__global__ __launch_bounds__(256) void attn_kernel(
    const bf16s* __restrict__ P1, const bf16s* __restrict__ P2,
    const float* __restrict__ phi,
    float* __restrict__ attn, bf16s* __restrict__ attn_bf)
{
    __shared__ bf16s As [2][64 * 32];
    __shared__ bf16s Bs1[2][128 * 32];
    __shared__ bf16s Bs2[2][128 * 32];

    const int tid  = threadIdx.x;
    const int wave = tid >> 6, lane = tid & 63;
    const int quad = lane >> 4, lr = lane & 15;
    const int b = blockIdx.y;
    const int s0 = blockIdx.x * 64;
    const bf16s* p1b = P1 + (size_t)b * 128 * 512;
    const bf16s* p2b = P2 + (size_t)b * 128 * 512;

    f32x4 accre[8], accim[8];
#pragma unroll
    for (int j = 0; j < 8; j++) {
        accre[j] = (f32x4){0.f, 0.f, 0.f, 0.f};
        accim[j] = (f32x4){0.f, 0.f, 0.f, 0.f};
    }

    auto stage = [&](int buf, int kt) {
        {
            int row = tid >> 2, kc = (tid & 3) * 8;
            __builtin_amdgcn_global_load_lds(
                (AS1 const void*)(p1b + (size_t)(s0 + row) * 512 + kt + kc),
                (AS3 void*)(As[buf] + (size_t)(wave * 64) * 8), 16, 0, 0);
        }
#pragma unroll
        for (int j = 0; j < 2; j++) {
            int ch = j * 256 + tid;
            int row = ch >> 2, kc = (ch & 3) * 8;
            __builtin_amdgcn_global_load_lds(
                (AS1 const void*)(p1b + (size_t)row * 512 + kt + kc),
                (AS3 void*)(Bs1[buf] + (size_t)(j * 256 + wave * 64) * 8), 16, 0, 0);
            __builtin_amdgcn_global_load_lds(
                (AS1 const void*)(p2b + (size_t)row * 512 + kt + kc),
                (AS3 void*)(Bs2[buf] + (size_t)(j * 256 + wave * 64) * 8), 16, 0, 0);
        }
    };
    auto compute = [&](int buf) {
        bf16x8 afr = *(const bf16x8*)(As[buf] + (wave * 16 + lr) * 32 + quad * 8);
#pragma unroll
        for (int j = 0; j < 8; j++) {
            bf16x8 b1 = *(const bf16x8*)(Bs1[buf] + (j * 16 + lr) * 32 + quad * 8);
            accre[j] = __builtin_amdgcn_mfma_f32_16x16x32_bf16(afr, b1, accre[j], 0, 0, 0);
            bf16x8 b2 = *(const bf16x8*)(Bs2[buf] + (j * 16 + lr) * 32 + quad * 8);
            accim[j] = __builtin_amdgcn_mfma_f32_16x16x32_bf16(afr, b2, accim[j], 0, 0, 0);
        }
    };

    const int nt = 16;   // K=512
    stage(0, 0);
    __syncthreads();
    for (int t = 0; t < nt - 2; t += 2) {
        stage(1, (t + 1) << 5);
        compute(0);
        __syncthreads();
        stage(0, (t + 2) << 5);
        compute(1);
        __syncthreads();
    }
    stage(1, (nt - 1) << 5);
    compute(0);
    __syncthreads();
    compute(1);

    const float isq = 0.35355339059327373f;
    float ph_r[4], ph_c[8];
#pragma unroll
    for (int r = 0; r < 4; r++) ph_r[r] = phi[s0 + wave * 16 + quad * 4 + r];
#pragma unroll
    for (int j = 0; j < 8; j++) ph_c[j] = phi[j * 16 + lr];

#pragma unroll
    for (int r = 0; r < 4; r++) {
        float v[8];
        float mx = -1e30f;
#pragma unroll
        for (int j = 0; j < 8; j++) {
            float re = accre[j][r], im = accim[j][r];
            v[j] = (re * re + im * im) * isq + __cosf(ph_c[j] - ph_r[r]);
            mx = fmaxf(mx, v[j]);
        }
#pragma unroll
        for (int off = 1; off <= 8; off <<= 1) mx = fmaxf(mx, __shfl_xor(mx, off, 64));
        float sm = 0.f;
#pragma unroll
        for (int j = 0; j < 8; j++) { v[j] = __expf(v[j] - mx); sm += v[j]; }
#pragma unroll
        for (int off = 1; off <= 8; off <<= 1) sm += __shfl_xor(sm, off, 64);
        float inv = 1.f / sm;
        int srow = b * 128 + s0 + wave * 16 + quad * 4 + r;
#pragma unroll
        for (int j = 0; j < 8; j++) {
            float o = v[j] * inv;
            attn[(size_t)srow * 128 + j * 16 + lr] = o;
            attn_bf[(size_t)srow * 128 + j * 16 + lr] = f2bf(o);
        }
    }
}

// ---------------------------------------------------------------------------
extern "C" void kernel_launch(void* const* d_in, const int* in_sizes, int n_in,
                              void* d_out, int out_size, void* d_ws, size_t ws_size,
                              hipStream_t stream) {
    const float* X     = (const float*)d_in[0];
    const float* Wi    = (const float*)d_in[1];
    const float* bi    = (const float*)d_in[2];
    const float* Wv    = (const float*)d_in[3];
    const float* bv    = (const float*)d_in[4];
    const float* Wo    = (const float*)d_in[5];
    const float* bo    = (const float*)d_in[6];
    const float* theta = (const float*)d_in[7];
    const float* phi   = (const float*)d_in[8];

    float* y    = (float*)d_out;
    float* attn = y + (size_t)MM * EE;

    bf16s* Xb   = (bf16s*)d_ws;                      // 16384*1024
    bf16s* P1   = Xb  + (size_t)MM * EE;             // 16384*512
    bf16s* P2   = P1  + (size_t)MM * 512;            // 16384*512
    bf16s* Vwtb = P2  + (size_t)MM * 512;            // 128 * 1024*128 (V@Wo)^T
    bf16s* scr  = Vwtb + (size_t)MM * EE;            // scratch region (old o2b)
    bf16s* abf  = scr + (size_t)MM * EE;             // 128*128*128
    bf16s* Wvb  = abf + (size_t)BB * SS * SS;        // 1024*1024 bf16(Wv)
    bf16s* Wot  = Wvb + (size_t)EE * EE;             // 1024*1024 Wo^T
    float* Wit  = (float*)(Wot + (size_t)EE * EE);   // 8*1024 fp32 (32 KB)
    float* bvo  = Wit + 8 * 1024;                    // 1024 fp32
    // scratch layout: v | Ubt | Wvot  (disjoint offsets, all fit in MM*EE)
    bf16s* v    = scr;                               // 16384*256
    bf16s* Ubt  = scr + (size_t)MM * DD;             // 512*256
    bf16s* Wvot = scr + (size_t)MM * DD + 512 * DD;  // 1024*1024 (Wv@Wo)^T

    // Wi transpose (coalesced encode loads)
    wtrans_kernel<<<32, 256, 0, stream>>>(Wi, Wit);
    // encode: qin -> product state v (bf16) + Xb side-product
    encode_kernel<<<MM / 4, 256, 0, stream>>>(X, Wit, bi, Xb, v);
    // build circuit unitary (theta only)
    ubuild_kernel<<<64, 256, 0, stream>>>(theta, Ubt);
    // weight prep: Wot = Wo^T (bf16), Wvb = bf16(Wv), bvo = bv@Wo + bo
    transpose_conv_kernel<<<dim3(32, 32), 256, 0, stream>>>(Wo, Wot, EE, EE);
    cvt_kernel<<<1024, 256, 0, stream>>>(Wv, Wvb);
    bvo_kernel<<<16, 256, 0, stream>>>(bv, Wo, bo, bvo);
    // Wvot[a][b] = (Wv@Wo)[b][a] :  A=Wot, Bt=Wvb  (M=N=K=1024)
    mfma_gemm<true><<<64, 256, 0, stream>>>(
        Wot, Wvb, nullptr, Wvot, EE, EE, EE, /*nm*/8, /*nn*/8, 0, 0, 0);
    // psi = v @ Ubt^T -> P1, P2
    psi_gemm_kernel<<<dim3(MM / 128, 4), 256, 0, stream>>>(v, Ubt, P1, P2);
    // Vwt_b = Wvot @ Xb_b^T   (batched; w = z*8 + m; Wvot L2-resident per XCD)
    mfma_gemm<true><<<1024, 256, 0, stream>>>(
        Wvot, Xb, nullptr, Vwtb, EE, SS, EE, /*nm*/8, /*nn*/1,
        0, (long long)SS * EE, (long long)EE * SS);
    // attn (Gram via MFMA + softmax)
    attn_kernel<<<dim3(2, BB), 256, 0, stream>>>(P1, P2, phi, attn, abf);
    // y_b = attn_b @ Vw_b + bvo   (fp32 out; w = z*8 + n)
    mfma_gemm<false><<<1024, 256, 0, stream>>>(
        abf, Vwtb, bvo, y, SS, EE, SS, /*nm*/1, /*nn*/8,
        (long long)SS * SS, (long long)EE * SS, (long long)SS * EE);
}

// Round 6
// 311.030 us; speedup vs baseline: 1.2330x; 1.2330x over previous
//
#include <hip/hip_runtime.h>
#include <hip/hip_bf16.h>

#define BB 128
#define SS 128
#define EE 1024
#define NQ 8
#define DD 256
#define LL 4
#define MM (BB*SS)

typedef unsigned short bf16s;
typedef __attribute__((ext_vector_type(8))) short bf16x8;
typedef __attribute__((ext_vector_type(4))) float f32x4;

#define AS1 __attribute__((address_space(1)))
#define AS3 __attribute__((address_space(3)))

__device__ __forceinline__ unsigned short f2bf(float x) {
    unsigned u = __float_as_uint(x);
    u += 0x7fffu + ((u >> 16) & 1u);
    return (unsigned short)(u >> 16);
}

// ---------------------------------------------------------------------------
// fp32 RxC -> bf16 CxR transpose-convert (weights)
// ---------------------------------------------------------------------------
__global__ __launch_bounds__(256) void transpose_conv_kernel(
    const float* __restrict__ in, bf16s* __restrict__ out, int R, int C)
{
    __shared__ float t[32][33];
    int bx = blockIdx.x * 32, by = blockIdx.y * 32;
    int lx = threadIdx.x & 31, ly = threadIdx.x >> 5;
#pragma unroll
    for (int i = 0; i < 32; i += 8)
        t[ly + i][lx] = in[(size_t)(by + ly + i) * C + bx + lx];
    __syncthreads();
#pragma unroll
    for (int i = 0; i < 32; i += 8)
        out[(size_t)(bx + ly + i) * R + by + lx] = f2bf(t[lx][ly + i]);
}

// ---------------------------------------------------------------------------
// fp32 -> bf16 straight convert (Wv), float4 vectorized
// ---------------------------------------------------------------------------
__global__ __launch_bounds__(256) void cvt_kernel(
    const float* __restrict__ in, bf16s* __restrict__ out)
{
    int g = blockIdx.x * 256 + threadIdx.x;      // float4 index
    f32x4 x = ((const f32x4*)in)[g];
    ushort4 o;
    o.x = f2bf(x[0]); o.y = f2bf(x[1]); o.z = f2bf(x[2]); o.w = f2bf(x[3]);
    ((ushort4*)out)[g] = o;
}

// ---------------------------------------------------------------------------
// bvo = bv@Wo + bo, two parallel stages.
// Stage 1: 256 blocks (kb,eb); block reduces 64 k-rows x 64 e-cols (coalesced).
// ---------------------------------------------------------------------------
__global__ __launch_bounds__(256) void bvo_part_kernel(
    const float* __restrict__ bv, const float* __restrict__ Wo,
    float* __restrict__ part)
{
    __shared__ float red[4][64];
    int lane = threadIdx.x & 63, w = threadIdx.x >> 6;
    int eb = blockIdx.x & 15, kb = blockIdx.x >> 4;
    int e = eb * 64 + lane;
    int k0 = kb * 64 + w * 16;
    float acc = 0.f;
#pragma unroll
    for (int i = 0; i < 16; i++)
        acc += bv[k0 + i] * Wo[(size_t)(k0 + i) * EE + e];
    red[w][lane] = acc;
    __syncthreads();
    if (w == 0)
        part[kb * EE + e] = red[0][lane] + red[1][lane] + red[2][lane] + red[3][lane];
}

__global__ __launch_bounds__(256) void bvo_reduce_kernel(
    const float* __restrict__ part, const float* __restrict__ bo,
    float* __restrict__ bvo)
{
    int e = blockIdx.x * 256 + threadIdx.x;
    float s = bo[e];
#pragma unroll
    for (int kb = 0; kb < 16; kb++) s += part[kb * EE + e];
    bvo[e] = s;
}

// ---------------------------------------------------------------------------
// Wi[1024][8] -> Wit[8][1024] fp32 (tiny; enables coalesced encode loads)
// ---------------------------------------------------------------------------
__global__ __launch_bounds__(256) void wtrans_kernel(
    const float* __restrict__ Wi, float* __restrict__ Wit)
{
    int g = blockIdx.x * 256 + threadIdx.x;   // 0..8191
    int k = g >> 3, j = g & 7;
    Wit[j * 1024 + k] = Wi[g];
}

// ---------------------------------------------------------------------------
// encode: qin = X@Wi+bi; product state v (bf16); Xb = bf16(X) side-product.
// One wave per sample row. float4-vectorized (16B/lane) global loads.
// ---------------------------------------------------------------------------
__global__ __launch_bounds__(256) void encode_kernel(
    const float* __restrict__ X, const float* __restrict__ Wit,
    const float* __restrict__ bi,
    bf16s* __restrict__ Xb, bf16s* __restrict__ v)
{
    const int lane = threadIdx.x & 63;
    const int wid  = threadIdx.x >> 6;
    const int row  = blockIdx.x * 4 + wid;

    const f32x4* xr4 = (const f32x4*)(X + (size_t)row * EE);
    ushort4* xbr4 = (ushort4*)(Xb + (size_t)row * EE);

    float acc[NQ];
#pragma unroll
    for (int j = 0; j < NQ; j++) acc[j] = 0.f;

#pragma unroll
    for (int t = 0; t < 4; t++) {
        int k4 = t * 64 + lane;          // float4 index within the row
        f32x4 x = xr4[k4];
        ushort4 xb;
        xb.x = f2bf(x[0]); xb.y = f2bf(x[1]);
        xb.z = f2bf(x[2]); xb.w = f2bf(x[3]);
        xbr4[k4] = xb;
#pragma unroll
        for (int j = 0; j < NQ; j++) {
            f32x4 w = ((const f32x4*)(Wit + j * 1024))[k4];
            acc[j] += x[0]*w[0] + x[1]*w[1] + x[2]*w[2] + x[3]*w[3];
        }
    }
    float qin[NQ];
#pragma unroll
    for (int j = 0; j < NQ; j++) {
        float s = acc[j];
#pragma unroll
        for (int off = 32; off >= 1; off >>= 1) s += __shfl_xor(s, off, 64);
        qin[j] = s + bi[j];
    }

    // product state: amp[idx] = prod_b (bit_b(idx) ? sin : cos)(qin[7-b]/2)
    float cs[NQ], sn[NQ];
#pragma unroll
    for (int q = 0; q < NQ; q++) __sincosf(0.5f * qin[q], &sn[q], &cs[q]);

    float common = 1.f;
#pragma unroll
    for (int b = 2; b < 8; b++) {
        int q = 7 - b;
        common *= ((lane >> (b - 2)) & 1) ? sn[q] : cs[q];
    }
    // cc bit0 -> qubit 7, bit1 -> qubit 6
    float a0 = common * cs[6] * cs[7];
    float a1 = common * cs[6] * sn[7];
    float a2 = common * sn[6] * cs[7];
    float a3 = common * sn[6] * sn[7];
    ushort4 vo;
    vo.x = f2bf(a0); vo.y = f2bf(a1); vo.z = f2bf(a2); vo.w = f2bf(a3);
    ((ushort4*)(v + (size_t)row * DD))[lane] = vo;
}

// ---------------------------------------------------------------------------
// ubuild: simulate the theta-circuit on all 256 basis states -> Ubt bf16.
// Ubt[n][j] (n<256: U_re[n][j]; n>=256: U_im[n-256][j]), j = basis column.
// ---------------------------------------------------------------------------
__global__ __launch_bounds__(256) void ubuild_kernel(
    const float* __restrict__ theta, bf16s* __restrict__ Ubt)
{
    const int lane = threadIdx.x & 63;
    const int wid  = threadIdx.x >> 6;
    const int col  = blockIdx.x * 4 + wid;   // 0..255

    float sr[4], si[4];
#pragma unroll
    for (int c = 0; c < 4; c++) { sr[c] = 0.f; si[c] = 0.f; }
    if (lane == (col >> 2)) sr[col & 3] = 1.f;

    auto apply_ry = [&](int b, float th) {
        float s, c;
        __sincosf(0.5f * th, &s, &c);
        if (b >= 2) {
            int lb = b - 2;
            int bit = (lane >> lb) & 1;
            float sgn = bit ? s : -s;
#pragma unroll
            for (int cc = 0; cc < 4; cc++) {
                float pr = __shfl_xor(sr[cc], 1 << lb, 64);
                float pi = __shfl_xor(si[cc], 1 << lb, 64);
                sr[cc] = c * sr[cc] + sgn * pr;
                si[cc] = c * si[cc] + sgn * pi;
            }
        } else {
            int m = 1 << b;
            float tr[4], ti[4];
#pragma unroll
            for (int cc = 0; cc < 4; cc++) { tr[cc] = sr[cc]; ti[cc] = si[cc]; }
#pragma unroll
            for (int cc = 0; cc < 4; cc++) {
                int bit = (cc >> b) & 1;
                float sgn = bit ? s : -s;
                sr[cc] = c * tr[cc] + sgn * tr[cc ^ m];
                si[cc] = c * ti[cc] + sgn * ti[cc ^ m];
            }
        }
    };
    auto apply_rz = [&](int b, float th) {
        float sz, cr;
        __sincosf(0.5f * th, &sz, &cr);
#pragma unroll
        for (int cc = 0; cc < 4; cc++) {
            int bit = (b >= 2) ? ((lane >> (b - 2)) & 1) : ((cc >> b) & 1);
            float ci = bit ? sz : -sz;
            float r = sr[cc], i = si[cc];
            sr[cc] = r * cr - i * ci;
            si[cc] = r * ci + i * cr;
        }
    };
    auto apply_cnot = [&](int bc, int bt) {
        float pr[4], pi[4];
        if (bt >= 2) {
            int m = 1 << (bt - 2);
#pragma unroll
            for (int cc = 0; cc < 4; cc++) {
                pr[cc] = __shfl_xor(sr[cc], m, 64);
                pi[cc] = __shfl_xor(si[cc], m, 64);
            }
        } else {
            int m = 1 << bt;
#pragma unroll
            for (int cc = 0; cc < 4; cc++) {
                pr[cc] = sr[cc ^ m];
                pi[cc] = si[cc ^ m];
            }
        }
#pragma unroll
        for (int cc = 0; cc < 4; cc++) {
            int ctrl = (bc >= 2) ? ((lane >> (bc - 2)) & 1) : ((cc >> bc) & 1);
            sr[cc] = ctrl ? pr[cc] : sr[cc];
            si[cc] = ctrl ? pi[cc] : si[cc];
        }
    };

#pragma unroll
    for (int l = 0; l < LL; l++) {
#pragma unroll
        for (int q = 0; q < NQ; q++) {
            apply_ry(7 - q, theta[(l * NQ + q) * 2 + 0]);
            apply_rz(7 - q, theta[(l * NQ + q) * 2 + 1]);
        }
#pragma unroll
        for (int q = 0; q < NQ; q++) {
            int t = (q + 1) & 7;
            apply_cnot(7 - q, 7 - t);
        }
    }

#pragma unroll
    for (int cc = 0; cc < 4; cc++) {
        int i = lane * 4 + cc;
        Ubt[(size_t)i * DD + col]         = f2bf(sr[cc]);
        Ubt[(size_t)(i + DD) * DD + col]  = f2bf(si[cc]);
    }
}

// ---------------------------------------------------------------------------
// psi_gemm: C[s][n] = v[s][:] . Ubt[n][:]  (M=16384, N=512, K=256)
// 2-phase double-buffered pipeline. Epilogue writes P1/P2.
// ---------------------------------------------------------------------------
__global__ __launch_bounds__(256) void psi_gemm_kernel(
    const bf16s* __restrict__ A, const bf16s* __restrict__ Bt,
    bf16s* __restrict__ P1, bf16s* __restrict__ P2)
{
    __shared__ bf16s As[2][128 * 32];
    __shared__ bf16s Bs[2][128 * 32];

    const int tid  = threadIdx.x;
    const int wave = tid >> 6, lane = tid & 63;
    const int quad = lane >> 4, lr = lane & 15;
    const int wm = (wave >> 1) * 64, wn = (wave & 1) * 64;
    const int m0 = blockIdx.x * 128, n0 = blockIdx.y * 128;
    const int K = DD, N = 2 * DD;

    f32x4 acc[4][4];
#pragma unroll
    for (int i = 0; i < 4; i++)
#pragma unroll
        for (int j = 0; j < 4; j++) acc[i][j] = (f32x4){0.f, 0.f, 0.f, 0.f};

    auto stage = [&](int buf, int kt) {
#pragma unroll
        for (int j = 0; j < 2; j++) {
            int ch = j * 256 + tid;
            int row = ch >> 2, kc = (ch & 3) * 8;
            __builtin_amdgcn_global_load_lds(
                (AS1 const void*)(A + (size_t)(m0 + row) * K + kt + kc),
                (AS3 void*)(As[buf] + (size_t)(j * 256 + wave * 64) * 8), 16, 0, 0);
            __builtin_amdgcn_global_load_lds(
                (AS1 const void*)(Bt + (size_t)(n0 + row) * K + kt + kc),
                (AS3 void*)(Bs[buf] + (size_t)(j * 256 + wave * 64) * 8), 16, 0, 0);
        }
    };
    auto compute = [&](int buf) {
        bf16x8 af[4], bfr[4];
#pragma unroll
        for (int i = 0; i < 4; i++)
            af[i] = *(const bf16x8*)(As[buf] + (wm + i * 16 + lr) * 32 + quad * 8);
#pragma unroll
        for (int j = 0; j < 4; j++)
            bfr[j] = *(const bf16x8*)(Bs[buf] + (wn + j * 16 + lr) * 32 + quad * 8);
#pragma unroll
        for (int i = 0; i < 4; i++)
#pragma unroll
            for (int j = 0; j < 4; j++)
                acc[i][j] = __builtin_amdgcn_mfma_f32_16x16x32_bf16(
                    af[i], bfr[j], acc[i][j], 0, 0, 0);
    };

    const int nt = K >> 5;   // 8 (even)
    stage(0, 0);
    __syncthreads();
    for (int t = 0; t < nt - 2; t += 2) {
        stage(1, (t + 1) << 5);
        compute(0);
        __syncthreads();
        stage(0, (t + 2) << 5);
        compute(1);
        __syncthreads();
    }
    stage(1, (nt - 1) << 5);
    compute(0);
    __syncthreads();
    compute(1);

#pragma unroll
    for (int i = 0; i < 4; i++) {
        int row0 = m0 + wm + i * 16 + quad * 4;
#pragma unroll
        for (int j = 0; j < 4; j++) {
            int col = n0 + wn + j * 16 + lr;
            int c2  = (col < DD) ? (col + DD) : (col - DD);
            float sgn = (col < DD) ? -1.f : 1.f;
#pragma unroll
            for (int r = 0; r < 4; r++) {
                float val = acc[i][j][r];
                P1[(size_t)(row0 + r) * N + col] = f2bf(val);
                P2[(size_t)(row0 + r) * N + c2] = f2bf(sgn * val);
            }
        }
    }
}

// ---------------------------------------------------------------------------
// MFMA bf16 GEMM: C[M][N] = A[M][K] @ Bt[N][K]^T (+bias[col]).
// 2-phase double-buffered pipeline. 1D grid with bijective XCD chunking.
// Work order: w = (z * nm + m) * nn + n.
// ---------------------------------------------------------------------------
template<bool OUT_BF16>
__global__ __launch_bounds__(256) void mfma_gemm(
    const bf16s* __restrict__ A, const bf16s* __restrict__ Bt,
    const float* __restrict__ bias, void* __restrict__ Cv,
    int M, int N, int K, int nm, int nn,
    long long sA, long long sB, long long sC)
{
    __shared__ bf16s As[2][128 * 32];
    __shared__ bf16s Bs[2][128 * 32];

    const int tid  = threadIdx.x;
    const int wave = tid >> 6, lane = tid & 63;
    const int quad = lane >> 4, lr = lane & 15;
    const int wm = (wave >> 1) * 64, wn = (wave & 1) * 64;

    // bijective XCD chunk swizzle (m204): xcd k -> work chunk k
    const int nwg = gridDim.x;
    const int q = nwg >> 3, r = nwg & 7;
    const int xcd = blockIdx.x & 7, idx = blockIdx.x >> 3;
    const int w = (xcd < r ? xcd * (q + 1) : r * (q + 1) + (xcd - r) * q) + idx;
    const int n_t = w % nn;
    const int m_t = (w / nn) % nm;
    const int z   = w / (nn * nm);
    const int m0 = m_t * 128, n0 = n_t * 128;

    A  += (size_t)z * sA;
    Bt += (size_t)z * sB;

    f32x4 acc[4][4];
#pragma unroll
    for (int i = 0; i < 4; i++)
#pragma unroll
        for (int j = 0; j < 4; j++) acc[i][j] = (f32x4){0.f, 0.f, 0.f, 0.f};

    auto stage = [&](int buf, int kt) {
#pragma unroll
        for (int j = 0; j < 2; j++) {
            int ch = j * 256 + tid;
            int row = ch >> 2, kc = (ch & 3) * 8;
            __builtin_amdgcn_global_load_lds(
                (AS1 const void*)(A + (size_t)(m0 + row) * K + kt + kc),
                (AS3 void*)(As[buf] + (size_t)(j * 256 + wave * 64) * 8), 16, 0, 0);
            __builtin_amdgcn_global_load_lds(
                (AS1 const void*)(Bt + (size_t)(n0 + row) * K + kt + kc),
                (AS3 void*)(Bs[buf] + (size_t)(j * 256 + wave * 64) * 8), 16, 0, 0);
        }
    };
    auto compute = [&](int buf) {
        bf16x8 af[4], bfr[4];
#pragma unroll
        for (int i = 0; i < 4; i++)
            af[i] = *(const bf16x8*)(As[buf] + (wm + i * 16 + lr) * 32 + quad * 8);
#pragma unroll
        for (int j = 0; j < 4; j++)
            bfr[j] = *(const bf16x8*)(Bs[buf] + (wn + j * 16 + lr) * 32 + quad * 8);
#pragma unroll
        for (int i = 0; i < 4; i++)
#pragma unroll
            for (int j = 0; j < 4; j++)
                acc[i][j] = __builtin_amdgcn_mfma_f32_16x16x32_bf16(
                    af[i], bfr[j], acc[i][j], 0, 0, 0);
    };

    const int nt = K >> 5;   // all call sites: even, >= 4
    stage(0, 0);
    __syncthreads();
    for (int t = 0; t < nt - 2; t += 2) {
        stage(1, (t + 1) << 5);
        compute(0);
        __syncthreads();
        stage(0, (t + 2) << 5);
        compute(1);
        __syncthreads();
    }
    stage(1, (nt - 1) << 5);
    compute(0);
    __syncthreads();
    compute(1);

    float* Cf = (float*)Cv + (size_t)z * sC;
    bf16s* Cb = (bf16s*)Cv + (size_t)z * sC;
#pragma unroll
    for (int i = 0; i < 4; i++) {
        int row0 = m0 + wm + i * 16 + quad * 4;
#pragma unroll
        for (int j = 0; j < 4; j++) {
            int col = n0 + wn + j * 16 + lr;
            float bb = bias ? bias[col] : 0.f;
#pragma unroll
            for (int r = 0; r < 4; r++) {
                float v = acc[i][j][r] + bb;
                if (OUT_BF16) Cb[(size_t)(row0 + r) * N + col] = f2bf(v);
                else          Cf[(size_t)(row0 + r) * N + col] = v;
            }
        }
    }
}

// ---------------------------------------------------------------------------
// attn: MFMA Gram + fused softmax. 2-phase double-buffered pipeline.
// ---------------------------------------------------------------------------
__global__ __launch_bounds__(256) void attn_kernel(
    const bf16s* __restrict__ P1, const bf16s* __restrict__ P2,
    const float* __restrict__ phi,
    float* __restrict__ attn, bf16s* __restrict__ attn_bf)
{
    __shared__ bf16s As [2][64 * 32];
    __shared__ bf16s Bs1[2][128 * 32];
    __shared__ bf16s Bs2[2][128 * 32];

    const int tid  = threadIdx.x;
    const int wave = tid >> 6, lane = tid & 63;
    const int quad = lane >> 4, lr = lane & 15;
    const int b = blockIdx.y;
    const int s0 = blockIdx.x * 64;
    const bf16s* p1b = P1 + (size_t)b * 128 * 512;
    const bf16s* p2b = P2 + (size_t)b * 128 * 512;

    f32x4 accre[8], accim[8];
#pragma unroll
    for (int j = 0; j < 8; j++) {
        accre[j] = (f32x4){0.f, 0.f, 0.f, 0.f};
        accim[j] = (f32x4){0.f, 0.f, 0.f, 0.f};
    }

    auto stage = [&](int buf, int kt) {
        {
            int row = tid >> 2, kc = (tid & 3) * 8;
            __builtin_amdgcn_global_load_lds(
                (AS1 const void*)(p1b + (size_t)(s0 + row) * 512 + kt + kc),
                (AS3 void*)(As[buf] + (size_t)(wave * 64) * 8), 16, 0, 0);
        }
#pragma unroll
        for (int j = 0; j < 2; j++) {
            int ch = j * 256 + tid;
            int row = ch >> 2, kc = (ch & 3) * 8;
            __builtin_amdgcn_global_load_lds(
                (AS1 const void*)(p1b + (size_t)row * 512 + kt + kc),
                (AS3 void*)(Bs1[buf] + (size_t)(j * 256 + wave * 64) * 8), 16, 0, 0);
            __builtin_amdgcn_global_load_lds(
                (AS1 const void*)(p2b + (size_t)row * 512 + kt + kc),
                (AS3 void*)(Bs2[buf] + (size_t)(j * 256 + wave * 64) * 8), 16, 0, 0);
        }
    };
    auto compute = [&](int buf) {
        bf16x8 afr = *(const bf16x8*)(As[buf] + (wave * 16 + lr) * 32 + quad * 8);
#pragma unroll
        for (int j = 0; j < 8; j++) {
            bf16x8 b1 = *(const bf16x8*)(Bs1[buf] + (j * 16 + lr) * 32 + quad * 8);
            accre[j] = __builtin_amdgcn_mfma_f32_16x16x32_bf16(afr, b1, accre[j], 0, 0, 0);
            bf16x8 b2 = *(const bf16x8*)(Bs2[buf] + (j * 16 + lr) * 32 + quad * 8);
            accim[j] = __builtin_amdgcn_mfma_f32_16x16x32_bf16(afr, b2, accim[j], 0, 0, 0);
        }
    };

    const int nt = 16;   // K=512
    stage(0, 0);
    __syncthreads();
    for (int t = 0; t < nt - 2; t += 2) {
        stage(1, (t + 1) << 5);
        compute(0);
        __syncthreads();
        stage(0, (t + 2) << 5);
        compute(1);
        __syncthreads();
    }
    stage(1, (nt - 1) << 5);
    compute(0);
    __syncthreads();
    compute(1);

    const float isq = 0.35355339059327373f;
    float ph_r[4], ph_c[8];
#pragma unroll
    for (int r = 0; r < 4; r++) ph_r[r] = phi[s0 + wave * 16 + quad * 4 + r];
#pragma unroll
    for (int j = 0; j < 8; j++) ph_c[j] = phi[j * 16 + lr];

#pragma unroll
    for (int r = 0; r < 4; r++) {
        float v[8];
        float mx = -1e30f;
#pragma unroll
        for (int j = 0; j < 8; j++) {
            float re = accre[j][r], im = accim[j][r];
            v[j] = (re * re + im * im) * isq + __cosf(ph_c[j] - ph_r[r]);
            mx = fmaxf(mx, v[j]);
        }
#pragma unroll
        for (int off = 1; off <= 8; off <<= 1) mx = fmaxf(mx, __shfl_xor(mx, off, 64));
        float sm = 0.f;
#pragma unroll
        for (int j = 0; j < 8; j++) { v[j] = __expf(v[j] - mx); sm += v[j]; }
#pragma unroll
        for (int off = 1; off <= 8; off <<= 1) sm += __shfl_xor(sm, off, 64);
        float inv = 1.f / sm;
        int srow = b * 128 + s0 + wave * 16 + quad * 4 + r;
#pragma unroll
        for (int j = 0; j < 8; j++) {
            float o = v[j] * inv;
            attn[(size_t)srow * 128 + j * 16 + lr] = o;
            attn_bf[(size_t)srow * 128 + j * 16 + lr] = f2bf(o);
        }
    }
}

// ---------------------------------------------------------------------------
extern "C" void kernel_launch(void* const* d_in, const int* in_sizes, int n_in,
                              void* d_out, int out_size, void* d_ws, size_t ws_size,
                              hipStream_t stream) {
    const float* X     = (const float*)d_in[0];
    const float* Wi    = (const float*)d_in[1];
    const float* bi    = (const float*)d_in[2];
    const float* Wv    = (const float*)d_in[3];
    const float* bv    = (const float*)d_in[4];
    const float* Wo    = (const float*)d_in[5];
    const float* bo    = (const float*)d_in[6];
    const float* theta = (const float*)d_in[7];
    const float* phi   = (const float*)d_in[8];

    float* y    = (float*)d_out;
    float* attn = y + (size_t)MM * EE;

    bf16s* Xb   = (bf16s*)d_ws;                      // 16384*1024
    bf16s* P1   = Xb  + (size_t)MM * EE;             // 16384*512
    bf16s* P2   = P1  + (size_t)MM * 512;            // 16384*512
    bf16s* Vwtb = P2  + (size_t)MM * 512;            // 128 * 1024*128 (V@Wo)^T
    bf16s* scr  = Vwtb + (size_t)MM * EE;            // scratch region
    bf16s* abf  = scr + (size_t)MM * EE;             // 128*128*128
    bf16s* Wvb  = abf + (size_t)BB * SS * SS;        // 1024*1024 bf16(Wv)
    bf16s* Wot  = Wvb + (size_t)EE * EE;             // 1024*1024 Wo^T
    float* Wit  = (float*)(Wot + (size_t)EE * EE);   // 8*1024 fp32 (32 KB)
    float* bvo  = Wit + 8 * 1024;                    // 1024 fp32
    float* bvop = bvo + 1024;                        // 16*1024 fp32 partials
    // scratch layout: v | Ubt | Wvot  (disjoint offsets, all fit in MM*EE)
    bf16s* v    = scr;                               // 16384*256
    bf16s* Ubt  = scr + (size_t)MM * DD;             // 512*256
    bf16s* Wvot = scr + (size_t)MM * DD + 512 * DD;  // 1024*1024 (Wv@Wo)^T

    // Wi transpose (coalesced encode loads)
    wtrans_kernel<<<32, 256, 0, stream>>>(Wi, Wit);
    // encode: qin -> product state v (bf16) + Xb side-product
    encode_kernel<<<MM / 4, 256, 0, stream>>>(X, Wit, bi, Xb, v);
    // build circuit unitary (theta only)
    ubuild_kernel<<<64, 256, 0, stream>>>(theta, Ubt);
    // weight prep: Wot = Wo^T (bf16), Wvb = bf16(Wv), bvo = bv@Wo + bo
    transpose_conv_kernel<<<dim3(32, 32), 256, 0, stream>>>(Wo, Wot, EE, EE);
    cvt_kernel<<<1024, 256, 0, stream>>>(Wv, Wvb);
    bvo_part_kernel<<<256, 256, 0, stream>>>(bv, Wo, bvop);
    bvo_reduce_kernel<<<4, 256, 0, stream>>>(bvop, bo, bvo);
    // Wvot[a][b] = (Wv@Wo)[b][a] :  A=Wot, Bt=Wvb  (M=N=K=1024)
    mfma_gemm<true><<<64, 256, 0, stream>>>(
        Wot, Wvb, nullptr, Wvot, EE, EE, EE, /*nm*/8, /*nn*/8, 0, 0, 0);
    // psi = v @ Ubt^T -> P1, P2
    psi_gemm_kernel<<<dim3(MM / 128, 4), 256, 0, stream>>>(v, Ubt, P1, P2);
    // Vwt_b = Wvot @ Xb_b^T   (batched; w = z*8 + m; Wvot L2-resident per XCD)
    mfma_gemm<true><<<1024, 256, 0, stream>>>(
        Wvot, Xb, nullptr, Vwtb, EE, SS, EE, /*nm*/8, /*nn*/1,
        0, (long long)SS * EE, (long long)EE * SS);
    // attn (Gram via MFMA + softmax)
    attn_kernel<<<dim3(2, BB), 256, 0, stream>>>(P1, P2, phi, attn, abf);
    // y_b = attn_b @ Vw_b + bvo   (fp32 out; w = z*8 + n)
    mfma_gemm<false><<<1024, 256, 0, stream>>>(
        abf, Vwtb, bvo, y, SS, EE, SS, /*nm*/1, /*nn*/8,
        (long long)SS * SS, (long long)EE * SS, (long long)SS * EE);
}

// Round 7
// 310.221 us; speedup vs baseline: 1.2363x; 1.0026x over previous
//
#include <hip/hip_runtime.h>
#include <hip/hip_bf16.h>

#define BB 128
#define SS 128
#define EE 1024
#define NQ 8
#define DD 256
#define LL 4
#define MM (BB*SS)

typedef unsigned short bf16s;
typedef __attribute__((ext_vector_type(8))) short bf16x8;
typedef __attribute__((ext_vector_type(4))) float f32x4;

#define AS1 __attribute__((address_space(1)))
#define AS3 __attribute__((address_space(3)))

__device__ __forceinline__ unsigned short f2bf(float x) {
    unsigned u = __float_as_uint(x);
    u += 0x7fffu + ((u >> 16) & 1u);
    return (unsigned short)(u >> 16);
}

// pipeline helpers: raw barrier + counted vmcnt (T4) with sched fences (#18)
#define PIPE_WAIT(N) do { \
    asm volatile("s_waitcnt vmcnt(" #N ")" ::: "memory"); \
    __builtin_amdgcn_sched_barrier(0); \
    __builtin_amdgcn_s_barrier(); \
    __builtin_amdgcn_sched_barrier(0); } while (0)
#define PIPE_BAR() do { \
    __builtin_amdgcn_sched_barrier(0); \
    __builtin_amdgcn_s_barrier(); } while (0)

// ---------------------------------------------------------------------------
// fp32 RxC -> bf16 CxR transpose-convert (weights)
// ---------------------------------------------------------------------------
__global__ __launch_bounds__(256) void transpose_conv_kernel(
    const float* __restrict__ in, bf16s* __restrict__ out, int R, int C)
{
    __shared__ float t[32][33];
    int bx = blockIdx.x * 32, by = blockIdx.y * 32;
    int lx = threadIdx.x & 31, ly = threadIdx.x >> 5;
#pragma unroll
    for (int i = 0; i < 32; i += 8)
        t[ly + i][lx] = in[(size_t)(by + ly + i) * C + bx + lx];
    __syncthreads();
#pragma unroll
    for (int i = 0; i < 32; i += 8)
        out[(size_t)(bx + ly + i) * R + by + lx] = f2bf(t[lx][ly + i]);
}

// ---------------------------------------------------------------------------
// fp32 -> bf16 straight convert (Wv), float4 vectorized
// ---------------------------------------------------------------------------
__global__ __launch_bounds__(256) void cvt_kernel(
    const float* __restrict__ in, bf16s* __restrict__ out)
{
    int g = blockIdx.x * 256 + threadIdx.x;      // float4 index
    f32x4 x = ((const f32x4*)in)[g];
    ushort4 o;
    o.x = f2bf(x[0]); o.y = f2bf(x[1]); o.z = f2bf(x[2]); o.w = f2bf(x[3]);
    ((ushort4*)out)[g] = o;
}

// ---------------------------------------------------------------------------
// bvo = bv@Wo + bo, two parallel stages.
// ---------------------------------------------------------------------------
__global__ __launch_bounds__(256) void bvo_part_kernel(
    const float* __restrict__ bv, const float* __restrict__ Wo,
    float* __restrict__ part)
{
    __shared__ float red[4][64];
    int lane = threadIdx.x & 63, w = threadIdx.x >> 6;
    int eb = blockIdx.x & 15, kb = blockIdx.x >> 4;
    int e = eb * 64 + lane;
    int k0 = kb * 64 + w * 16;
    float acc = 0.f;
#pragma unroll
    for (int i = 0; i < 16; i++)
        acc += bv[k0 + i] * Wo[(size_t)(k0 + i) * EE + e];
    red[w][lane] = acc;
    __syncthreads();
    if (w == 0)
        part[kb * EE + e] = red[0][lane] + red[1][lane] + red[2][lane] + red[3][lane];
}

__global__ __launch_bounds__(256) void bvo_reduce_kernel(
    const float* __restrict__ part, const float* __restrict__ bo,
    float* __restrict__ bvo)
{
    int e = blockIdx.x * 256 + threadIdx.x;
    float s = bo[e];
#pragma unroll
    for (int kb = 0; kb < 16; kb++) s += part[kb * EE + e];
    bvo[e] = s;
}

// ---------------------------------------------------------------------------
// Wi[1024][8] -> Wit[8][1024] fp32
// ---------------------------------------------------------------------------
__global__ __launch_bounds__(256) void wtrans_kernel(
    const float* __restrict__ Wi, float* __restrict__ Wit)
{
    int g = blockIdx.x * 256 + threadIdx.x;   // 0..8191
    int k = g >> 3, j = g & 7;
    Wit[j * 1024 + k] = Wi[g];
}

// ---------------------------------------------------------------------------
// encode: qin = X@Wi+bi; product state v (bf16); Xb = bf16(X) side-product.
// ---------------------------------------------------------------------------
__global__ __launch_bounds__(256) void encode_kernel(
    const float* __restrict__ X, const float* __restrict__ Wit,
    const float* __restrict__ bi,
    bf16s* __restrict__ Xb, bf16s* __restrict__ v)
{
    const int lane = threadIdx.x & 63;
    const int wid  = threadIdx.x >> 6;
    const int row  = blockIdx.x * 4 + wid;

    const f32x4* xr4 = (const f32x4*)(X + (size_t)row * EE);
    ushort4* xbr4 = (ushort4*)(Xb + (size_t)row * EE);

    float acc[NQ];
#pragma unroll
    for (int j = 0; j < NQ; j++) acc[j] = 0.f;

#pragma unroll
    for (int t = 0; t < 4; t++) {
        int k4 = t * 64 + lane;
        f32x4 x = xr4[k4];
        ushort4 xb;
        xb.x = f2bf(x[0]); xb.y = f2bf(x[1]);
        xb.z = f2bf(x[2]); xb.w = f2bf(x[3]);
        xbr4[k4] = xb;
#pragma unroll
        for (int j = 0; j < NQ; j++) {
            f32x4 w = ((const f32x4*)(Wit + j * 1024))[k4];
            acc[j] += x[0]*w[0] + x[1]*w[1] + x[2]*w[2] + x[3]*w[3];
        }
    }
    float qin[NQ];
#pragma unroll
    for (int j = 0; j < NQ; j++) {
        float s = acc[j];
#pragma unroll
        for (int off = 32; off >= 1; off >>= 1) s += __shfl_xor(s, off, 64);
        qin[j] = s + bi[j];
    }

    float cs[NQ], sn[NQ];
#pragma unroll
    for (int q = 0; q < NQ; q++) __sincosf(0.5f * qin[q], &sn[q], &cs[q]);

    float common = 1.f;
#pragma unroll
    for (int b = 2; b < 8; b++) {
        int q = 7 - b;
        common *= ((lane >> (b - 2)) & 1) ? sn[q] : cs[q];
    }
    float a0 = common * cs[6] * cs[7];
    float a1 = common * cs[6] * sn[7];
    float a2 = common * sn[6] * cs[7];
    float a3 = common * sn[6] * sn[7];
    ushort4 vo;
    vo.x = f2bf(a0); vo.y = f2bf(a1); vo.z = f2bf(a2); vo.w = f2bf(a3);
    ((ushort4*)(v + (size_t)row * DD))[lane] = vo;
}

// ---------------------------------------------------------------------------
// ubuild: theta-circuit on all 256 basis states -> Ubt bf16.
// ---------------------------------------------------------------------------
__global__ __launch_bounds__(256) void ubuild_kernel(
    const float* __restrict__ theta, bf16s* __restrict__ Ubt)
{
    const int lane = threadIdx.x & 63;
    const int wid  = threadIdx.x >> 6;
    const int col  = blockIdx.x * 4 + wid;   // 0..255

    float sr[4], si[4];
#pragma unroll
    for (int c = 0; c < 4; c++) { sr[c] = 0.f; si[c] = 0.f; }
    if (lane == (col >> 2)) sr[col & 3] = 1.f;

    auto apply_ry = [&](int b, float th) {
        float s, c;
        __sincosf(0.5f * th, &s, &c);
        if (b >= 2) {
            int lb = b - 2;
            int bit = (lane >> lb) & 1;
            float sgn = bit ? s : -s;
#pragma unroll
            for (int cc = 0; cc < 4; cc++) {
                float pr = __shfl_xor(sr[cc], 1 << lb, 64);
                float pi = __shfl_xor(si[cc], 1 << lb, 64);
                sr[cc] = c * sr[cc] + sgn * pr;
                si[cc] = c * si[cc] + sgn * pi;
            }
        } else {
            int m = 1 << b;
            float tr[4], ti[4];
#pragma unroll
            for (int cc = 0; cc < 4; cc++) { tr[cc] = sr[cc]; ti[cc] = si[cc]; }
#pragma unroll
            for (int cc = 0; cc < 4; cc++) {
                int bit = (cc >> b) & 1;
                float sgn = bit ? s : -s;
                sr[cc] = c * tr[cc] + sgn * tr[cc ^ m];
                si[cc] = c * ti[cc] + sgn * ti[cc ^ m];
            }
        }
    };
    auto apply_rz = [&](int b, float th) {
        float sz, cr;
        __sincosf(0.5f * th, &sz, &cr);
#pragma unroll
        for (int cc = 0; cc < 4; cc++) {
            int bit = (b >= 2) ? ((lane >> (b - 2)) & 1) : ((cc >> b) & 1);
            float ci = bit ? sz : -sz;
            float r = sr[cc], i = si[cc];
            sr[cc] = r * cr - i * ci;
            si[cc] = r * ci + i * cr;
        }
    };
    auto apply_cnot = [&](int bc, int bt) {
        float pr[4], pi[4];
        if (bt >= 2) {
            int m = 1 << (bt - 2);
#pragma unroll
            for (int cc = 0; cc < 4; cc++) {
                pr[cc] = __shfl_xor(sr[cc], m, 64);
                pi[cc] = __shfl_xor(si[cc], m, 64);
            }
        } else {
            int m = 1 << bt;
#pragma unroll
            for (int cc = 0; cc < 4; cc++) {
                pr[cc] = sr[cc ^ m];
                pi[cc] = si[cc ^ m];
            }
        }
#pragma unroll
        for (int cc = 0; cc < 4; cc++) {
            int ctrl = (bc >= 2) ? ((lane >> (bc - 2)) & 1) : ((cc >> bc) & 1);
            sr[cc] = ctrl ? pr[cc] : sr[cc];
            si[cc] = ctrl ? pi[cc] : si[cc];
        }
    };

#pragma unroll
    for (int l = 0; l < LL; l++) {
#pragma unroll
        for (int q = 0; q < NQ; q++) {
            apply_ry(7 - q, theta[(l * NQ + q) * 2 + 0]);
            apply_rz(7 - q, theta[(l * NQ + q) * 2 + 1]);
        }
#pragma unroll
        for (int q = 0; q < NQ; q++) {
            int t = (q + 1) & 7;
            apply_cnot(7 - q, 7 - t);
        }
    }

#pragma unroll
    for (int cc = 0; cc < 4; cc++) {
        int i = lane * 4 + cc;
        Ubt[(size_t)i * DD + col]         = f2bf(sr[cc]);
        Ubt[(size_t)(i + DD) * DD + col]  = f2bf(si[cc]);
    }
}

// ---------------------------------------------------------------------------
// psi_gemm: counted-vmcnt pipelined. Epilogue writes P1/P2.
// ---------------------------------------------------------------------------
__global__ __launch_bounds__(256) void psi_gemm_kernel(
    const bf16s* __restrict__ A, const bf16s* __restrict__ Bt,
    bf16s* __restrict__ P1, bf16s* __restrict__ P2)
{
    __shared__ bf16s As[2][128 * 32];
    __shared__ bf16s Bs[2][128 * 32];

    const int tid  = threadIdx.x;
    const int wave = tid >> 6, lane = tid & 63;
    const int quad = lane >> 4, lr = lane & 15;
    const int wm = (wave >> 1) * 64, wn = (wave & 1) * 64;
    const int m0 = blockIdx.x * 128, n0 = blockIdx.y * 128;
    const int K = DD, N = 2 * DD;

    f32x4 acc[4][4];
#pragma unroll
    for (int i = 0; i < 4; i++)
#pragma unroll
        for (int j = 0; j < 4; j++) acc[i][j] = (f32x4){0.f, 0.f, 0.f, 0.f};

    auto stage = [&](int buf, int kt) {
#pragma unroll
        for (int j = 0; j < 2; j++) {
            int ch = j * 256 + tid;
            int row = ch >> 2, kc = (ch & 3) * 8;
            __builtin_amdgcn_global_load_lds(
                (AS1 const void*)(A + (size_t)(m0 + row) * K + kt + kc),
                (AS3 void*)(As[buf] + (size_t)(j * 256 + wave * 64) * 8), 16, 0, 0);
            __builtin_amdgcn_global_load_lds(
                (AS1 const void*)(Bt + (size_t)(n0 + row) * K + kt + kc),
                (AS3 void*)(Bs[buf] + (size_t)(j * 256 + wave * 64) * 8), 16, 0, 0);
        }
    };
    auto compute = [&](int buf) {
        bf16x8 af[4], bfr[4];
#pragma unroll
        for (int i = 0; i < 4; i++)
            af[i] = *(const bf16x8*)(As[buf] + (wm + i * 16 + lr) * 32 + quad * 8);
#pragma unroll
        for (int j = 0; j < 4; j++)
            bfr[j] = *(const bf16x8*)(Bs[buf] + (wn + j * 16 + lr) * 32 + quad * 8);
#pragma unroll
        for (int i = 0; i < 4; i++)
#pragma unroll
            for (int j = 0; j < 4; j++)
                acc[i][j] = __builtin_amdgcn_mfma_f32_16x16x32_bf16(
                    af[i], bfr[j], acc[i][j], 0, 0, 0);
    };

    const int nt = K >> 5;   // 8
    stage(0, 0);
    int cur = 0;
    for (int t = 0; t < nt; t++) {
        if (t + 1 < nt) {
            stage(cur ^ 1, (t + 1) << 5);
            PIPE_WAIT(4);
        } else {
            PIPE_WAIT(0);
        }
        compute(cur);
        PIPE_BAR();
        cur ^= 1;
    }

#pragma unroll
    for (int i = 0; i < 4; i++) {
        int row0 = m0 + wm + i * 16 + quad * 4;
#pragma unroll
        for (int j = 0; j < 4; j++) {
            int col = n0 + wn + j * 16 + lr;
            int c2  = (col < DD) ? (col + DD) : (col - DD);
            float sgn = (col < DD) ? -1.f : 1.f;
#pragma unroll
            for (int r = 0; r < 4; r++) {
                float val = acc[i][j][r];
                P1[(size_t)(row0 + r) * N + col] = f2bf(val);
                P2[(size_t)(row0 + r) * N + c2] = f2bf(sgn * val);
            }
        }
    }
}

// ---------------------------------------------------------------------------
// MFMA bf16 GEMM: counted-vmcnt pipelined; bijective XCD chunking.
// Work order: w = (z * nm + m) * nn + n.
// ---------------------------------------------------------------------------
template<bool OUT_BF16>
__global__ __launch_bounds__(256) void mfma_gemm(
    const bf16s* __restrict__ A, const bf16s* __restrict__ Bt,
    const float* __restrict__ bias, void* __restrict__ Cv,
    int M, int N, int K, int nm, int nn,
    long long sA, long long sB, long long sC)
{
    __shared__ bf16s As[2][128 * 32];
    __shared__ bf16s Bs[2][128 * 32];

    const int tid  = threadIdx.x;
    const int wave = tid >> 6, lane = tid & 63;
    const int quad = lane >> 4, lr = lane & 15;
    const int wm = (wave >> 1) * 64, wn = (wave & 1) * 64;

    const int nwg = gridDim.x;
    const int q = nwg >> 3, r = nwg & 7;
    const int xcd = blockIdx.x & 7, idx = blockIdx.x >> 3;
    const int w = (xcd < r ? xcd * (q + 1) : r * (q + 1) + (xcd - r) * q) + idx;
    const int n_t = w % nn;
    const int m_t = (w / nn) % nm;
    const int z   = w / (nn * nm);
    const int m0 = m_t * 128, n0 = n_t * 128;

    A  += (size_t)z * sA;
    Bt += (size_t)z * sB;

    f32x4 acc[4][4];
#pragma unroll
    for (int i = 0; i < 4; i++)
#pragma unroll
        for (int j = 0; j < 4; j++) acc[i][j] = (f32x4){0.f, 0.f, 0.f, 0.f};

    auto stage = [&](int buf, int kt) {
#pragma unroll
        for (int j = 0; j < 2; j++) {
            int ch = j * 256 + tid;
            int row = ch >> 2, kc = (ch & 3) * 8;
            __builtin_amdgcn_global_load_lds(
                (AS1 const void*)(A + (size_t)(m0 + row) * K + kt + kc),
                (AS3 void*)(As[buf] + (size_t)(j * 256 + wave * 64) * 8), 16, 0, 0);
            __builtin_amdgcn_global_load_lds(
                (AS1 const void*)(Bt + (size_t)(n0 + row) * K + kt + kc),
                (AS3 void*)(Bs[buf] + (size_t)(j * 256 + wave * 64) * 8), 16, 0, 0);
        }
    };
    auto compute = [&](int buf) {
        bf16x8 af[4], bfr[4];
#pragma unroll
        for (int i = 0; i < 4; i++)
            af[i] = *(const bf16x8*)(As[buf] + (wm + i * 16 + lr) * 32 + quad * 8);
#pragma unroll
        for (int j = 0; j < 4; j++)
            bfr[j] = *(const bf16x8*)(Bs[buf] + (wn + j * 16 + lr) * 32 + quad * 8);
#pragma unroll
        for (int i = 0; i < 4; i++)
#pragma unroll
            for (int j = 0; j < 4; j++)
                acc[i][j] = __builtin_amdgcn_mfma_f32_16x16x32_bf16(
                    af[i], bfr[j], acc[i][j], 0, 0, 0);
    };

    const int nt = K >> 5;
    stage(0, 0);
    int cur = 0;
    for (int t = 0; t < nt; t++) {
        if (t + 1 < nt) {
            stage(cur ^ 1, (t + 1) << 5);
            PIPE_WAIT(4);
        } else {
            PIPE_WAIT(0);
        }
        compute(cur);
        PIPE_BAR();
        cur ^= 1;
    }

    float* Cf = (float*)Cv + (size_t)z * sC;
    bf16s* Cb = (bf16s*)Cv + (size_t)z * sC;
#pragma unroll
    for (int i = 0; i < 4; i++) {
        int row0 = m0 + wm + i * 16 + quad * 4;
#pragma unroll
        for (int j = 0; j < 4; j++) {
            int col = n0 + wn + j * 16 + lr;
            float bb = bias ? bias[col] : 0.f;
#pragma unroll
            for (int r = 0; r < 4; r++) {
                float v = acc[i][j][r] + bb;
                if (OUT_BF16) Cb[(size_t)(row0 + r) * N + col] = f2bf(v);
                else          Cf[(size_t)(row0 + r) * N + col] = v;
            }
        }
    }
}

// ---------------------------------------------------------------------------
// attn: MFMA Gram + fused softmax. Counted-vmcnt pipeline; A-fragments read
// from Bs1 (As rows were a subset of Bs1 rows -> staging dropped).
// ---------------------------------------------------------------------------
__global__ __launch_bounds__(256) void attn_kernel(
    const bf16s* __restrict__ P1, const bf16s* __restrict__ P2,
    const float* __restrict__ phi,
    float* __restrict__ attn, bf16s* __restrict__ attn_bf)
{
    __shared__ bf16s Bs1[2][128 * 32];
    __shared__ bf16s Bs2[2][128 * 32];

    const int tid  = threadIdx.x;
    const int wave = tid >> 6, lane = tid & 63;
    const int quad = lane >> 4, lr = lane & 15;
    const int b = blockIdx.y;
    const int s0 = blockIdx.x * 64;
    const bf16s* p1b = P1 + (size_t)b * 128 * 512;
    const bf16s* p2b = P2 + (size_t)b * 128 * 512;

    f32x4 accre[8], accim[8];
#pragma unroll
    for (int j = 0; j < 8; j++) {
        accre[j] = (f32x4){0.f, 0.f, 0.f, 0.f};
        accim[j] = (f32x4){0.f, 0.f, 0.f, 0.f};
    }

    auto stage = [&](int buf, int kt) {
#pragma unroll
        for (int j = 0; j < 2; j++) {
            int ch = j * 256 + tid;
            int row = ch >> 2, kc = (ch & 3) * 8;
            __builtin_amdgcn_global_load_lds(
                (AS1 const void*)(p1b + (size_t)row * 512 + kt + kc),
                (AS3 void*)(Bs1[buf] + (size_t)(j * 256 + wave * 64) * 8), 16, 0, 0);
            __builtin_amdgcn_global_load_lds(
                (AS1 const void*)(p2b + (size_t)row * 512 + kt + kc),
                (AS3 void*)(Bs2[buf] + (size_t)(j * 256 + wave * 64) * 8), 16, 0, 0);
        }
    };
    auto compute = [&](int buf) {
        bf16x8 afr = *(const bf16x8*)(Bs1[buf] + (s0 + wave * 16 + lr) * 32 + quad * 8);
#pragma unroll
        for (int j = 0; j < 8; j++) {
            bf16x8 b1 = *(const bf16x8*)(Bs1[buf] + (j * 16 + lr) * 32 + quad * 8);
            accre[j] = __builtin_amdgcn_mfma_f32_16x16x32_bf16(afr, b1, accre[j], 0, 0, 0);
            bf16x8 b2 = *(const bf16x8*)(Bs2[buf] + (j * 16 + lr) * 32 + quad * 8);
            accim[j] = __builtin_amdgcn_mfma_f32_16x16x32_bf16(afr, b2, accim[j], 0, 0, 0);
        }
    };

    const int nt = 16;   // K=512
    stage(0, 0);
    int cur = 0;
    for (int t = 0; t < nt; t++) {
        if (t + 1 < nt) {
            stage(cur ^ 1, (t + 1) << 5);
            PIPE_WAIT(4);
        } else {
            PIPE_WAIT(0);
        }
        compute(cur);
        PIPE_BAR();
        cur ^= 1;
    }

    const float isq = 0.35355339059327373f;
    float ph_r[4], ph_c[8];
#pragma unroll
    for (int r = 0; r < 4; r++) ph_r[r] = phi[s0 + wave * 16 + quad * 4 + r];
#pragma unroll
    for (int j = 0; j < 8; j++) ph_c[j] = phi[j * 16 + lr];

#pragma unroll
    for (int r = 0; r < 4; r++) {
        float v[8];
        float mx = -1e30f;
#pragma unroll
        for (int j = 0; j < 8; j++) {
            float re = accre[j][r], im = accim[j][r];
            v[j] = (re * re + im * im) * isq + __cosf(ph_c[j] - ph_r[r]);
            mx = fmaxf(mx, v[j]);
        }
#pragma unroll
        for (int off = 1; off <= 8; off <<= 1) mx = fmaxf(mx, __shfl_xor(mx, off, 64));
        float sm = 0.f;
#pragma unroll
        for (int j = 0; j < 8; j++) { v[j] = __expf(v[j] - mx); sm += v[j]; }
#pragma unroll
        for (int off = 1; off <= 8; off <<= 1) sm += __shfl_xor(sm, off, 64);
        float inv = 1.f / sm;
        int srow = b * 128 + s0 + wave * 16 + quad * 4 + r;
#pragma unroll
        for (int j = 0; j < 8; j++) {
            float o = v[j] * inv;
            attn[(size_t)srow * 128 + j * 16 + lr] = o;
            attn_bf[(size_t)srow * 128 + j * 16 + lr] = f2bf(o);
        }
    }
}

// ---------------------------------------------------------------------------
extern "C" void kernel_launch(void* const* d_in, const int* in_sizes, int n_in,
                              void* d_out, int out_size, void* d_ws, size_t ws_size,
                              hipStream_t stream) {
    const float* X     = (const float*)d_in[0];
    const float* Wi    = (const float*)d_in[1];
    const float* bi    = (const float*)d_in[2];
    const float* Wv    = (const float*)d_in[3];
    const float* bv    = (const float*)d_in[4];
    const float* Wo    = (const float*)d_in[5];
    const float* bo    = (const float*)d_in[6];
    const float* theta = (const float*)d_in[7];
    const float* phi   = (const float*)d_in[8];

    float* y    = (float*)d_out;
    float* attn = y + (size_t)MM * EE;

    bf16s* Xb   = (bf16s*)d_ws;                      // 16384*1024
    bf16s* P1   = Xb  + (size_t)MM * EE;             // 16384*512
    bf16s* P2   = P1  + (size_t)MM * 512;            // 16384*512
    bf16s* Vwtb = P2  + (size_t)MM * 512;            // 128 * 1024*128 (V@Wo)^T
    bf16s* scr  = Vwtb + (size_t)MM * EE;            // scratch region
    bf16s* abf  = scr + (size_t)MM * EE;             // 128*128*128
    bf16s* Wvb  = abf + (size_t)BB * SS * SS;        // 1024*1024 bf16(Wv)
    bf16s* Wot  = Wvb + (size_t)EE * EE;             // 1024*1024 Wo^T
    float* Wit  = (float*)(Wot + (size_t)EE * EE);   // 8*1024 fp32
    float* bvo  = Wit + 8 * 1024;                    // 1024 fp32
    float* bvop = bvo + 1024;                        // 16*1024 fp32 partials
    bf16s* v    = scr;                               // 16384*256
    bf16s* Ubt  = scr + (size_t)MM * DD;             // 512*256
    bf16s* Wvot = scr + (size_t)MM * DD + 512 * DD;  // 1024*1024 (Wv@Wo)^T

    wtrans_kernel<<<32, 256, 0, stream>>>(Wi, Wit);
    encode_kernel<<<MM / 4, 256, 0, stream>>>(X, Wit, bi, Xb, v);
    ubuild_kernel<<<64, 256, 0, stream>>>(theta, Ubt);
    transpose_conv_kernel<<<dim3(32, 32), 256, 0, stream>>>(Wo, Wot, EE, EE);
    cvt_kernel<<<1024, 256, 0, stream>>>(Wv, Wvb);
    bvo_part_kernel<<<256, 256, 0, stream>>>(bv, Wo, bvop);
    bvo_reduce_kernel<<<4, 256, 0, stream>>>(bvop, bo, bvo);
    // Wvot[a][b] = (Wv@Wo)[b][a] :  A=Wot, Bt=Wvb  (M=N=K=1024)
    mfma_gemm<true><<<64, 256, 0, stream>>>(
        Wot, Wvb, nullptr, Wvot, EE, EE, EE, /*nm*/8, /*nn*/8, 0, 0, 0);
    // psi = v @ Ubt^T -> P1, P2
    psi_gemm_kernel<<<dim3(MM / 128, 4), 256, 0, stream>>>(v, Ubt, P1, P2);
    // Vwt_b = Wvot @ Xb_b^T
    mfma_gemm<true><<<1024, 256, 0, stream>>>(
        Wvot, Xb, nullptr, Vwtb, EE, SS, EE, /*nm*/8, /*nn*/1,
        0, (long long)SS * EE, (long long)EE * SS);
    // attn (Gram via MFMA + softmax)
    attn_kernel<<<dim3(2, BB), 256, 0, stream>>>(P1, P2, phi, attn, abf);
    // y_b = attn_b @ Vw_b + bvo
    mfma_gemm<false><<<1024, 256, 0, stream>>>(
        abf, Vwtb, bvo, y, SS, EE, SS, /*nm*/1, /*nn*/8,
        (long long)SS * SS, (long long)EE * SS, (long long)SS * EE);
}

// Round 8
// 309.842 us; speedup vs baseline: 1.2378x; 1.0012x over previous
//
#include <hip/hip_runtime.h>
#include <hip/hip_bf16.h>

#define BB 128
#define SS 128
#define EE 1024
#define NQ 8
#define DD 256
#define LL 4
#define MM (BB*SS)

typedef unsigned short bf16s;
typedef __attribute__((ext_vector_type(8))) short bf16x8;
typedef __attribute__((ext_vector_type(4))) float f32x4;

#define AS1 __attribute__((address_space(1)))
#define AS3 __attribute__((address_space(3)))

__device__ __forceinline__ unsigned short f2bf(float x) {
    unsigned u = __float_as_uint(x);
    u += 0x7fffu + ((u >> 16) & 1u);
    return (unsigned short)(u >> 16);
}

// pipeline helpers: counted vmcnt (T4) + raw barrier, sched fences (#18)
#define PIPE_WAIT(N) do { \
    asm volatile("s_waitcnt vmcnt(" #N ")" ::: "memory"); \
    __builtin_amdgcn_sched_barrier(0); \
    __builtin_amdgcn_s_barrier(); \
    __builtin_amdgcn_sched_barrier(0); } while (0)
#define PIPE_BAR() do { \
    __builtin_amdgcn_sched_barrier(0); \
    __builtin_amdgcn_s_barrier(); } while (0)

// ---------------------------------------------------------------------------
// fp32 RxC -> bf16 CxR transpose-convert (weights)
// ---------------------------------------------------------------------------
__global__ __launch_bounds__(256) void transpose_conv_kernel(
    const float* __restrict__ in, bf16s* __restrict__ out, int R, int C)
{
    __shared__ float t[32][33];
    int bx = blockIdx.x * 32, by = blockIdx.y * 32;
    int lx = threadIdx.x & 31, ly = threadIdx.x >> 5;
#pragma unroll
    for (int i = 0; i < 32; i += 8)
        t[ly + i][lx] = in[(size_t)(by + ly + i) * C + bx + lx];
    __syncthreads();
#pragma unroll
    for (int i = 0; i < 32; i += 8)
        out[(size_t)(bx + ly + i) * R + by + lx] = f2bf(t[lx][ly + i]);
}

// ---------------------------------------------------------------------------
// fp32 -> bf16 straight convert (Wv), float4 vectorized
// ---------------------------------------------------------------------------
__global__ __launch_bounds__(256) void cvt_kernel(
    const float* __restrict__ in, bf16s* __restrict__ out)
{
    int g = blockIdx.x * 256 + threadIdx.x;      // float4 index
    f32x4 x = ((const f32x4*)in)[g];
    ushort4 o;
    o.x = f2bf(x[0]); o.y = f2bf(x[1]); o.z = f2bf(x[2]); o.w = f2bf(x[3]);
    ((ushort4*)out)[g] = o;
}

// ---------------------------------------------------------------------------
// bvo = bv@Wo + bo, two parallel stages.
// ---------------------------------------------------------------------------
__global__ __launch_bounds__(256) void bvo_part_kernel(
    const float* __restrict__ bv, const float* __restrict__ Wo,
    float* __restrict__ part)
{
    __shared__ float red[4][64];
    int lane = threadIdx.x & 63, w = threadIdx.x >> 6;
    int eb = blockIdx.x & 15, kb = blockIdx.x >> 4;
    int e = eb * 64 + lane;
    int k0 = kb * 64 + w * 16;
    float acc = 0.f;
#pragma unroll
    for (int i = 0; i < 16; i++)
        acc += bv[k0 + i] * Wo[(size_t)(k0 + i) * EE + e];
    red[w][lane] = acc;
    __syncthreads();
    if (w == 0)
        part[kb * EE + e] = red[0][lane] + red[1][lane] + red[2][lane] + red[3][lane];
}

__global__ __launch_bounds__(256) void bvo_reduce_kernel(
    const float* __restrict__ part, const float* __restrict__ bo,
    float* __restrict__ bvo)
{
    int e = blockIdx.x * 256 + threadIdx.x;
    float s = bo[e];
#pragma unroll
    for (int kb = 0; kb < 16; kb++) s += part[kb * EE + e];
    bvo[e] = s;
}

// ---------------------------------------------------------------------------
// Wi[1024][8] -> Wit[8][1024] fp32
// ---------------------------------------------------------------------------
__global__ __launch_bounds__(256) void wtrans_kernel(
    const float* __restrict__ Wi, float* __restrict__ Wit)
{
    int g = blockIdx.x * 256 + threadIdx.x;   // 0..8191
    int k = g >> 3, j = g & 7;
    Wit[j * 1024 + k] = Wi[g];
}

// ---------------------------------------------------------------------------
// encode: qin = X@Wi+bi; product state v (bf16); Xb = bf16(X) side-product.
// ---------------------------------------------------------------------------
__global__ __launch_bounds__(256) void encode_kernel(
    const float* __restrict__ X, const float* __restrict__ Wit,
    const float* __restrict__ bi,
    bf16s* __restrict__ Xb, bf16s* __restrict__ v)
{
    const int lane = threadIdx.x & 63;
    const int wid  = threadIdx.x >> 6;
    const int row  = blockIdx.x * 4 + wid;

    const f32x4* xr4 = (const f32x4*)(X + (size_t)row * EE);
    ushort4* xbr4 = (ushort4*)(Xb + (size_t)row * EE);

    float acc[NQ];
#pragma unroll
    for (int j = 0; j < NQ; j++) acc[j] = 0.f;

#pragma unroll
    for (int t = 0; t < 4; t++) {
        int k4 = t * 64 + lane;
        f32x4 x = xr4[k4];
        ushort4 xb;
        xb.x = f2bf(x[0]); xb.y = f2bf(x[1]);
        xb.z = f2bf(x[2]); xb.w = f2bf(x[3]);
        xbr4[k4] = xb;
#pragma unroll
        for (int j = 0; j < NQ; j++) {
            f32x4 w = ((const f32x4*)(Wit + j * 1024))[k4];
            acc[j] += x[0]*w[0] + x[1]*w[1] + x[2]*w[2] + x[3]*w[3];
        }
    }
    float qin[NQ];
#pragma unroll
    for (int j = 0; j < NQ; j++) {
        float s = acc[j];
#pragma unroll
        for (int off = 32; off >= 1; off >>= 1) s += __shfl_xor(s, off, 64);
        qin[j] = s + bi[j];
    }

    float cs[NQ], sn[NQ];
#pragma unroll
    for (int q = 0; q < NQ; q++) __sincosf(0.5f * qin[q], &sn[q], &cs[q]);

    float common = 1.f;
#pragma unroll
    for (int b = 2; b < 8; b++) {
        int q = 7 - b;
        common *= ((lane >> (b - 2)) & 1) ? sn[q] : cs[q];
    }
    float a0 = common * cs[6] * cs[7];
    float a1 = common * cs[6] * sn[7];
    float a2 = common * sn[6] * cs[7];
    float a3 = common * sn[6] * sn[7];
    ushort4 vo;
    vo.x = f2bf(a0); vo.y = f2bf(a1); vo.z = f2bf(a2); vo.w = f2bf(a3);
    ((ushort4*)(v + (size_t)row * DD))[lane] = vo;
}

// ---------------------------------------------------------------------------
// ubuild: theta-circuit on all 256 basis states -> Ubt bf16.
// ---------------------------------------------------------------------------
__global__ __launch_bounds__(256) void ubuild_kernel(
    const float* __restrict__ theta, bf16s* __restrict__ Ubt)
{
    const int lane = threadIdx.x & 63;
    const int wid  = threadIdx.x >> 6;
    const int col  = blockIdx.x * 4 + wid;   // 0..255

    float sr[4], si[4];
#pragma unroll
    for (int c = 0; c < 4; c++) { sr[c] = 0.f; si[c] = 0.f; }
    if (lane == (col >> 2)) sr[col & 3] = 1.f;

    auto apply_ry = [&](int b, float th) {
        float s, c;
        __sincosf(0.5f * th, &s, &c);
        if (b >= 2) {
            int lb = b - 2;
            int bit = (lane >> lb) & 1;
            float sgn = bit ? s : -s;
#pragma unroll
            for (int cc = 0; cc < 4; cc++) {
                float pr = __shfl_xor(sr[cc], 1 << lb, 64);
                float pi = __shfl_xor(si[cc], 1 << lb, 64);
                sr[cc] = c * sr[cc] + sgn * pr;
                si[cc] = c * si[cc] + sgn * pi;
            }
        } else {
            int m = 1 << b;
            float tr[4], ti[4];
#pragma unroll
            for (int cc = 0; cc < 4; cc++) { tr[cc] = sr[cc]; ti[cc] = si[cc]; }
#pragma unroll
            for (int cc = 0; cc < 4; cc++) {
                int bit = (cc >> b) & 1;
                float sgn = bit ? s : -s;
                sr[cc] = c * tr[cc] + sgn * tr[cc ^ m];
                si[cc] = c * ti[cc] + sgn * ti[cc ^ m];
            }
        }
    };
    auto apply_rz = [&](int b, float th) {
        float sz, cr;
        __sincosf(0.5f * th, &sz, &cr);
#pragma unroll
        for (int cc = 0; cc < 4; cc++) {
            int bit = (b >= 2) ? ((lane >> (b - 2)) & 1) : ((cc >> b) & 1);
            float ci = bit ? sz : -sz;
            float r = sr[cc], i = si[cc];
            sr[cc] = r * cr - i * ci;
            si[cc] = r * ci + i * cr;
        }
    };
    auto apply_cnot = [&](int bc, int bt) {
        float pr[4], pi[4];
        if (bt >= 2) {
            int m = 1 << (bt - 2);
#pragma unroll
            for (int cc = 0; cc < 4; cc++) {
                pr[cc] = __shfl_xor(sr[cc], m, 64);
                pi[cc] = __shfl_xor(si[cc], m, 64);
            }
        } else {
            int m = 1 << bt;
#pragma unroll
            for (int cc = 0; cc < 4; cc++) {
                pr[cc] = sr[cc ^ m];
                pi[cc] = si[cc ^ m];
            }
        }
#pragma unroll
        for (int cc = 0; cc < 4; cc++) {
            int ctrl = (bc >= 2) ? ((lane >> (bc - 2)) & 1) : ((cc >> bc) & 1);
            sr[cc] = ctrl ? pr[cc] : sr[cc];
            si[cc] = ctrl ? pi[cc] : si[cc];
        }
    };

#pragma unroll
    for (int l = 0; l < LL; l++) {
#pragma unroll
        for (int q = 0; q < NQ; q++) {
            apply_ry(7 - q, theta[(l * NQ + q) * 2 + 0]);
            apply_rz(7 - q, theta[(l * NQ + q) * 2 + 1]);
        }
#pragma unroll
        for (int q = 0; q < NQ; q++) {
            int t = (q + 1) & 7;
            apply_cnot(7 - q, 7 - t);
        }
    }

#pragma unroll
    for (int cc = 0; cc < 4; cc++) {
        int i = lane * 4 + cc;
        Ubt[(size_t)i * DD + col]         = f2bf(sr[cc]);
        Ubt[(size_t)(i + DD) * DD + col]  = f2bf(si[cc]);
    }
}

// ---------------------------------------------------------------------------
// psi_gemm: depth-2 (3-buffer) pipelined. Epilogue writes P1/P2.
// ---------------------------------------------------------------------------
__global__ __launch_bounds__(256) void psi_gemm_kernel(
    const bf16s* __restrict__ A, const bf16s* __restrict__ Bt,
    bf16s* __restrict__ P1, bf16s* __restrict__ P2)
{
    __shared__ bf16s As[3][128 * 32];
    __shared__ bf16s Bs[3][128 * 32];

    const int tid  = threadIdx.x;
    const int wave = tid >> 6, lane = tid & 63;
    const int quad = lane >> 4, lr = lane & 15;
    const int wm = (wave >> 1) * 64, wn = (wave & 1) * 64;
    const int m0 = blockIdx.x * 128, n0 = blockIdx.y * 128;
    const int K = DD, N = 2 * DD;

    f32x4 acc[4][4];
#pragma unroll
    for (int i = 0; i < 4; i++)
#pragma unroll
        for (int j = 0; j < 4; j++) acc[i][j] = (f32x4){0.f, 0.f, 0.f, 0.f};

    auto stage = [&](int buf, int kt) {
#pragma unroll
        for (int j = 0; j < 2; j++) {
            int ch = j * 256 + tid;
            int row = ch >> 2, kc = (ch & 3) * 8;
            __builtin_amdgcn_global_load_lds(
                (AS1 const void*)(A + (size_t)(m0 + row) * K + kt + kc),
                (AS3 void*)(As[buf] + (size_t)(j * 256 + wave * 64) * 8), 16, 0, 0);
            __builtin_amdgcn_global_load_lds(
                (AS1 const void*)(Bt + (size_t)(n0 + row) * K + kt + kc),
                (AS3 void*)(Bs[buf] + (size_t)(j * 256 + wave * 64) * 8), 16, 0, 0);
        }
    };
    auto compute = [&](int buf) {
        bf16x8 af[4], bfr[4];
#pragma unroll
        for (int i = 0; i < 4; i++)
            af[i] = *(const bf16x8*)(As[buf] + (wm + i * 16 + lr) * 32 + quad * 8);
#pragma unroll
        for (int j = 0; j < 4; j++)
            bfr[j] = *(const bf16x8*)(Bs[buf] + (wn + j * 16 + lr) * 32 + quad * 8);
#pragma unroll
        for (int i = 0; i < 4; i++)
#pragma unroll
            for (int j = 0; j < 4; j++)
                acc[i][j] = __builtin_amdgcn_mfma_f32_16x16x32_bf16(
                    af[i], bfr[j], acc[i][j], 0, 0, 0);
    };

    const int nt = K >> 5;   // 8
    stage(0, 0);
    stage(1, 1 << 5);
    int cur = 0, nxt = 2;
    for (int t = 0; t < nt; t++) {
        if (t + 2 < nt) { stage(nxt, (t + 2) << 5); PIPE_WAIT(8); }
        else if (t + 1 < nt) PIPE_WAIT(4);
        else PIPE_WAIT(0);
        compute(cur);
        PIPE_BAR();
        cur = (cur == 2) ? 0 : cur + 1;
        nxt = (nxt == 2) ? 0 : nxt + 1;
    }

#pragma unroll
    for (int i = 0; i < 4; i++) {
        int row0 = m0 + wm + i * 16 + quad * 4;
#pragma unroll
        for (int j = 0; j < 4; j++) {
            int col = n0 + wn + j * 16 + lr;
            int c2  = (col < DD) ? (col + DD) : (col - DD);
            float sgn = (col < DD) ? -1.f : 1.f;
#pragma unroll
            for (int r = 0; r < 4; r++) {
                float val = acc[i][j][r];
                P1[(size_t)(row0 + r) * N + col] = f2bf(val);
                P2[(size_t)(row0 + r) * N + c2] = f2bf(sgn * val);
            }
        }
    }
}

// ---------------------------------------------------------------------------
// MFMA bf16 GEMM: depth-2 (3-buffer) pipeline; bijective XCD chunking.
// Work order: w = (z * nm + m) * nn + n.
// ---------------------------------------------------------------------------
template<bool OUT_BF16>
__global__ __launch_bounds__(256) void mfma_gemm(
    const bf16s* __restrict__ A, const bf16s* __restrict__ Bt,
    const float* __restrict__ bias, void* __restrict__ Cv,
    int M, int N, int K, int nm, int nn,
    long long sA, long long sB, long long sC)
{
    __shared__ bf16s As[3][128 * 32];
    __shared__ bf16s Bs[3][128 * 32];

    const int tid  = threadIdx.x;
    const int wave = tid >> 6, lane = tid & 63;
    const int quad = lane >> 4, lr = lane & 15;
    const int wm = (wave >> 1) * 64, wn = (wave & 1) * 64;

    const int nwg = gridDim.x;
    const int q = nwg >> 3, r = nwg & 7;
    const int xcd = blockIdx.x & 7, idx = blockIdx.x >> 3;
    const int w = (xcd < r ? xcd * (q + 1) : r * (q + 1) + (xcd - r) * q) + idx;
    const int n_t = w % nn;
    const int m_t = (w / nn) % nm;
    const int z   = w / (nn * nm);
    const int m0 = m_t * 128, n0 = n_t * 128;

    A  += (size_t)z * sA;
    Bt += (size_t)z * sB;

    f32x4 acc[4][4];
#pragma unroll
    for (int i = 0; i < 4; i++)
#pragma unroll
        for (int j = 0; j < 4; j++) acc[i][j] = (f32x4){0.f, 0.f, 0.f, 0.f};

    auto stage = [&](int buf, int kt) {
#pragma unroll
        for (int j = 0; j < 2; j++) {
            int ch = j * 256 + tid;
            int row = ch >> 2, kc = (ch & 3) * 8;
            __builtin_amdgcn_global_load_lds(
                (AS1 const void*)(A + (size_t)(m0 + row) * K + kt + kc),
                (AS3 void*)(As[buf] + (size_t)(j * 256 + wave * 64) * 8), 16, 0, 0);
            __builtin_amdgcn_global_load_lds(
                (AS1 const void*)(Bt + (size_t)(n0 + row) * K + kt + kc),
                (AS3 void*)(Bs[buf] + (size_t)(j * 256 + wave * 64) * 8), 16, 0, 0);
        }
    };
    auto compute = [&](int buf) {
        bf16x8 af[4], bfr[4];
#pragma unroll
        for (int i = 0; i < 4; i++)
            af[i] = *(const bf16x8*)(As[buf] + (wm + i * 16 + lr) * 32 + quad * 8);
#pragma unroll
        for (int j = 0; j < 4; j++)
            bfr[j] = *(const bf16x8*)(Bs[buf] + (wn + j * 16 + lr) * 32 + quad * 8);
#pragma unroll
        for (int i = 0; i < 4; i++)
#pragma unroll
            for (int j = 0; j < 4; j++)
                acc[i][j] = __builtin_amdgcn_mfma_f32_16x16x32_bf16(
                    af[i], bfr[j], acc[i][j], 0, 0, 0);
    };

    const int nt = K >> 5;   // all call sites: >= 4
    stage(0, 0);
    stage(1, 1 << 5);
    int cur = 0, nxt = 2;
    for (int t = 0; t < nt; t++) {
        if (t + 2 < nt) { stage(nxt, (t + 2) << 5); PIPE_WAIT(8); }
        else if (t + 1 < nt) PIPE_WAIT(4);
        else PIPE_WAIT(0);
        compute(cur);
        PIPE_BAR();
        cur = (cur == 2) ? 0 : cur + 1;
        nxt = (nxt == 2) ? 0 : nxt + 1;
    }

    float* Cf = (float*)Cv + (size_t)z * sC;
    bf16s* Cb = (bf16s*)Cv + (size_t)z * sC;
#pragma unroll
    for (int i = 0; i < 4; i++) {
        int row0 = m0 + wm + i * 16 + quad * 4;
#pragma unroll
        for (int j = 0; j < 4; j++) {
            int col = n0 + wn + j * 16 + lr;
            float bb = bias ? bias[col] : 0.f;
#pragma unroll
            for (int r = 0; r < 4; r++) {
                float v = acc[i][j][r] + bb;
                if (OUT_BF16) Cb[(size_t)(row0 + r) * N + col] = f2bf(v);
                else          Cf[(size_t)(row0 + r) * N + col] = v;
            }
        }
    }
}

// ---------------------------------------------------------------------------
// attn: MFMA Gram + fused softmax. Depth-2 (3-buffer) pipeline; A-fragments
// read from Bs1 (As rows subset of Bs1 rows).
// ---------------------------------------------------------------------------
__global__ __launch_bounds__(256) void attn_kernel(
    const bf16s* __restrict__ P1, const bf16s* __restrict__ P2,
    const float* __restrict__ phi,
    float* __restrict__ attn, bf16s* __restrict__ attn_bf)
{
    __shared__ bf16s Bs1[3][128 * 32];
    __shared__ bf16s Bs2[3][128 * 32];

    const int tid  = threadIdx.x;
    const int wave = tid >> 6, lane = tid & 63;
    const int quad = lane >> 4, lr = lane & 15;
    const int b = blockIdx.y;
    const int s0 = blockIdx.x * 64;
    const bf16s* p1b = P1 + (size_t)b * 128 * 512;
    const bf16s* p2b = P2 + (size_t)b * 128 * 512;

    f32x4 accre[8], accim[8];
#pragma unroll
    for (int j = 0; j < 8; j++) {
        accre[j] = (f32x4){0.f, 0.f, 0.f, 0.f};
        accim[j] = (f32x4){0.f, 0.f, 0.f, 0.f};
    }

    auto stage = [&](int buf, int kt) {
#pragma unroll
        for (int j = 0; j < 2; j++) {
            int ch = j * 256 + tid;
            int row = ch >> 2, kc = (ch & 3) * 8;
            __builtin_amdgcn_global_load_lds(
                (AS1 const void*)(p1b + (size_t)row * 512 + kt + kc),
                (AS3 void*)(Bs1[buf] + (size_t)(j * 256 + wave * 64) * 8), 16, 0, 0);
            __builtin_amdgcn_global_load_lds(
                (AS1 const void*)(p2b + (size_t)row * 512 + kt + kc),
                (AS3 void*)(Bs2[buf] + (size_t)(j * 256 + wave * 64) * 8), 16, 0, 0);
        }
    };
    auto compute = [&](int buf) {
        bf16x8 afr = *(const bf16x8*)(Bs1[buf] + (s0 + wave * 16 + lr) * 32 + quad * 8);
#pragma unroll
        for (int j = 0; j < 8; j++) {
            bf16x8 b1 = *(const bf16x8*)(Bs1[buf] + (j * 16 + lr) * 32 + quad * 8);
            accre[j] = __builtin_amdgcn_mfma_f32_16x16x32_bf16(afr, b1, accre[j], 0, 0, 0);
            bf16x8 b2 = *(const bf16x8*)(Bs2[buf] + (j * 16 + lr) * 32 + quad * 8);
            accim[j] = __builtin_amdgcn_mfma_f32_16x16x32_bf16(afr, b2, accim[j], 0, 0, 0);
        }
    };

    const int nt = 16;   // K=512
    stage(0, 0);
    stage(1, 1 << 5);
    int cur = 0, nxt = 2;
    for (int t = 0; t < nt; t++) {
        if (t + 2 < nt) { stage(nxt, (t + 2) << 5); PIPE_WAIT(8); }
        else if (t + 1 < nt) PIPE_WAIT(4);
        else PIPE_WAIT(0);
        compute(cur);
        PIPE_BAR();
        cur = (cur == 2) ? 0 : cur + 1;
        nxt = (nxt == 2) ? 0 : nxt + 1;
    }

    const float isq = 0.35355339059327373f;
    float ph_r[4], ph_c[8];
#pragma unroll
    for (int r = 0; r < 4; r++) ph_r[r] = phi[s0 + wave * 16 + quad * 4 + r];
#pragma unroll
    for (int j = 0; j < 8; j++) ph_c[j] = phi[j * 16 + lr];

#pragma unroll
    for (int r = 0; r < 4; r++) {
        float v[8];
        float mx = -1e30f;
#pragma unroll
        for (int j = 0; j < 8; j++) {
            float re = accre[j][r], im = accim[j][r];
            v[j] = (re * re + im * im) * isq + __cosf(ph_c[j] - ph_r[r]);
            mx = fmaxf(mx, v[j]);
        }
#pragma unroll
        for (int off = 1; off <= 8; off <<= 1) mx = fmaxf(mx, __shfl_xor(mx, off, 64));
        float sm = 0.f;
#pragma unroll
        for (int j = 0; j < 8; j++) { v[j] = __expf(v[j] - mx); sm += v[j]; }
#pragma unroll
        for (int off = 1; off <= 8; off <<= 1) sm += __shfl_xor(sm, off, 64);
        float inv = 1.f / sm;
        int srow = b * 128 + s0 + wave * 16 + quad * 4 + r;
#pragma unroll
        for (int j = 0; j < 8; j++) {
            float o = v[j] * inv;
            attn[(size_t)srow * 128 + j * 16 + lr] = o;
            attn_bf[(size_t)srow * 128 + j * 16 + lr] = f2bf(o);
        }
    }
}

// ---------------------------------------------------------------------------
extern "C" void kernel_launch(void* const* d_in, const int* in_sizes, int n_in,
                              void* d_out, int out_size, void* d_ws, size_t ws_size,
                              hipStream_t stream) {
    const float* X     = (const float*)d_in[0];
    const float* Wi    = (const float*)d_in[1];
    const float* bi    = (const float*)d_in[2];
    const float* Wv    = (const float*)d_in[3];
    const float* bv    = (const float*)d_in[4];
    const float* Wo    = (const float*)d_in[5];
    const float* bo    = (const float*)d_in[6];
    const float* theta = (const float*)d_in[7];
    const float* phi   = (const float*)d_in[8];

    float* y    = (float*)d_out;
    float* attn = y + (size_t)MM * EE;

    bf16s* Xb   = (bf16s*)d_ws;                      // 16384*1024
    bf16s* P1   = Xb  + (size_t)MM * EE;             // 16384*512
    bf16s* P2   = P1  + (size_t)MM * 512;            // 16384*512
    bf16s* Vwtb = P2  + (size_t)MM * 512;            // 128 * 1024*128 (V@Wo)^T
    bf16s* scr  = Vwtb + (size_t)MM * EE;            // scratch region
    bf16s* abf  = scr + (size_t)MM * EE;             // 128*128*128
    bf16s* Wvb  = abf + (size_t)BB * SS * SS;        // 1024*1024 bf16(Wv)
    bf16s* Wot  = Wvb + (size_t)EE * EE;             // 1024*1024 Wo^T
    float* Wit  = (float*)(Wot + (size_t)EE * EE);   // 8*1024 fp32
    float* bvo  = Wit + 8 * 1024;                    // 1024 fp32
    float* bvop = bvo + 1024;                        // 16*1024 fp32 partials
    bf16s* v    = scr;                               // 16384*256
    bf16s* Ubt  = scr + (size_t)MM * DD;             // 512*256
    bf16s* Wvot = scr + (size_t)MM * DD + 512 * DD;  // 1024*1024 (Wv@Wo)^T

    wtrans_kernel<<<32, 256, 0, stream>>>(Wi, Wit);
    encode_kernel<<<MM / 4, 256, 0, stream>>>(X, Wit, bi, Xb, v);
    ubuild_kernel<<<64, 256, 0, stream>>>(theta, Ubt);
    transpose_conv_kernel<<<dim3(32, 32), 256, 0, stream>>>(Wo, Wot, EE, EE);
    cvt_kernel<<<1024, 256, 0, stream>>>(Wv, Wvb);
    bvo_part_kernel<<<256, 256, 0, stream>>>(bv, Wo, bvop);
    bvo_reduce_kernel<<<4, 256, 0, stream>>>(bvop, bo, bvo);
    // Wvot[a][b] = (Wv@Wo)[b][a] :  A=Wot, Bt=Wvb  (M=N=K=1024)
    mfma_gemm<true><<<64, 256, 0, stream>>>(
        Wot, Wvb, nullptr, Wvot, EE, EE, EE, /*nm*/8, /*nn*/8, 0, 0, 0);
    // psi = v @ Ubt^T -> P1, P2
    psi_gemm_kernel<<<dim3(MM / 128, 4), 256, 0, stream>>>(v, Ubt, P1, P2);
    // Vwt_b = Wvot @ Xb_b^T
    mfma_gemm<true><<<1024, 256, 0, stream>>>(
        Wvot, Xb, nullptr, Vwtb, EE, SS, EE, /*nm*/8, /*nn*/1,
        0, (long long)SS * EE, (long long)EE * SS);
    // attn (Gram via MFMA + softmax)
    attn_kernel<<<dim3(2, BB), 256, 0, stream>>>(P1, P2, phi, attn, abf);
    // y_b = attn_b @ Vw_b + bvo
    mfma_gemm<false><<<1024, 256, 0, stream>>>(
        abf, Vwtb, bvo, y, SS, EE, SS, /*nm*/1, /*nn*/8,
        (long long)SS * SS, (long long)EE * SS, (long long)SS * EE);
}

// Round 9
// 274.074 us; speedup vs baseline: 1.3993x; 1.1305x over previous
//
#include <hip/hip_runtime.h>
#include <hip/hip_bf16.h>

#define BB 128
#define SS 128
#define EE 1024
#define NQ 8
#define DD 256
#define LL 4
#define MM (BB*SS)

typedef unsigned short bf16s;
typedef __attribute__((ext_vector_type(8))) short bf16x8;
typedef __attribute__((ext_vector_type(4))) float f32x4;

#define AS1 __attribute__((address_space(1)))
#define AS3 __attribute__((address_space(3)))

__device__ __forceinline__ unsigned short f2bf(float x) {
    unsigned u = __float_as_uint(x);
    u += 0x7fffu + ((u >> 16) & 1u);
    return (unsigned short)(u >> 16);
}

// pipeline helpers: counted vmcnt (T4) + raw barrier, sched fences (#18)
#define PIPE_WAIT(N) do { \
    asm volatile("s_waitcnt vmcnt(" #N ")" ::: "memory"); \
    __builtin_amdgcn_sched_barrier(0); \
    __builtin_amdgcn_s_barrier(); \
    __builtin_amdgcn_sched_barrier(0); } while (0)
#define PIPE_BAR() do { \
    __builtin_amdgcn_sched_barrier(0); \
    __builtin_amdgcn_s_barrier(); } while (0)

// ---------------------------------------------------------------------------
// fp32 RxC -> bf16 CxR transpose-convert (weights)
// ---------------------------------------------------------------------------
__global__ __launch_bounds__(256) void transpose_conv_kernel(
    const float* __restrict__ in, bf16s* __restrict__ out, int R, int C)
{
    __shared__ float t[32][33];
    int bx = blockIdx.x * 32, by = blockIdx.y * 32;
    int lx = threadIdx.x & 31, ly = threadIdx.x >> 5;
#pragma unroll
    for (int i = 0; i < 32; i += 8)
        t[ly + i][lx] = in[(size_t)(by + ly + i) * C + bx + lx];
    __syncthreads();
#pragma unroll
    for (int i = 0; i < 32; i += 8)
        out[(size_t)(bx + ly + i) * R + by + lx] = f2bf(t[lx][ly + i]);
}

// ---------------------------------------------------------------------------
// fp32 -> bf16 straight convert (Wv), float4 vectorized
// ---------------------------------------------------------------------------
__global__ __launch_bounds__(256) void cvt_kernel(
    const float* __restrict__ in, bf16s* __restrict__ out)
{
    int g = blockIdx.x * 256 + threadIdx.x;      // float4 index
    f32x4 x = ((const f32x4*)in)[g];
    ushort4 o;
    o.x = f2bf(x[0]); o.y = f2bf(x[1]); o.z = f2bf(x[2]); o.w = f2bf(x[3]);
    ((ushort4*)out)[g] = o;
}

// ---------------------------------------------------------------------------
// bvo = bv@Wo + bo, two parallel stages.
// ---------------------------------------------------------------------------
__global__ __launch_bounds__(256) void bvo_part_kernel(
    const float* __restrict__ bv, const float* __restrict__ Wo,
    float* __restrict__ part)
{
    __shared__ float red[4][64];
    int lane = threadIdx.x & 63, w = threadIdx.x >> 6;
    int eb = blockIdx.x & 15, kb = blockIdx.x >> 4;
    int e = eb * 64 + lane;
    int k0 = kb * 64 + w * 16;
    float acc = 0.f;
#pragma unroll
    for (int i = 0; i < 16; i++)
        acc += bv[k0 + i] * Wo[(size_t)(k0 + i) * EE + e];
    red[w][lane] = acc;
    __syncthreads();
    if (w == 0)
        part[kb * EE + e] = red[0][lane] + red[1][lane] + red[2][lane] + red[3][lane];
}

__global__ __launch_bounds__(256) void bvo_reduce_kernel(
    const float* __restrict__ part, const float* __restrict__ bo,
    float* __restrict__ bvo)
{
    int e = blockIdx.x * 256 + threadIdx.x;
    float s = bo[e];
#pragma unroll
    for (int kb = 0; kb < 16; kb++) s += part[kb * EE + e];
    bvo[e] = s;
}

// ---------------------------------------------------------------------------
// Wi[1024][8] -> Wit[8][1024] fp32
// ---------------------------------------------------------------------------
__global__ __launch_bounds__(256) void wtrans_kernel(
    const float* __restrict__ Wi, float* __restrict__ Wit)
{
    int g = blockIdx.x * 256 + threadIdx.x;   // 0..8191
    int k = g >> 3, j = g & 7;
    Wit[j * 1024 + k] = Wi[g];
}

// ---------------------------------------------------------------------------
// encode: qin = X@Wi+bi; product state v (bf16); Xb = bf16(X) side-product.
// ---------------------------------------------------------------------------
__global__ __launch_bounds__(256) void encode_kernel(
    const float* __restrict__ X, const float* __restrict__ Wit,
    const float* __restrict__ bi,
    bf16s* __restrict__ Xb, bf16s* __restrict__ v)
{
    const int lane = threadIdx.x & 63;
    const int wid  = threadIdx.x >> 6;
    const int row  = blockIdx.x * 4 + wid;

    const f32x4* xr4 = (const f32x4*)(X + (size_t)row * EE);
    ushort4* xbr4 = (ushort4*)(Xb + (size_t)row * EE);

    float acc[NQ];
#pragma unroll
    for (int j = 0; j < NQ; j++) acc[j] = 0.f;

#pragma unroll
    for (int t = 0; t < 4; t++) {
        int k4 = t * 64 + lane;
        f32x4 x = xr4[k4];
        ushort4 xb;
        xb.x = f2bf(x[0]); xb.y = f2bf(x[1]);
        xb.z = f2bf(x[2]); xb.w = f2bf(x[3]);
        xbr4[k4] = xb;
#pragma unroll
        for (int j = 0; j < NQ; j++) {
            f32x4 w = ((const f32x4*)(Wit + j * 1024))[k4];
            acc[j] += x[0]*w[0] + x[1]*w[1] + x[2]*w[2] + x[3]*w[3];
        }
    }
    float qin[NQ];
#pragma unroll
    for (int j = 0; j < NQ; j++) {
        float s = acc[j];
#pragma unroll
        for (int off = 32; off >= 1; off >>= 1) s += __shfl_xor(s, off, 64);
        qin[j] = s + bi[j];
    }

    float cs[NQ], sn[NQ];
#pragma unroll
    for (int q = 0; q < NQ; q++) __sincosf(0.5f * qin[q], &sn[q], &cs[q]);

    float common = 1.f;
#pragma unroll
    for (int b = 2; b < 8; b++) {
        int q = 7 - b;
        common *= ((lane >> (b - 2)) & 1) ? sn[q] : cs[q];
    }
    float a0 = common * cs[6] * cs[7];
    float a1 = common * cs[6] * sn[7];
    float a2 = common * sn[6] * cs[7];
    float a3 = common * sn[6] * sn[7];
    ushort4 vo;
    vo.x = f2bf(a0); vo.y = f2bf(a1); vo.z = f2bf(a2); vo.w = f2bf(a3);
    ((ushort4*)(v + (size_t)row * DD))[lane] = vo;
}

// ---------------------------------------------------------------------------
// MFMA bf16 GEMM: depth-2 (3-buffer) pipeline; bijective XCD chunking.
// Work order: w = (z * nm + m) * nn + n.
// ---------------------------------------------------------------------------
template<bool OUT_BF16>
__global__ __launch_bounds__(256) void mfma_gemm(
    const bf16s* __restrict__ A, const bf16s* __restrict__ Bt,
    const float* __restrict__ bias, void* __restrict__ Cv,
    int M, int N, int K, int nm, int nn,
    long long sA, long long sB, long long sC)
{
    __shared__ bf16s As[3][128 * 32];
    __shared__ bf16s Bs[3][128 * 32];

    const int tid  = threadIdx.x;
    const int wave = tid >> 6, lane = tid & 63;
    const int quad = lane >> 4, lr = lane & 15;
    const int wm = (wave >> 1) * 64, wn = (wave & 1) * 64;

    const int nwg = gridDim.x;
    const int q = nwg >> 3, r = nwg & 7;
    const int xcd = blockIdx.x & 7, idx = blockIdx.x >> 3;
    const int w = (xcd < r ? xcd * (q + 1) : r * (q + 1) + (xcd - r) * q) + idx;
    const int n_t = w % nn;
    const int m_t = (w / nn) % nm;
    const int z   = w / (nn * nm);
    const int m0 = m_t * 128, n0 = n_t * 128;

    A  += (size_t)z * sA;
    Bt += (size_t)z * sB;

    f32x4 acc[4][4];
#pragma unroll
    for (int i = 0; i < 4; i++)
#pragma unroll
        for (int j = 0; j < 4; j++) acc[i][j] = (f32x4){0.f, 0.f, 0.f, 0.f};

    auto stage = [&](int buf, int kt) {
#pragma unroll
        for (int j = 0; j < 2; j++) {
            int ch = j * 256 + tid;
            int row = ch >> 2, kc = (ch & 3) * 8;
            __builtin_amdgcn_global_load_lds(
                (AS1 const void*)(A + (size_t)(m0 + row) * K + kt + kc),
                (AS3 void*)(As[buf] + (size_t)(j * 256 + wave * 64) * 8), 16, 0, 0);
            __builtin_amdgcn_global_load_lds(
                (AS1 const void*)(Bt + (size_t)(n0 + row) * K + kt + kc),
                (AS3 void*)(Bs[buf] + (size_t)(j * 256 + wave * 64) * 8), 16, 0, 0);
        }
    };
    auto compute = [&](int buf) {
        bf16x8 af[4], bfr[4];
#pragma unroll
        for (int i = 0; i < 4; i++)
            af[i] = *(const bf16x8*)(As[buf] + (wm + i * 16 + lr) * 32 + quad * 8);
#pragma unroll
        for (int j = 0; j < 4; j++)
            bfr[j] = *(const bf16x8*)(Bs[buf] + (wn + j * 16 + lr) * 32 + quad * 8);
#pragma unroll
        for (int i = 0; i < 4; i++)
#pragma unroll
            for (int j = 0; j < 4; j++)
                acc[i][j] = __builtin_amdgcn_mfma_f32_16x16x32_bf16(
                    af[i], bfr[j], acc[i][j], 0, 0, 0);
    };

    const int nt = K >> 5;   // all call sites: >= 4
    stage(0, 0);
    stage(1, 1 << 5);
    int cur = 0, nxt = 2;
    for (int t = 0; t < nt; t++) {
        if (t + 2 < nt) { stage(nxt, (t + 2) << 5); PIPE_WAIT(8); }
        else if (t + 1 < nt) PIPE_WAIT(4);
        else PIPE_WAIT(0);
        compute(cur);
        PIPE_BAR();
        cur = (cur == 2) ? 0 : cur + 1;
        nxt = (nxt == 2) ? 0 : nxt + 1;
    }

    float* Cf = (float*)Cv + (size_t)z * sC;
    bf16s* Cb = (bf16s*)Cv + (size_t)z * sC;
#pragma unroll
    for (int i = 0; i < 4; i++) {
        int row0 = m0 + wm + i * 16 + quad * 4;
#pragma unroll
        for (int j = 0; j < 4; j++) {
            int col = n0 + wn + j * 16 + lr;
            float bb = bias ? bias[col] : 0.f;
#pragma unroll
            for (int r = 0; r < 4; r++) {
                float v = acc[i][j][r] + bb;
                if (OUT_BF16) Cb[(size_t)(row0 + r) * N + col] = f2bf(v);
                else          Cf[(size_t)(row0 + r) * N + col] = v;
            }
        }
    }
}

// ---------------------------------------------------------------------------
// attn: G[s,t] = v_s . v_t (REAL — the circuit unitary cancels in the Gram:
// psi = U q  =>  G = q^T (U^T U^*) q = q . q since U^T U^* = I).
// K = G^2/sqrt(8) + cos(phi_t - phi_s); fused softmax. Depth-2 pipeline,
// K-dim = 256 over the real product-state matrix v (one LDS buffer stream).
// ---------------------------------------------------------------------------
__global__ __launch_bounds__(256) void attn_kernel(
    const bf16s* __restrict__ v, const float* __restrict__ phi,
    float* __restrict__ attn, bf16s* __restrict__ attn_bf)
{
    __shared__ bf16s Bs[3][128 * 32];

    const int tid  = threadIdx.x;
    const int wave = tid >> 6, lane = tid & 63;
    const int quad = lane >> 4, lr = lane & 15;
    const int b = blockIdx.y;
    const int s0 = blockIdx.x * 64;
    const bf16s* vb = v + (size_t)b * 128 * DD;

    f32x4 accre[8];
#pragma unroll
    for (int j = 0; j < 8; j++) accre[j] = (f32x4){0.f, 0.f, 0.f, 0.f};

    // stage one 128x32 K-slice of v_b (2 global_load_lds per thread)
    auto stage = [&](int buf, int kt) {
#pragma unroll
        for (int j = 0; j < 2; j++) {
            int ch = j * 256 + tid;
            int row = ch >> 2, kc = (ch & 3) * 8;
            __builtin_amdgcn_global_load_lds(
                (AS1 const void*)(vb + (size_t)row * DD + kt + kc),
                (AS3 void*)(Bs[buf] + (size_t)(j * 256 + wave * 64) * 8), 16, 0, 0);
        }
    };
    auto compute = [&](int buf) {
        bf16x8 afr = *(const bf16x8*)(Bs[buf] + (s0 + wave * 16 + lr) * 32 + quad * 8);
#pragma unroll
        for (int j = 0; j < 8; j++) {
            bf16x8 b1 = *(const bf16x8*)(Bs[buf] + (j * 16 + lr) * 32 + quad * 8);
            accre[j] = __builtin_amdgcn_mfma_f32_16x16x32_bf16(afr, b1, accre[j], 0, 0, 0);
        }
    };

    const int nt = DD >> 5;   // 8
    stage(0, 0);
    stage(1, 1 << 5);
    int cur = 0, nxt = 2;
    for (int t = 0; t < nt; t++) {
        if (t + 2 < nt) { stage(nxt, (t + 2) << 5); PIPE_WAIT(4); }
        else if (t + 1 < nt) PIPE_WAIT(2);
        else PIPE_WAIT(0);
        compute(cur);
        PIPE_BAR();
        cur = (cur == 2) ? 0 : cur + 1;
        nxt = (nxt == 2) ? 0 : nxt + 1;
    }

    const float isq = 0.35355339059327373f;   // 1/sqrt(8)
    float ph_r[4], ph_c[8];
#pragma unroll
    for (int r = 0; r < 4; r++) ph_r[r] = phi[s0 + wave * 16 + quad * 4 + r];
#pragma unroll
    for (int j = 0; j < 8; j++) ph_c[j] = phi[j * 16 + lr];

#pragma unroll
    for (int r = 0; r < 4; r++) {
        float vv[8];
        float mx = -1e30f;
#pragma unroll
        for (int j = 0; j < 8; j++) {
            float re = accre[j][r];
            vv[j] = re * re * isq + __cosf(ph_c[j] - ph_r[r]);
            mx = fmaxf(mx, vv[j]);
        }
#pragma unroll
        for (int off = 1; off <= 8; off <<= 1) mx = fmaxf(mx, __shfl_xor(mx, off, 64));
        float sm = 0.f;
#pragma unroll
        for (int j = 0; j < 8; j++) { vv[j] = __expf(vv[j] - mx); sm += vv[j]; }
#pragma unroll
        for (int off = 1; off <= 8; off <<= 1) sm += __shfl_xor(sm, off, 64);
        float inv = 1.f / sm;
        int srow = b * 128 + s0 + wave * 16 + quad * 4 + r;
#pragma unroll
        for (int j = 0; j < 8; j++) {
            float o = vv[j] * inv;
            attn[(size_t)srow * 128 + j * 16 + lr] = o;
            attn_bf[(size_t)srow * 128 + j * 16 + lr] = f2bf(o);
        }
    }
}

// ---------------------------------------------------------------------------
extern "C" void kernel_launch(void* const* d_in, const int* in_sizes, int n_in,
                              void* d_out, int out_size, void* d_ws, size_t ws_size,
                              hipStream_t stream) {
    const float* X     = (const float*)d_in[0];
    const float* Wi    = (const float*)d_in[1];
    const float* bi    = (const float*)d_in[2];
    const float* Wv    = (const float*)d_in[3];
    const float* bv    = (const float*)d_in[4];
    const float* Wo    = (const float*)d_in[5];
    const float* bo    = (const float*)d_in[6];
    const float* phi   = (const float*)d_in[8];

    float* y    = (float*)d_out;
    float* attn = y + (size_t)MM * EE;

    bf16s* Xb   = (bf16s*)d_ws;                      // 16384*1024
    bf16s* Vwtb = Xb  + (size_t)MM * EE;             // 128 * 1024*128 (V@Wo)^T
    bf16s* v    = Vwtb + (size_t)MM * EE;            // 16384*256 product states
    bf16s* abf  = v   + (size_t)MM * DD;             // 128*128*128
    bf16s* Wvb  = abf + (size_t)BB * SS * SS;        // 1024*1024 bf16(Wv)
    bf16s* Wot  = Wvb + (size_t)EE * EE;             // 1024*1024 Wo^T
    bf16s* Wvot = Wot + (size_t)EE * EE;             // 1024*1024 (Wv@Wo)^T
    float* Wit  = (float*)(Wvot + (size_t)EE * EE);  // 8*1024 fp32
    float* bvo  = Wit + 8 * 1024;                    // 1024 fp32
    float* bvop = bvo + 1024;                        // 16*1024 fp32 partials

    wtrans_kernel<<<32, 256, 0, stream>>>(Wi, Wit);
    encode_kernel<<<MM / 4, 256, 0, stream>>>(X, Wit, bi, Xb, v);
    transpose_conv_kernel<<<dim3(32, 32), 256, 0, stream>>>(Wo, Wot, EE, EE);
    cvt_kernel<<<1024, 256, 0, stream>>>(Wv, Wvb);
    bvo_part_kernel<<<256, 256, 0, stream>>>(bv, Wo, bvop);
    bvo_reduce_kernel<<<4, 256, 0, stream>>>(bvop, bo, bvo);
    // Wvot[a][b] = (Wv@Wo)[b][a] :  A=Wot, Bt=Wvb  (M=N=K=1024)
    mfma_gemm<true><<<64, 256, 0, stream>>>(
        Wot, Wvb, nullptr, Wvot, EE, EE, EE, /*nm*/8, /*nn*/8, 0, 0, 0);
    // attn: real Gram of v + phase term + softmax (unitary cancels)
    attn_kernel<<<dim3(2, BB), 256, 0, stream>>>(v, phi, attn, abf);
    // Vwt_b = Wvot @ Xb_b^T
    mfma_gemm<true><<<1024, 256, 0, stream>>>(
        Wvot, Xb, nullptr, Vwtb, EE, SS, EE, /*nm*/8, /*nn*/1,
        0, (long long)SS * EE, (long long)EE * SS);
    // y_b = attn_b @ Vw_b + bvo
    mfma_gemm<false><<<1024, 256, 0, stream>>>(
        abf, Vwtb, bvo, y, SS, EE, SS, /*nm*/1, /*nn*/8,
        (long long)SS * SS, (long long)EE * SS, (long long)SS * EE);
}

// Round 10
// 257.044 us; speedup vs baseline: 1.4920x; 1.0663x over previous
//
#include <hip/hip_runtime.h>
#include <hip/hip_bf16.h>

#define BB 128
#define SS 128
#define EE 1024
#define NQ 8
#define DD 256
#define LL 4
#define MM (BB*SS)

typedef unsigned short bf16s;
typedef __attribute__((ext_vector_type(8))) short bf16x8;
typedef __attribute__((ext_vector_type(4))) float f32x4;

#define AS1 __attribute__((address_space(1)))
#define AS3 __attribute__((address_space(3)))

__device__ __forceinline__ unsigned short f2bf(float x) {
    unsigned u = __float_as_uint(x);
    u += 0x7fffu + ((u >> 16) & 1u);
    return (unsigned short)(u >> 16);
}

// pipeline helpers: counted vmcnt (T4) + raw barrier, sched fences (#18)
#define PIPE_WAIT(N) do { \
    asm volatile("s_waitcnt vmcnt(" #N ")" ::: "memory"); \
    __builtin_amdgcn_sched_barrier(0); \
    __builtin_amdgcn_s_barrier(); \
    __builtin_amdgcn_sched_barrier(0); } while (0)
#define PIPE_BAR() do { \
    __builtin_amdgcn_sched_barrier(0); \
    __builtin_amdgcn_s_barrier(); } while (0)

// ---------------------------------------------------------------------------
// fp32 RxC -> bf16 CxR transpose-convert (weights)
// ---------------------------------------------------------------------------
__global__ __launch_bounds__(256) void transpose_conv_kernel(
    const float* __restrict__ in, bf16s* __restrict__ out, int R, int C)
{
    __shared__ float t[32][33];
    int bx = blockIdx.x * 32, by = blockIdx.y * 32;
    int lx = threadIdx.x & 31, ly = threadIdx.x >> 5;
#pragma unroll
    for (int i = 0; i < 32; i += 8)
        t[ly + i][lx] = in[(size_t)(by + ly + i) * C + bx + lx];
    __syncthreads();
#pragma unroll
    for (int i = 0; i < 32; i += 8)
        out[(size_t)(bx + ly + i) * R + by + lx] = f2bf(t[lx][ly + i]);
}

// ---------------------------------------------------------------------------
// fp32 -> bf16 straight convert (Wv), float4 vectorized
// ---------------------------------------------------------------------------
__global__ __launch_bounds__(256) void cvt_kernel(
    const float* __restrict__ in, bf16s* __restrict__ out)
{
    int g = blockIdx.x * 256 + threadIdx.x;      // float4 index
    f32x4 x = ((const f32x4*)in)[g];
    ushort4 o;
    o.x = f2bf(x[0]); o.y = f2bf(x[1]); o.z = f2bf(x[2]); o.w = f2bf(x[3]);
    ((ushort4*)out)[g] = o;
}

// ---------------------------------------------------------------------------
// bvo = bv@Wo + bo, two parallel stages.
// ---------------------------------------------------------------------------
__global__ __launch_bounds__(256) void bvo_part_kernel(
    const float* __restrict__ bv, const float* __restrict__ Wo,
    float* __restrict__ part)
{
    __shared__ float red[4][64];
    int lane = threadIdx.x & 63, w = threadIdx.x >> 6;
    int eb = blockIdx.x & 15, kb = blockIdx.x >> 4;
    int e = eb * 64 + lane;
    int k0 = kb * 64 + w * 16;
    float acc = 0.f;
#pragma unroll
    for (int i = 0; i < 16; i++)
        acc += bv[k0 + i] * Wo[(size_t)(k0 + i) * EE + e];
    red[w][lane] = acc;
    __syncthreads();
    if (w == 0)
        part[kb * EE + e] = red[0][lane] + red[1][lane] + red[2][lane] + red[3][lane];
}

__global__ __launch_bounds__(256) void bvo_reduce_kernel(
    const float* __restrict__ part, const float* __restrict__ bo,
    float* __restrict__ bvo)
{
    int e = blockIdx.x * 256 + threadIdx.x;
    float s = bo[e];
#pragma unroll
    for (int kb = 0; kb < 16; kb++) s += part[kb * EE + e];
    bvo[e] = s;
}

// ---------------------------------------------------------------------------
// Wi[1024][8] -> Wit[8][1024] fp32
// ---------------------------------------------------------------------------
__global__ __launch_bounds__(256) void wtrans_kernel(
    const float* __restrict__ Wi, float* __restrict__ Wit)
{
    int g = blockIdx.x * 256 + threadIdx.x;   // 0..8191
    int k = g >> 3, j = g & 7;
    Wit[j * 1024 + k] = Wi[g];
}

// ---------------------------------------------------------------------------
// encode: qin = X@Wi+bi; product state v (bf16); Xb = bf16(X) side-product.
// ---------------------------------------------------------------------------
__global__ __launch_bounds__(256) void encode_kernel(
    const float* __restrict__ X, const float* __restrict__ Wit,
    const float* __restrict__ bi,
    bf16s* __restrict__ Xb, bf16s* __restrict__ v)
{
    const int lane = threadIdx.x & 63;
    const int wid  = threadIdx.x >> 6;
    const int row  = blockIdx.x * 4 + wid;

    const f32x4* xr4 = (const f32x4*)(X + (size_t)row * EE);
    ushort4* xbr4 = (ushort4*)(Xb + (size_t)row * EE);

    float acc[NQ];
#pragma unroll
    for (int j = 0; j < NQ; j++) acc[j] = 0.f;

#pragma unroll
    for (int t = 0; t < 4; t++) {
        int k4 = t * 64 + lane;
        f32x4 x = xr4[k4];
        ushort4 xb;
        xb.x = f2bf(x[0]); xb.y = f2bf(x[1]);
        xb.z = f2bf(x[2]); xb.w = f2bf(x[3]);
        xbr4[k4] = xb;
#pragma unroll
        for (int j = 0; j < NQ; j++) {
            f32x4 w = ((const f32x4*)(Wit + j * 1024))[k4];
            acc[j] += x[0]*w[0] + x[1]*w[1] + x[2]*w[2] + x[3]*w[3];
        }
    }
    float qin[NQ];
#pragma unroll
    for (int j = 0; j < NQ; j++) {
        float s = acc[j];
#pragma unroll
        for (int off = 32; off >= 1; off >>= 1) s += __shfl_xor(s, off, 64);
        qin[j] = s + bi[j];
    }

    float cs[NQ], sn[NQ];
#pragma unroll
    for (int q = 0; q < NQ; q++) __sincosf(0.5f * qin[q], &sn[q], &cs[q]);

    float common = 1.f;
#pragma unroll
    for (int b = 2; b < 8; b++) {
        int q = 7 - b;
        common *= ((lane >> (b - 2)) & 1) ? sn[q] : cs[q];
    }
    float a0 = common * cs[6] * cs[7];
    float a1 = common * cs[6] * sn[7];
    float a2 = common * sn[6] * cs[7];
    float a3 = common * sn[6] * sn[7];
    ushort4 vo;
    vo.x = f2bf(a0); vo.y = f2bf(a1); vo.z = f2bf(a2); vo.w = f2bf(a3);
    ((ushort4*)(v + (size_t)row * DD))[lane] = vo;
}

// ---------------------------------------------------------------------------
// gemm256: C[M][N] = A[M][K] @ Bt[N][K]^T, bf16 out. 256x256 tile, 512 thr
// (8 waves 2Mx4N, wave tile 128x64), BK=32, 4 LDS K-slots (128 KB dynamic),
// ONE barrier + counted vmcnt(4) per K-tile, prefetch distance 2.
// Slot safety: stage kt+2 -> slot (kt+2)&3 != read slot kt&3; previous
// readers of that slot (tile kt-2) are >=2 barriers upstream.
// T2 swizzle: involution c16 ^= row&3 applied on the pre-swizzled GLOBAL
// source (linear LDS dest, rule #21) and on the ds_read address.
// ---------------------------------------------------------------------------
__global__ __launch_bounds__(512) void gemm256_kernel(
    const bf16s* __restrict__ A, const bf16s* __restrict__ Bt,
    bf16s* __restrict__ C, int M, int N, int K, int nm, int nn)
{
    extern __shared__ bf16s lds[];
    bf16s* As = lds;               // 4 slots x 8192 el (256 rows x 32 k)
    bf16s* Bs = lds + 4 * 8192;    // 4 slots x 8192 el

    const int tid  = threadIdx.x;
    const int lane = tid & 63;
    const int wid  = tid >> 6;
    const int quad = lane >> 4, lr = lane & 15;
    const int wr = wid >> 2, wc = wid & 3;   // 2x4 wave grid

    // bijective XCD chunk swizzle
    const int nwg = gridDim.x;
    const int q = nwg >> 3, r = nwg & 7;
    const int xcd = blockIdx.x & 7, idx = blockIdx.x >> 3;
    const int w = (xcd < r ? xcd * (q + 1) : r * (q + 1) + (xcd - r) * q) + idx;
    const int n_t = w % nn, m_t = w / nn;
    const int m0 = m_t * 256, n0 = n_t * 256;

    f32x4 acc[8][4];
#pragma unroll
    for (int i = 0; i < 8; i++)
#pragma unroll
        for (int j = 0; j < 4; j++) acc[i][j] = (f32x4){0.f, 0.f, 0.f, 0.f};

    // stage one 256x32 K-tile of A and B into slot (4 loads/thread total)
    auto stage = [&](int slot, int kt) {
#pragma unroll
        for (int l = 0; l < 2; l++) {
            int ch = l * 512 + tid;                       // 16B chunk id
            int row = ch >> 2;
            int kc = ((ch & 3) ^ (row & 3)) * 8;          // inverse-swizzled src
            __builtin_amdgcn_global_load_lds(
                (AS1 const void*)(A + (size_t)(m0 + row) * K + kt * 32 + kc),
                (AS3 void*)(As + slot * 8192 + ch * 8), 16, 0, 0);
        }
#pragma unroll
        for (int l = 0; l < 2; l++) {
            int ch = l * 512 + tid;
            int row = ch >> 2;
            int kc = ((ch & 3) ^ (row & 3)) * 8;
            __builtin_amdgcn_global_load_lds(
                (AS1 const void*)(Bt + (size_t)(n0 + row) * K + kt * 32 + kc),
                (AS3 void*)(Bs + slot * 8192 + ch * 8), 16, 0, 0);
        }
    };
    // one K-tile of MFMA: 8 fm x 4 fn, swizzled ds_read (12 x b128 per lane)
    auto compute = [&](int slot) {
        bf16x8 af[8];
#pragma unroll
        for (int i = 0; i < 8; i++) {
            int rowl = wr * 128 + i * 16 + lr;
            af[i] = *(const bf16x8*)(As + slot * 8192 + rowl * 32
                                     + ((quad ^ (rowl & 3)) * 8));
        }
#pragma unroll
        for (int j = 0; j < 4; j++) {
            int rowl = wc * 64 + j * 16 + lr;
            bf16x8 bfr = *(const bf16x8*)(Bs + slot * 8192 + rowl * 32
                                          + ((quad ^ (rowl & 3)) * 8));
#pragma unroll
            for (int i = 0; i < 8; i++)
                acc[i][j] = __builtin_amdgcn_mfma_f32_16x16x32_bf16(
                    af[i], bfr, acc[i][j], 0, 0, 0);
        }
    };

    const int NT = K >> 5;   // 32
    stage(0, 0);
    stage(1, 1);
    for (int kt = 0; kt < NT; kt++) {
        if (kt + 1 < NT) PIPE_WAIT(4);   // tile kt landed; kt+1 in flight
        else             PIPE_WAIT(0);
        if (kt + 2 < NT) stage((kt + 2) & 3, kt + 2);
        compute(kt & 3);
    }

#pragma unroll
    for (int i = 0; i < 8; i++) {
        int row0 = m0 + wr * 128 + i * 16 + quad * 4;
#pragma unroll
        for (int j = 0; j < 4; j++) {
            int col = n0 + wc * 64 + j * 16 + lr;
#pragma unroll
            for (int rr = 0; rr < 4; rr++)
                C[(size_t)(row0 + rr) * N + col] = f2bf(acc[i][j][rr]);
        }
    }
}

// ---------------------------------------------------------------------------
// MFMA bf16 GEMM: depth-2 (3-buffer) pipeline; bijective XCD chunking.
// Work order: w = (z * nm + m) * nn + n.  B row-stride = ldB.
// ---------------------------------------------------------------------------
template<bool OUT_BF16>
__global__ __launch_bounds__(256) void mfma_gemm(
    const bf16s* __restrict__ A, const bf16s* __restrict__ Bt,
    const float* __restrict__ bias, void* __restrict__ Cv,
    int M, int N, int K, int ldB, int nm, int nn,
    long long sA, long long sB, long long sC)
{
    __shared__ bf16s As[3][128 * 32];
    __shared__ bf16s Bs[3][128 * 32];

    const int tid  = threadIdx.x;
    const int wave = tid >> 6, lane = tid & 63;
    const int quad = lane >> 4, lr = lane & 15;
    const int wm = (wave >> 1) * 64, wn = (wave & 1) * 64;

    const int nwg = gridDim.x;
    const int q = nwg >> 3, r = nwg & 7;
    const int xcd = blockIdx.x & 7, idx = blockIdx.x >> 3;
    const int w = (xcd < r ? xcd * (q + 1) : r * (q + 1) + (xcd - r) * q) + idx;
    const int n_t = w % nn;
    const int m_t = (w / nn) % nm;
    const int z   = w / (nn * nm);
    const int m0 = m_t * 128, n0 = n_t * 128;

    A  += (size_t)z * sA;
    Bt += (size_t)z * sB;

    f32x4 acc[4][4];
#pragma unroll
    for (int i = 0; i < 4; i++)
#pragma unroll
        for (int j = 0; j < 4; j++) acc[i][j] = (f32x4){0.f, 0.f, 0.f, 0.f};

    auto stage = [&](int buf, int kt) {
#pragma unroll
        for (int j = 0; j < 2; j++) {
            int ch = j * 256 + tid;
            int row = ch >> 2, kc = (ch & 3) * 8;
            __builtin_amdgcn_global_load_lds(
                (AS1 const void*)(A + (size_t)(m0 + row) * K + kt + kc),
                (AS3 void*)(As[buf] + (size_t)(j * 256 + wave * 64) * 8), 16, 0, 0);
            __builtin_amdgcn_global_load_lds(
                (AS1 const void*)(Bt + (size_t)(n0 + row) * ldB + kt + kc),
                (AS3 void*)(Bs[buf] + (size_t)(j * 256 + wave * 64) * 8), 16, 0, 0);
        }
    };
    auto compute = [&](int buf) {
        bf16x8 af[4], bfr[4];
#pragma unroll
        for (int i = 0; i < 4; i++)
            af[i] = *(const bf16x8*)(As[buf] + (wm + i * 16 + lr) * 32 + quad * 8);
#pragma unroll
        for (int j = 0; j < 4; j++)
            bfr[j] = *(const bf16x8*)(Bs[buf] + (wn + j * 16 + lr) * 32 + quad * 8);
#pragma unroll
        for (int i = 0; i < 4; i++)
#pragma unroll
            for (int j = 0; j < 4; j++)
                acc[i][j] = __builtin_amdgcn_mfma_f32_16x16x32_bf16(
                    af[i], bfr[j], acc[i][j], 0, 0, 0);
    };

    const int nt = K >> 5;
    stage(0, 0);
    stage(1, 1 << 5);
    int cur = 0, nxt = 2;
    for (int t = 0; t < nt; t++) {
        if (t + 2 < nt) { stage(nxt, (t + 2) << 5); PIPE_WAIT(8); }
        else if (t + 1 < nt) PIPE_WAIT(4);
        else PIPE_WAIT(0);
        compute(cur);
        PIPE_BAR();
        cur = (cur == 2) ? 0 : cur + 1;
        nxt = (nxt == 2) ? 0 : nxt + 1;
    }

    float* Cf = (float*)Cv + (size_t)z * sC;
    bf16s* Cb = (bf16s*)Cv + (size_t)z * sC;
#pragma unroll
    for (int i = 0; i < 4; i++) {
        int row0 = m0 + wm + i * 16 + quad * 4;
#pragma unroll
        for (int j = 0; j < 4; j++) {
            int col = n0 + wn + j * 16 + lr;
            float bb = bias ? bias[col] : 0.f;
#pragma unroll
            for (int r = 0; r < 4; r++) {
                float v = acc[i][j][r] + bb;
                if (OUT_BF16) Cb[(size_t)(row0 + r) * N + col] = f2bf(v);
                else          Cf[(size_t)(row0 + r) * N + col] = v;
            }
        }
    }
}

// ---------------------------------------------------------------------------
// attn: G[s,t] = v_s . v_t (real; unitary cancels). K = G^2/sqrt(8) +
// cos(phi_t-phi_s); fused softmax. Depth-2 pipeline over v (K=256).
// ---------------------------------------------------------------------------
__global__ __launch_bounds__(256) void attn_kernel(
    const bf16s* __restrict__ v, const float* __restrict__ phi,
    float* __restrict__ attn, bf16s* __restrict__ attn_bf)
{
    __shared__ bf16s Bs[3][128 * 32];

    const int tid  = threadIdx.x;
    const int wave = tid >> 6, lane = tid & 63;
    const int quad = lane >> 4, lr = lane & 15;
    const int b = blockIdx.y;
    const int s0 = blockIdx.x * 64;
    const bf16s* vb = v + (size_t)b * 128 * DD;

    f32x4 accre[8];
#pragma unroll
    for (int j = 0; j < 8; j++) accre[j] = (f32x4){0.f, 0.f, 0.f, 0.f};

    auto stage = [&](int buf, int kt) {
#pragma unroll
        for (int j = 0; j < 2; j++) {
            int ch = j * 256 + tid;
            int row = ch >> 2, kc = (ch & 3) * 8;
            __builtin_amdgcn_global_load_lds(
                (AS1 const void*)(vb + (size_t)row * DD + kt + kc),
                (AS3 void*)(Bs[buf] + (size_t)(j * 256 + wave * 64) * 8), 16, 0, 0);
        }
    };
    auto compute = [&](int buf) {
        bf16x8 afr = *(const bf16x8*)(Bs[buf] + (s0 + wave * 16 + lr) * 32 + quad * 8);
#pragma unroll
        for (int j = 0; j < 8; j++) {
            bf16x8 b1 = *(const bf16x8*)(Bs[buf] + (j * 16 + lr) * 32 + quad * 8);
            accre[j] = __builtin_amdgcn_mfma_f32_16x16x32_bf16(afr, b1, accre[j], 0, 0, 0);
        }
    };

    const int nt = DD >> 5;   // 8
    stage(0, 0);
    stage(1, 1 << 5);
    int cur = 0, nxt = 2;
    for (int t = 0; t < nt; t++) {
        if (t + 2 < nt) { stage(nxt, (t + 2) << 5); PIPE_WAIT(4); }
        else if (t + 1 < nt) PIPE_WAIT(2);
        else PIPE_WAIT(0);
        compute(cur);
        PIPE_BAR();
        cur = (cur == 2) ? 0 : cur + 1;
        nxt = (nxt == 2) ? 0 : nxt + 1;
    }

    const float isq = 0.35355339059327373f;   // 1/sqrt(8)
    float ph_r[4], ph_c[8];
#pragma unroll
    for (int r = 0; r < 4; r++) ph_r[r] = phi[s0 + wave * 16 + quad * 4 + r];
#pragma unroll
    for (int j = 0; j < 8; j++) ph_c[j] = phi[j * 16 + lr];

#pragma unroll
    for (int r = 0; r < 4; r++) {
        float vv[8];
        float mx = -1e30f;
#pragma unroll
        for (int j = 0; j < 8; j++) {
            float re = accre[j][r];
            vv[j] = re * re * isq + __cosf(ph_c[j] - ph_r[r]);
            mx = fmaxf(mx, vv[j]);
        }
#pragma unroll
        for (int off = 1; off <= 8; off <<= 1) mx = fmaxf(mx, __shfl_xor(mx, off, 64));
        float sm = 0.f;
#pragma unroll
        for (int j = 0; j < 8; j++) { vv[j] = __expf(vv[j] - mx); sm += vv[j]; }
#pragma unroll
        for (int off = 1; off <= 8; off <<= 1) sm += __shfl_xor(sm, off, 64);
        float inv = 1.f / sm;
        int srow = b * 128 + s0 + wave * 16 + quad * 4 + r;
#pragma unroll
        for (int j = 0; j < 8; j++) {
            float o = vv[j] * inv;
            attn[(size_t)srow * 128 + j * 16 + lr] = o;
            attn_bf[(size_t)srow * 128 + j * 16 + lr] = f2bf(o);
        }
    }
}

// ---------------------------------------------------------------------------
extern "C" void kernel_launch(void* const* d_in, const int* in_sizes, int n_in,
                              void* d_out, int out_size, void* d_ws, size_t ws_size,
                              hipStream_t stream) {
    const float* X     = (const float*)d_in[0];
    const float* Wi    = (const float*)d_in[1];
    const float* bi    = (const float*)d_in[2];
    const float* Wv    = (const float*)d_in[3];
    const float* bv    = (const float*)d_in[4];
    const float* Wo    = (const float*)d_in[5];
    const float* bo    = (const float*)d_in[6];
    const float* phi   = (const float*)d_in[8];

    float* y    = (float*)d_out;
    float* attn = y + (size_t)MM * EE;

    bf16s* Xb   = (bf16s*)d_ws;                      // 16384*1024
    bf16s* Vwt  = Xb  + (size_t)MM * EE;             // [1024 e][16384 g] (X@WvWo)^T
    bf16s* v    = Vwt + (size_t)MM * EE;             // 16384*256 product states
    bf16s* abf  = v   + (size_t)MM * DD;             // 128*128*128
    bf16s* Wvb  = abf + (size_t)BB * SS * SS;        // 1024*1024 bf16(Wv)
    bf16s* Wot  = Wvb + (size_t)EE * EE;             // 1024*1024 Wo^T
    bf16s* Wvot = Wot + (size_t)EE * EE;             // 1024*1024 (Wv@Wo)^T
    float* Wit  = (float*)(Wvot + (size_t)EE * EE);  // 8*1024 fp32
    float* bvo  = Wit + 8 * 1024;                    // 1024 fp32
    float* bvop = bvo + 1024;                        // 16*1024 fp32 partials

    wtrans_kernel<<<32, 256, 0, stream>>>(Wi, Wit);
    encode_kernel<<<MM / 4, 256, 0, stream>>>(X, Wit, bi, Xb, v);
    transpose_conv_kernel<<<dim3(32, 32), 256, 0, stream>>>(Wo, Wot, EE, EE);
    cvt_kernel<<<1024, 256, 0, stream>>>(Wv, Wvb);
    bvo_part_kernel<<<256, 256, 0, stream>>>(bv, Wo, bvop);
    bvo_reduce_kernel<<<4, 256, 0, stream>>>(bvop, bo, bvo);
    // Wvot[a][b] = (Wv@Wo)[b][a] :  A=Wot, Bt=Wvb  (M=N=K=1024)
    mfma_gemm<true><<<64, 256, 0, stream>>>(
        Wot, Wvb, nullptr, Wvot, EE, EE, EE, EE, /*nm*/8, /*nn*/8, 0, 0, 0);
    // attn: real Gram of v + phase term + softmax (unitary cancels)
    attn_kernel<<<dim3(2, BB), 256, 0, stream>>>(v, phi, attn, abf);
    // Vwt[e][g] = Wvot[e][:] . Xb[g][:]  — 256^2-tile counted-vmcnt GEMM
    gemm256_kernel<<<256, 512, 128 * 1024, stream>>>(
        Wvot, Xb, Vwt, EE, MM, EE, /*nm*/4, /*nn*/64);
    // y_b = attn_b @ Vw_b + bvo   (B from merged Vwt: ldB=16384, batch off 128)
    mfma_gemm<false><<<1024, 256, 0, stream>>>(
        abf, Vwt, bvo, y, SS, EE, SS, MM, /*nm*/1, /*nn*/8,
        (long long)SS * SS, (long long)SS, (long long)SS * EE);
}

// Round 11
// 251.515 us; speedup vs baseline: 1.5248x; 1.0220x over previous
//
#include <hip/hip_runtime.h>
#include <hip/hip_bf16.h>

#define BB 128
#define SS 128
#define EE 1024
#define NQ 8
#define DD 256
#define LL 4
#define MM (BB*SS)

typedef unsigned short bf16s;
typedef __attribute__((ext_vector_type(8))) short bf16x8;
typedef __attribute__((ext_vector_type(4))) float f32x4;

#define AS1 __attribute__((address_space(1)))
#define AS3 __attribute__((address_space(3)))

__device__ __forceinline__ unsigned short f2bf(float x) {
    unsigned u = __float_as_uint(x);
    u += 0x7fffu + ((u >> 16) & 1u);
    return (unsigned short)(u >> 16);
}

// pipeline helpers: counted vmcnt (T4) + raw barrier, sched fences (#18)
#define PIPE_WAIT(N) do { \
    asm volatile("s_waitcnt vmcnt(" #N ")" ::: "memory"); \
    __builtin_amdgcn_sched_barrier(0); \
    __builtin_amdgcn_s_barrier(); \
    __builtin_amdgcn_sched_barrier(0); } while (0)
#define PIPE_BAR() do { \
    __builtin_amdgcn_sched_barrier(0); \
    __builtin_amdgcn_s_barrier(); } while (0)

// ---------------------------------------------------------------------------
// fp32 RxC -> bf16 CxR transpose-convert (weights)
// ---------------------------------------------------------------------------
__global__ __launch_bounds__(256) void transpose_conv_kernel(
    const float* __restrict__ in, bf16s* __restrict__ out, int R, int C)
{
    __shared__ float t[32][33];
    int bx = blockIdx.x * 32, by = blockIdx.y * 32;
    int lx = threadIdx.x & 31, ly = threadIdx.x >> 5;
#pragma unroll
    for (int i = 0; i < 32; i += 8)
        t[ly + i][lx] = in[(size_t)(by + ly + i) * C + bx + lx];
    __syncthreads();
#pragma unroll
    for (int i = 0; i < 32; i += 8)
        out[(size_t)(bx + ly + i) * R + by + lx] = f2bf(t[lx][ly + i]);
}

// ---------------------------------------------------------------------------
// fp32 -> bf16 straight convert (Wv), float4 vectorized
// ---------------------------------------------------------------------------
__global__ __launch_bounds__(256) void cvt_kernel(
    const float* __restrict__ in, bf16s* __restrict__ out)
{
    int g = blockIdx.x * 256 + threadIdx.x;      // float4 index
    f32x4 x = ((const f32x4*)in)[g];
    ushort4 o;
    o.x = f2bf(x[0]); o.y = f2bf(x[1]); o.z = f2bf(x[2]); o.w = f2bf(x[3]);
    ((ushort4*)out)[g] = o;
}

// ---------------------------------------------------------------------------
// bvo = bv@Wo + bo, two parallel stages.
// ---------------------------------------------------------------------------
__global__ __launch_bounds__(256) void bvo_part_kernel(
    const float* __restrict__ bv, const float* __restrict__ Wo,
    float* __restrict__ part)
{
    __shared__ float red[4][64];
    int lane = threadIdx.x & 63, w = threadIdx.x >> 6;
    int eb = blockIdx.x & 15, kb = blockIdx.x >> 4;
    int e = eb * 64 + lane;
    int k0 = kb * 64 + w * 16;
    float acc = 0.f;
#pragma unroll
    for (int i = 0; i < 16; i++)
        acc += bv[k0 + i] * Wo[(size_t)(k0 + i) * EE + e];
    red[w][lane] = acc;
    __syncthreads();
    if (w == 0)
        part[kb * EE + e] = red[0][lane] + red[1][lane] + red[2][lane] + red[3][lane];
}

__global__ __launch_bounds__(256) void bvo_reduce_kernel(
    const float* __restrict__ part, const float* __restrict__ bo,
    float* __restrict__ bvo)
{
    int e = blockIdx.x * 256 + threadIdx.x;
    float s = bo[e];
#pragma unroll
    for (int kb = 0; kb < 16; kb++) s += part[kb * EE + e];
    bvo[e] = s;
}

// ---------------------------------------------------------------------------
// Wi[1024][8] -> Wit[8][1024] fp32
// ---------------------------------------------------------------------------
__global__ __launch_bounds__(256) void wtrans_kernel(
    const float* __restrict__ Wi, float* __restrict__ Wit)
{
    int g = blockIdx.x * 256 + threadIdx.x;   // 0..8191
    int k = g >> 3, j = g & 7;
    Wit[j * 1024 + k] = Wi[g];
}

// ---------------------------------------------------------------------------
// encode: qin = X@Wi+bi; product state v (bf16); Xb = bf16(X) side-product.
// v2: Wit staged in LDS (32 KB) once per block; 16 rows/block (4/wave) so
// the 8 table-reads per X-quad come from LDS, keeping L1/HBM for the X
// stream (was: 8 global loads per X-quad thrashing the 32 KB L1).
// ---------------------------------------------------------------------------
__global__ __launch_bounds__(256) void encode_kernel(
    const float* __restrict__ X, const float* __restrict__ Wit,
    const float* __restrict__ bi,
    bf16s* __restrict__ Xb, bf16s* __restrict__ v)
{
    __shared__ float ldsW[8 * 1024];

    const int tid  = threadIdx.x;
    const int lane = tid & 63;
    const int wid  = tid >> 6;

#pragma unroll
    for (int i = 0; i < 8; i++)
        ((f32x4*)ldsW)[i * 256 + tid] = ((const f32x4*)Wit)[i * 256 + tid];
    __syncthreads();

#pragma unroll
    for (int rr = 0; rr < 4; rr++) {
        const int row = blockIdx.x * 16 + wid * 4 + rr;
        const f32x4* xr4 = (const f32x4*)(X + (size_t)row * EE);
        ushort4* xbr4 = (ushort4*)(Xb + (size_t)row * EE);

        float acc[NQ];
#pragma unroll
        for (int j = 0; j < NQ; j++) acc[j] = 0.f;

#pragma unroll
        for (int t = 0; t < 4; t++) {
            int k4 = t * 64 + lane;
            f32x4 x = xr4[k4];
            ushort4 xb;
            xb.x = f2bf(x[0]); xb.y = f2bf(x[1]);
            xb.z = f2bf(x[2]); xb.w = f2bf(x[3]);
            xbr4[k4] = xb;
#pragma unroll
            for (int j = 0; j < NQ; j++) {
                f32x4 w = ((const f32x4*)(ldsW + j * 1024))[k4];
                acc[j] += x[0]*w[0] + x[1]*w[1] + x[2]*w[2] + x[3]*w[3];
            }
        }
        float qin[NQ];
#pragma unroll
        for (int j = 0; j < NQ; j++) {
            float s = acc[j];
#pragma unroll
            for (int off = 32; off >= 1; off >>= 1) s += __shfl_xor(s, off, 64);
            qin[j] = s + bi[j];
        }

        float cs[NQ], sn[NQ];
#pragma unroll
        for (int q = 0; q < NQ; q++) __sincosf(0.5f * qin[q], &sn[q], &cs[q]);

        float common = 1.f;
#pragma unroll
        for (int b = 2; b < 8; b++) {
            int q = 7 - b;
            common *= ((lane >> (b - 2)) & 1) ? sn[q] : cs[q];
        }
        float a0 = common * cs[6] * cs[7];
        float a1 = common * cs[6] * sn[7];
        float a2 = common * sn[6] * cs[7];
        float a3 = common * sn[6] * sn[7];
        ushort4 vo;
        vo.x = f2bf(a0); vo.y = f2bf(a1); vo.z = f2bf(a2); vo.w = f2bf(a3);
        ((ushort4*)(v + (size_t)row * DD))[lane] = vo;
    }
}

// ---------------------------------------------------------------------------
// gemm256: C[M][N] = A[M][K] @ Bt[N][K]^T, bf16 out. 256x256 tile, 512 thr
// (8 waves 2Mx4N, wave tile 128x64), BK=32, 4 LDS K-slots (128 KB dynamic),
// ONE barrier + counted vmcnt(4) per K-tile, prefetch distance 2.
// T2 swizzle via pre-swizzled global source (rule #21).
// ---------------------------------------------------------------------------
__global__ __launch_bounds__(512) void gemm256_kernel(
    const bf16s* __restrict__ A, const bf16s* __restrict__ Bt,
    bf16s* __restrict__ C, int M, int N, int K, int nm, int nn)
{
    extern __shared__ bf16s lds[];
    bf16s* As = lds;               // 4 slots x 8192 el (256 rows x 32 k)
    bf16s* Bs = lds + 4 * 8192;    // 4 slots x 8192 el

    const int tid  = threadIdx.x;
    const int lane = tid & 63;
    const int wid  = tid >> 6;
    const int quad = lane >> 4, lr = lane & 15;
    const int wr = wid >> 2, wc = wid & 3;   // 2x4 wave grid

    const int nwg = gridDim.x;
    const int q = nwg >> 3, r = nwg & 7;
    const int xcd = blockIdx.x & 7, idx = blockIdx.x >> 3;
    const int w = (xcd < r ? xcd * (q + 1) : r * (q + 1) + (xcd - r) * q) + idx;
    const int n_t = w % nn, m_t = w / nn;
    const int m0 = m_t * 256, n0 = n_t * 256;

    f32x4 acc[8][4];
#pragma unroll
    for (int i = 0; i < 8; i++)
#pragma unroll
        for (int j = 0; j < 4; j++) acc[i][j] = (f32x4){0.f, 0.f, 0.f, 0.f};

    auto stage = [&](int slot, int kt) {
#pragma unroll
        for (int l = 0; l < 2; l++) {
            int ch = l * 512 + tid;                       // 16B chunk id
            int row = ch >> 2;
            int kc = ((ch & 3) ^ (row & 3)) * 8;          // inverse-swizzled src
            __builtin_amdgcn_global_load_lds(
                (AS1 const void*)(A + (size_t)(m0 + row) * K + kt * 32 + kc),
                (AS3 void*)(As + slot * 8192 + ch * 8), 16, 0, 0);
        }
#pragma unroll
        for (int l = 0; l < 2; l++) {
            int ch = l * 512 + tid;
            int row = ch >> 2;
            int kc = ((ch & 3) ^ (row & 3)) * 8;
            __builtin_amdgcn_global_load_lds(
                (AS1 const void*)(Bt + (size_t)(n0 + row) * K + kt * 32 + kc),
                (AS3 void*)(Bs + slot * 8192 + ch * 8), 16, 0, 0);
        }
    };
    auto compute = [&](int slot) {
        bf16x8 af[8];
#pragma unroll
        for (int i = 0; i < 8; i++) {
            int rowl = wr * 128 + i * 16 + lr;
            af[i] = *(const bf16x8*)(As + slot * 8192 + rowl * 32
                                     + ((quad ^ (rowl & 3)) * 8));
        }
#pragma unroll
        for (int j = 0; j < 4; j++) {
            int rowl = wc * 64 + j * 16 + lr;
            bf16x8 bfr = *(const bf16x8*)(Bs + slot * 8192 + rowl * 32
                                          + ((quad ^ (rowl & 3)) * 8));
#pragma unroll
            for (int i = 0; i < 8; i++)
                acc[i][j] = __builtin_amdgcn_mfma_f32_16x16x32_bf16(
                    af[i], bfr, acc[i][j], 0, 0, 0);
        }
    };

    const int NT = K >> 5;   // 32
    stage(0, 0);
    stage(1, 1);
    for (int kt = 0; kt < NT; kt++) {
        if (kt + 1 < NT) PIPE_WAIT(4);
        else             PIPE_WAIT(0);
        if (kt + 2 < NT) stage((kt + 2) & 3, kt + 2);
        compute(kt & 3);
    }

#pragma unroll
    for (int i = 0; i < 8; i++) {
        int row0 = m0 + wr * 128 + i * 16 + quad * 4;
#pragma unroll
        for (int j = 0; j < 4; j++) {
            int col = n0 + wc * 64 + j * 16 + lr;
#pragma unroll
            for (int rr = 0; rr < 4; rr++)
                C[(size_t)(row0 + rr) * N + col] = f2bf(acc[i][j][rr]);
        }
    }
}

// ---------------------------------------------------------------------------
// MFMA bf16 GEMM: depth-2 (3-buffer) pipeline; bijective XCD chunking.
// Work order: w = (z * nm + m) * nn + n.  B row-stride = ldB.
// ---------------------------------------------------------------------------
template<bool OUT_BF16>
__global__ __launch_bounds__(256) void mfma_gemm(
    const bf16s* __restrict__ A, const bf16s* __restrict__ Bt,
    const float* __restrict__ bias, void* __restrict__ Cv,
    int M, int N, int K, int ldB, int nm, int nn,
    long long sA, long long sB, long long sC)
{
    __shared__ bf16s As[3][128 * 32];
    __shared__ bf16s Bs[3][128 * 32];

    const int tid  = threadIdx.x;
    const int wave = tid >> 6, lane = tid & 63;
    const int quad = lane >> 4, lr = lane & 15;
    const int wm = (wave >> 1) * 64, wn = (wave & 1) * 64;

    const int nwg = gridDim.x;
    const int q = nwg >> 3, r = nwg & 7;
    const int xcd = blockIdx.x & 7, idx = blockIdx.x >> 3;
    const int w = (xcd < r ? xcd * (q + 1) : r * (q + 1) + (xcd - r) * q) + idx;
    const int n_t = w % nn;
    const int m_t = (w / nn) % nm;
    const int z   = w / (nn * nm);
    const int m0 = m_t * 128, n0 = n_t * 128;

    A  += (size_t)z * sA;
    Bt += (size_t)z * sB;

    f32x4 acc[4][4];
#pragma unroll
    for (int i = 0; i < 4; i++)
#pragma unroll
        for (int j = 0; j < 4; j++) acc[i][j] = (f32x4){0.f, 0.f, 0.f, 0.f};

    auto stage = [&](int buf, int kt) {
#pragma unroll
        for (int j = 0; j < 2; j++) {
            int ch = j * 256 + tid;
            int row = ch >> 2, kc = (ch & 3) * 8;
            __builtin_amdgcn_global_load_lds(
                (AS1 const void*)(A + (size_t)(m0 + row) * K + kt + kc),
                (AS3 void*)(As[buf] + (size_t)(j * 256 + wave * 64) * 8), 16, 0, 0);
            __builtin_amdgcn_global_load_lds(
                (AS1 const void*)(Bt + (size_t)(n0 + row) * ldB + kt + kc),
                (AS3 void*)(Bs[buf] + (size_t)(j * 256 + wave * 64) * 8), 16, 0, 0);
        }
    };
    auto compute = [&](int buf) {
        bf16x8 af[4], bfr[4];
#pragma unroll
        for (int i = 0; i < 4; i++)
            af[i] = *(const bf16x8*)(As[buf] + (wm + i * 16 + lr) * 32 + quad * 8);
#pragma unroll
        for (int j = 0; j < 4; j++)
            bfr[j] = *(const bf16x8*)(Bs[buf] + (wn + j * 16 + lr) * 32 + quad * 8);
#pragma unroll
        for (int i = 0; i < 4; i++)
#pragma unroll
            for (int j = 0; j < 4; j++)
                acc[i][j] = __builtin_amdgcn_mfma_f32_16x16x32_bf16(
                    af[i], bfr[j], acc[i][j], 0, 0, 0);
    };

    const int nt = K >> 5;
    stage(0, 0);
    stage(1, 1 << 5);
    int cur = 0, nxt = 2;
    for (int t = 0; t < nt; t++) {
        if (t + 2 < nt) { stage(nxt, (t + 2) << 5); PIPE_WAIT(8); }
        else if (t + 1 < nt) PIPE_WAIT(4);
        else PIPE_WAIT(0);
        compute(cur);
        PIPE_BAR();
        cur = (cur == 2) ? 0 : cur + 1;
        nxt = (nxt == 2) ? 0 : nxt + 1;
    }

    float* Cf = (float*)Cv + (size_t)z * sC;
    bf16s* Cb = (bf16s*)Cv + (size_t)z * sC;
#pragma unroll
    for (int i = 0; i < 4; i++) {
        int row0 = m0 + wm + i * 16 + quad * 4;
#pragma unroll
        for (int j = 0; j < 4; j++) {
            int col = n0 + wn + j * 16 + lr;
            float bb = bias ? bias[col] : 0.f;
#pragma unroll
            for (int r = 0; r < 4; r++) {
                float v = acc[i][j][r] + bb;
                if (OUT_BF16) Cb[(size_t)(row0 + r) * N + col] = f2bf(v);
                else          Cf[(size_t)(row0 + r) * N + col] = v;
            }
        }
    }
}

// ---------------------------------------------------------------------------
// attn: G[s,t] = v_s . v_t (real; unitary cancels). K = G^2/sqrt(8) +
// cos(phi_t-phi_s); fused softmax. Depth-2 pipeline over v (K=256).
// ---------------------------------------------------------------------------
__global__ __launch_bounds__(256) void attn_kernel(
    const bf16s* __restrict__ v, const float* __restrict__ phi,
    float* __restrict__ attn, bf16s* __restrict__ attn_bf)
{
    __shared__ bf16s Bs[3][128 * 32];

    const int tid  = threadIdx.x;
    const int wave = tid >> 6, lane = tid & 63;
    const int quad = lane >> 4, lr = lane & 15;
    const int b = blockIdx.y;
    const int s0 = blockIdx.x * 64;
    const bf16s* vb = v + (size_t)b * 128 * DD;

    f32x4 accre[8];
#pragma unroll
    for (int j = 0; j < 8; j++) accre[j] = (f32x4){0.f, 0.f, 0.f, 0.f};

    auto stage = [&](int buf, int kt) {
#pragma unroll
        for (int j = 0; j < 2; j++) {
            int ch = j * 256 + tid;
            int row = ch >> 2, kc = (ch & 3) * 8;
            __builtin_amdgcn_global_load_lds(
                (AS1 const void*)(vb + (size_t)row * DD + kt + kc),
                (AS3 void*)(Bs[buf] + (size_t)(j * 256 + wave * 64) * 8), 16, 0, 0);
        }
    };
    auto compute = [&](int buf) {
        bf16x8 afr = *(const bf16x8*)(Bs[buf] + (s0 + wave * 16 + lr) * 32 + quad * 8);
#pragma unroll
        for (int j = 0; j < 8; j++) {
            bf16x8 b1 = *(const bf16x8*)(Bs[buf] + (j * 16 + lr) * 32 + quad * 8);
            accre[j] = __builtin_amdgcn_mfma_f32_16x16x32_bf16(afr, b1, accre[j], 0, 0, 0);
        }
    };

    const int nt = DD >> 5;   // 8
    stage(0, 0);
    stage(1, 1 << 5);
    int cur = 0, nxt = 2;
    for (int t = 0; t < nt; t++) {
        if (t + 2 < nt) { stage(nxt, (t + 2) << 5); PIPE_WAIT(4); }
        else if (t + 1 < nt) PIPE_WAIT(2);
        else PIPE_WAIT(0);
        compute(cur);
        PIPE_BAR();
        cur = (cur == 2) ? 0 : cur + 1;
        nxt = (nxt == 2) ? 0 : nxt + 1;
    }

    const float isq = 0.35355339059327373f;   // 1/sqrt(8)
    float ph_r[4], ph_c[8];
#pragma unroll
    for (int r = 0; r < 4; r++) ph_r[r] = phi[s0 + wave * 16 + quad * 4 + r];
#pragma unroll
    for (int j = 0; j < 8; j++) ph_c[j] = phi[j * 16 + lr];

#pragma unroll
    for (int r = 0; r < 4; r++) {
        float vv[8];
        float mx = -1e30f;
#pragma unroll
        for (int j = 0; j < 8; j++) {
            float re = accre[j][r];
            vv[j] = re * re * isq + __cosf(ph_c[j] - ph_r[r]);
            mx = fmaxf(mx, vv[j]);
        }
#pragma unroll
        for (int off = 1; off <= 8; off <<= 1) mx = fmaxf(mx, __shfl_xor(mx, off, 64));
        float sm = 0.f;
#pragma unroll
        for (int j = 0; j < 8; j++) { vv[j] = __expf(vv[j] - mx); sm += vv[j]; }
#pragma unroll
        for (int off = 1; off <= 8; off <<= 1) sm += __shfl_xor(sm, off, 64);
        float inv = 1.f / sm;
        int srow = b * 128 + s0 + wave * 16 + quad * 4 + r;
#pragma unroll
        for (int j = 0; j < 8; j++) {
            float o = vv[j] * inv;
            attn[(size_t)srow * 128 + j * 16 + lr] = o;
            attn_bf[(size_t)srow * 128 + j * 16 + lr] = f2bf(o);
        }
    }
}

// ---------------------------------------------------------------------------
extern "C" void kernel_launch(void* const* d_in, const int* in_sizes, int n_in,
                              void* d_out, int out_size, void* d_ws, size_t ws_size,
                              hipStream_t stream) {
    const float* X     = (const float*)d_in[0];
    const float* Wi    = (const float*)d_in[1];
    const float* bi    = (const float*)d_in[2];
    const float* Wv    = (const float*)d_in[3];
    const float* bv    = (const float*)d_in[4];
    const float* Wo    = (const float*)d_in[5];
    const float* bo    = (const float*)d_in[6];
    const float* phi   = (const float*)d_in[8];

    float* y    = (float*)d_out;
    float* attn = y + (size_t)MM * EE;

    bf16s* Xb   = (bf16s*)d_ws;                      // 16384*1024
    bf16s* Vwt  = Xb  + (size_t)MM * EE;             // [1024 e][16384 g] (X@WvWo)^T
    bf16s* v    = Vwt + (size_t)MM * EE;             // 16384*256 product states
    bf16s* abf  = v   + (size_t)MM * DD;             // 128*128*128
    bf16s* Wvb  = abf + (size_t)BB * SS * SS;        // 1024*1024 bf16(Wv)
    bf16s* Wot  = Wvb + (size_t)EE * EE;             // 1024*1024 Wo^T
    bf16s* Wvot = Wot + (size_t)EE * EE;             // 1024*1024 (Wv@Wo)^T
    float* Wit  = (float*)(Wvot + (size_t)EE * EE);  // 8*1024 fp32
    float* bvo  = Wit + 8 * 1024;                    // 1024 fp32
    float* bvop = bvo + 1024;                        // 16*1024 fp32 partials

    wtrans_kernel<<<32, 256, 0, stream>>>(Wi, Wit);
    encode_kernel<<<MM / 16, 256, 0, stream>>>(X, Wit, bi, Xb, v);
    transpose_conv_kernel<<<dim3(32, 32), 256, 0, stream>>>(Wo, Wot, EE, EE);
    cvt_kernel<<<1024, 256, 0, stream>>>(Wv, Wvb);
    bvo_part_kernel<<<256, 256, 0, stream>>>(bv, Wo, bvop);
    bvo_reduce_kernel<<<4, 256, 0, stream>>>(bvop, bo, bvo);
    // Wvot[a][b] = (Wv@Wo)[b][a] :  A=Wot, Bt=Wvb  (M=N=K=1024)
    mfma_gemm<true><<<64, 256, 0, stream>>>(
        Wot, Wvb, nullptr, Wvot, EE, EE, EE, EE, /*nm*/8, /*nn*/8, 0, 0, 0);
    // attn: real Gram of v + phase term + softmax (unitary cancels)
    attn_kernel<<<dim3(2, BB), 256, 0, stream>>>(v, phi, attn, abf);
    // Vwt[e][g] = Wvot[e][:] . Xb[g][:]  — 256^2-tile counted-vmcnt GEMM
    gemm256_kernel<<<256, 512, 128 * 1024, stream>>>(
        Wvot, Xb, Vwt, EE, MM, EE, /*nm*/4, /*nn*/64);
    // y_b = attn_b @ Vw_b + bvo   (B from merged Vwt: ldB=16384, batch off 128)
    mfma_gemm<false><<<1024, 256, 0, stream>>>(
        abf, Vwt, bvo, y, SS, EE, SS, MM, /*nm*/1, /*nn*/8,
        (long long)SS * SS, (long long)SS, (long long)SS * EE);
}

// Round 12
// 248.446 us; speedup vs baseline: 1.5436x; 1.0124x over previous
//
#include <hip/hip_runtime.h>
#include <hip/hip_bf16.h>

#define BB 128
#define SS 128
#define EE 1024
#define NQ 8
#define DD 256
#define LL 4
#define MM (BB*SS)

typedef unsigned short bf16s;
typedef __attribute__((ext_vector_type(8))) short bf16x8;
typedef __attribute__((ext_vector_type(4))) float f32x4;

#define AS1 __attribute__((address_space(1)))
#define AS3 __attribute__((address_space(3)))

__device__ __forceinline__ unsigned short f2bf(float x) {
    unsigned u = __float_as_uint(x);
    u += 0x7fffu + ((u >> 16) & 1u);
    return (unsigned short)(u >> 16);
}

// pipeline helpers: counted vmcnt (T4) + raw barrier, sched fences (#18)
#define PIPE_WAIT(N) do { \
    asm volatile("s_waitcnt vmcnt(" #N ")" ::: "memory"); \
    __builtin_amdgcn_sched_barrier(0); \
    __builtin_amdgcn_s_barrier(); \
    __builtin_amdgcn_sched_barrier(0); } while (0)
#define PIPE_BAR() do { \
    __builtin_amdgcn_sched_barrier(0); \
    __builtin_amdgcn_s_barrier(); } while (0)

// ---------------------------------------------------------------------------
// fp32 RxC -> bf16 CxR transpose-convert (weights)
// ---------------------------------------------------------------------------
__global__ __launch_bounds__(256) void transpose_conv_kernel(
    const float* __restrict__ in, bf16s* __restrict__ out, int R, int C)
{
    __shared__ float t[32][33];
    int bx = blockIdx.x * 32, by = blockIdx.y * 32;
    int lx = threadIdx.x & 31, ly = threadIdx.x >> 5;
#pragma unroll
    for (int i = 0; i < 32; i += 8)
        t[ly + i][lx] = in[(size_t)(by + ly + i) * C + bx + lx];
    __syncthreads();
#pragma unroll
    for (int i = 0; i < 32; i += 8)
        out[(size_t)(bx + ly + i) * R + by + lx] = f2bf(t[lx][ly + i]);
}

// ---------------------------------------------------------------------------
// fp32 -> bf16 straight convert (Wv), float4 vectorized
// ---------------------------------------------------------------------------
__global__ __launch_bounds__(256) void cvt_kernel(
    const float* __restrict__ in, bf16s* __restrict__ out)
{
    int g = blockIdx.x * 256 + threadIdx.x;      // float4 index
    f32x4 x = ((const f32x4*)in)[g];
    ushort4 o;
    o.x = f2bf(x[0]); o.y = f2bf(x[1]); o.z = f2bf(x[2]); o.w = f2bf(x[3]);
    ((ushort4*)out)[g] = o;
}

// ---------------------------------------------------------------------------
// bvo = bv@Wo + bo, two parallel stages.
// ---------------------------------------------------------------------------
__global__ __launch_bounds__(256) void bvo_part_kernel(
    const float* __restrict__ bv, const float* __restrict__ Wo,
    float* __restrict__ part)
{
    __shared__ float red[4][64];
    int lane = threadIdx.x & 63, w = threadIdx.x >> 6;
    int eb = blockIdx.x & 15, kb = blockIdx.x >> 4;
    int e = eb * 64 + lane;
    int k0 = kb * 64 + w * 16;
    float acc = 0.f;
#pragma unroll
    for (int i = 0; i < 16; i++)
        acc += bv[k0 + i] * Wo[(size_t)(k0 + i) * EE + e];
    red[w][lane] = acc;
    __syncthreads();
    if (w == 0)
        part[kb * EE + e] = red[0][lane] + red[1][lane] + red[2][lane] + red[3][lane];
}

__global__ __launch_bounds__(256) void bvo_reduce_kernel(
    const float* __restrict__ part, const float* __restrict__ bo,
    float* __restrict__ bvo)
{
    int e = blockIdx.x * 256 + threadIdx.x;
    float s = bo[e];
#pragma unroll
    for (int kb = 0; kb < 16; kb++) s += part[kb * EE + e];
    bvo[e] = s;
}

// ---------------------------------------------------------------------------
// Wi[1024][8] -> Wit[8][1024] fp32
// ---------------------------------------------------------------------------
__global__ __launch_bounds__(256) void wtrans_kernel(
    const float* __restrict__ Wi, float* __restrict__ Wit)
{
    int g = blockIdx.x * 256 + threadIdx.x;   // 0..8191
    int k = g >> 3, j = g & 7;
    Wit[j * 1024 + k] = Wi[g];
}

// ---------------------------------------------------------------------------
// encode v3: the lane->k map (k4 = t*64+lane) is row-invariant, so each
// lane's 128 W floats are hoisted into VGPRs ONCE per wave. Row loop has
// only 9 VMEM instrs (4 X loads, 4 Xb stores, 1 v store), zero table reads.
// 4 rows/wave, manual 1-row-ahead X prefetch overlaps the serial tail.
// ---------------------------------------------------------------------------
__global__ __launch_bounds__(256) void encode_kernel(
    const float* __restrict__ X, const float* __restrict__ Wit,
    const float* __restrict__ bi,
    bf16s* __restrict__ Xb, bf16s* __restrict__ v)
{
    const int lane = threadIdx.x & 63;
    const int wid  = threadIdx.x >> 6;
    const int row0 = blockIdx.x * 16 + wid * 4;

    // per-lane W slice: wreg[j][t] = Wit[j][(t*64+lane)*4 ..]
    f32x4 wreg[8][4];
#pragma unroll
    for (int j = 0; j < 8; j++)
#pragma unroll
        for (int t = 0; t < 4; t++)
            wreg[j][t] = ((const f32x4*)(Wit + j * 1024))[t * 64 + lane];

    float bis[8];
#pragma unroll
    for (int j = 0; j < 8; j++) bis[j] = bi[j];

    f32x4 xa0, xa1, xa2, xa3, xn0, xn1, xn2, xn3;
    {
        const f32x4* xr = (const f32x4*)(X + (size_t)row0 * EE);
        xa0 = xr[0 * 64 + lane]; xa1 = xr[1 * 64 + lane];
        xa2 = xr[2 * 64 + lane]; xa3 = xr[3 * 64 + lane];
    }

#pragma unroll
    for (int rr = 0; rr < 4; rr++) {
        const int row = row0 + rr;
        if (rr < 3) {
            const f32x4* xn = (const f32x4*)(X + (size_t)(row + 1) * EE);
            xn0 = xn[0 * 64 + lane]; xn1 = xn[1 * 64 + lane];
            xn2 = xn[2 * 64 + lane]; xn3 = xn[3 * 64 + lane];
        }

        ushort4* xbr4 = (ushort4*)(Xb + (size_t)row * EE);
        float acc[8];
#pragma unroll
        for (int j = 0; j < 8; j++) acc[j] = 0.f;

        f32x4 xs[4] = {xa0, xa1, xa2, xa3};
#pragma unroll
        for (int t = 0; t < 4; t++) {
            f32x4 x = xs[t];
            ushort4 xb;
            xb.x = f2bf(x[0]); xb.y = f2bf(x[1]);
            xb.z = f2bf(x[2]); xb.w = f2bf(x[3]);
            xbr4[t * 64 + lane] = xb;
#pragma unroll
            for (int j = 0; j < 8; j++) {
                f32x4 w = wreg[j][t];
                acc[j] += x[0]*w[0] + x[1]*w[1] + x[2]*w[2] + x[3]*w[3];
            }
        }

        float qin[8];
#pragma unroll
        for (int j = 0; j < 8; j++) {
            float s = acc[j];
#pragma unroll
            for (int off = 32; off >= 1; off >>= 1) s += __shfl_xor(s, off, 64);
            qin[j] = s + bis[j];
        }

        float cs[8], sn[8];
#pragma unroll
        for (int q = 0; q < 8; q++) __sincosf(0.5f * qin[q], &sn[q], &cs[q]);

        float common = 1.f;
#pragma unroll
        for (int b = 2; b < 8; b++) {
            int q = 7 - b;
            common *= ((lane >> (b - 2)) & 1) ? sn[q] : cs[q];
        }
        float a0 = common * cs[6] * cs[7];
        float a1 = common * cs[6] * sn[7];
        float a2 = common * sn[6] * cs[7];
        float a3 = common * sn[6] * sn[7];
        ushort4 vo;
        vo.x = f2bf(a0); vo.y = f2bf(a1); vo.z = f2bf(a2); vo.w = f2bf(a3);
        ((ushort4*)(v + (size_t)row * DD))[lane] = vo;

        xa0 = xn0; xa1 = xn1; xa2 = xn2; xa3 = xn3;
    }
}

// ---------------------------------------------------------------------------
// gemm256: C[M][N] = A[M][K] @ Bt[N][K]^T, bf16 out. 256x256 tile, 512 thr
// (8 waves 2Mx4N, wave tile 128x64), BK=32, 4 LDS K-slots (128 KB dynamic),
// ONE barrier + counted vmcnt(4) per K-tile, prefetch distance 2.
// T2 swizzle via pre-swizzled global source (rule #21).
// ---------------------------------------------------------------------------
__global__ __launch_bounds__(512) void gemm256_kernel(
    const bf16s* __restrict__ A, const bf16s* __restrict__ Bt,
    bf16s* __restrict__ C, int M, int N, int K, int nm, int nn)
{
    extern __shared__ bf16s lds[];
    bf16s* As = lds;               // 4 slots x 8192 el (256 rows x 32 k)
    bf16s* Bs = lds + 4 * 8192;    // 4 slots x 8192 el

    const int tid  = threadIdx.x;
    const int lane = tid & 63;
    const int wid  = tid >> 6;
    const int quad = lane >> 4, lr = lane & 15;
    const int wr = wid >> 2, wc = wid & 3;   // 2x4 wave grid

    const int nwg = gridDim.x;
    const int q = nwg >> 3, r = nwg & 7;
    const int xcd = blockIdx.x & 7, idx = blockIdx.x >> 3;
    const int w = (xcd < r ? xcd * (q + 1) : r * (q + 1) + (xcd - r) * q) + idx;
    const int n_t = w % nn, m_t = w / nn;
    const int m0 = m_t * 256, n0 = n_t * 256;

    f32x4 acc[8][4];
#pragma unroll
    for (int i = 0; i < 8; i++)
#pragma unroll
        for (int j = 0; j < 4; j++) acc[i][j] = (f32x4){0.f, 0.f, 0.f, 0.f};

    auto stage = [&](int slot, int kt) {
#pragma unroll
        for (int l = 0; l < 2; l++) {
            int ch = l * 512 + tid;                       // 16B chunk id
            int row = ch >> 2;
            int kc = ((ch & 3) ^ (row & 3)) * 8;          // inverse-swizzled src
            __builtin_amdgcn_global_load_lds(
                (AS1 const void*)(A + (size_t)(m0 + row) * K + kt * 32 + kc),
                (AS3 void*)(As + slot * 8192 + ch * 8), 16, 0, 0);
        }
#pragma unroll
        for (int l = 0; l < 2; l++) {
            int ch = l * 512 + tid;
            int row = ch >> 2;
            int kc = ((ch & 3) ^ (row & 3)) * 8;
            __builtin_amdgcn_global_load_lds(
                (AS1 const void*)(Bt + (size_t)(n0 + row) * K + kt * 32 + kc),
                (AS3 void*)(Bs + slot * 8192 + ch * 8), 16, 0, 0);
        }
    };
    auto compute = [&](int slot) {
        bf16x8 af[8];
#pragma unroll
        for (int i = 0; i < 8; i++) {
            int rowl = wr * 128 + i * 16 + lr;
            af[i] = *(const bf16x8*)(As + slot * 8192 + rowl * 32
                                     + ((quad ^ (rowl & 3)) * 8));
        }
#pragma unroll
        for (int j = 0; j < 4; j++) {
            int rowl = wc * 64 + j * 16 + lr;
            bf16x8 bfr = *(const bf16x8*)(Bs + slot * 8192 + rowl * 32
                                          + ((quad ^ (rowl & 3)) * 8));
#pragma unroll
            for (int i = 0; i < 8; i++)
                acc[i][j] = __builtin_amdgcn_mfma_f32_16x16x32_bf16(
                    af[i], bfr, acc[i][j], 0, 0, 0);
        }
    };

    const int NT = K >> 5;   // 32
    stage(0, 0);
    stage(1, 1);
    for (int kt = 0; kt < NT; kt++) {
        if (kt + 1 < NT) PIPE_WAIT(4);
        else             PIPE_WAIT(0);
        if (kt + 2 < NT) stage((kt + 2) & 3, kt + 2);
        compute(kt & 3);
    }

#pragma unroll
    for (int i = 0; i < 8; i++) {
        int row0 = m0 + wr * 128 + i * 16 + quad * 4;
#pragma unroll
        for (int j = 0; j < 4; j++) {
            int col = n0 + wc * 64 + j * 16 + lr;
#pragma unroll
            for (int rr = 0; rr < 4; rr++)
                C[(size_t)(row0 + rr) * N + col] = f2bf(acc[i][j][rr]);
        }
    }
}

// ---------------------------------------------------------------------------
// MFMA bf16 GEMM: depth-2 (3-buffer) pipeline; bijective XCD chunking.
// Work order: w = (z * nm + m) * nn + n.  B row-stride = ldB.
// ---------------------------------------------------------------------------
template<bool OUT_BF16>
__global__ __launch_bounds__(256) void mfma_gemm(
    const bf16s* __restrict__ A, const bf16s* __restrict__ Bt,
    const float* __restrict__ bias, void* __restrict__ Cv,
    int M, int N, int K, int ldB, int nm, int nn,
    long long sA, long long sB, long long sC)
{
    __shared__ bf16s As[3][128 * 32];
    __shared__ bf16s Bs[3][128 * 32];

    const int tid  = threadIdx.x;
    const int wave = tid >> 6, lane = tid & 63;
    const int quad = lane >> 4, lr = lane & 15;
    const int wm = (wave >> 1) * 64, wn = (wave & 1) * 64;

    const int nwg = gridDim.x;
    const int q = nwg >> 3, r = nwg & 7;
    const int xcd = blockIdx.x & 7, idx = blockIdx.x >> 3;
    const int w = (xcd < r ? xcd * (q + 1) : r * (q + 1) + (xcd - r) * q) + idx;
    const int n_t = w % nn;
    const int m_t = (w / nn) % nm;
    const int z   = w / (nn * nm);
    const int m0 = m_t * 128, n0 = n_t * 128;

    A  += (size_t)z * sA;
    Bt += (size_t)z * sB;

    f32x4 acc[4][4];
#pragma unroll
    for (int i = 0; i < 4; i++)
#pragma unroll
        for (int j = 0; j < 4; j++) acc[i][j] = (f32x4){0.f, 0.f, 0.f, 0.f};

    auto stage = [&](int buf, int kt) {
#pragma unroll
        for (int j = 0; j < 2; j++) {
            int ch = j * 256 + tid;
            int row = ch >> 2, kc = (ch & 3) * 8;
            __builtin_amdgcn_global_load_lds(
                (AS1 const void*)(A + (size_t)(m0 + row) * K + kt + kc),
                (AS3 void*)(As[buf] + (size_t)(j * 256 + wave * 64) * 8), 16, 0, 0);
            __builtin_amdgcn_global_load_lds(
                (AS1 const void*)(Bt + (size_t)(n0 + row) * ldB + kt + kc),
                (AS3 void*)(Bs[buf] + (size_t)(j * 256 + wave * 64) * 8), 16, 0, 0);
        }
    };
    auto compute = [&](int buf) {
        bf16x8 af[4], bfr[4];
#pragma unroll
        for (int i = 0; i < 4; i++)
            af[i] = *(const bf16x8*)(As[buf] + (wm + i * 16 + lr) * 32 + quad * 8);
#pragma unroll
        for (int j = 0; j < 4; j++)
            bfr[j] = *(const bf16x8*)(Bs[buf] + (wn + j * 16 + lr) * 32 + quad * 8);
#pragma unroll
        for (int i = 0; i < 4; i++)
#pragma unroll
            for (int j = 0; j < 4; j++)
                acc[i][j] = __builtin_amdgcn_mfma_f32_16x16x32_bf16(
                    af[i], bfr[j], acc[i][j], 0, 0, 0);
    };

    const int nt = K >> 5;
    stage(0, 0);
    stage(1, 1 << 5);
    int cur = 0, nxt = 2;
    for (int t = 0; t < nt; t++) {
        if (t + 2 < nt) { stage(nxt, (t + 2) << 5); PIPE_WAIT(8); }
        else if (t + 1 < nt) PIPE_WAIT(4);
        else PIPE_WAIT(0);
        compute(cur);
        PIPE_BAR();
        cur = (cur == 2) ? 0 : cur + 1;
        nxt = (nxt == 2) ? 0 : nxt + 1;
    }

    float* Cf = (float*)Cv + (size_t)z * sC;
    bf16s* Cb = (bf16s*)Cv + (size_t)z * sC;
#pragma unroll
    for (int i = 0; i < 4; i++) {
        int row0 = m0 + wm + i * 16 + quad * 4;
#pragma unroll
        for (int j = 0; j < 4; j++) {
            int col = n0 + wn + j * 16 + lr;
            float bb = bias ? bias[col] : 0.f;
#pragma unroll
            for (int r = 0; r < 4; r++) {
                float v = acc[i][j][r] + bb;
                if (OUT_BF16) Cb[(size_t)(row0 + r) * N + col] = f2bf(v);
                else          Cf[(size_t)(row0 + r) * N + col] = v;
            }
        }
    }
}

// ---------------------------------------------------------------------------
// attn: G[s,t] = v_s . v_t (real; unitary cancels). K = G^2/sqrt(8) +
// cos(phi_t-phi_s); fused softmax. Depth-2 pipeline over v (K=256).
// ---------------------------------------------------------------------------
__global__ __launch_bounds__(256) void attn_kernel(
    const bf16s* __restrict__ v, const float* __restrict__ phi,
    float* __restrict__ attn, bf16s* __restrict__ attn_bf)
{
    __shared__ bf16s Bs[3][128 * 32];

    const int tid  = threadIdx.x;
    const int wave = tid >> 6, lane = tid & 63;
    const int quad = lane >> 4, lr = lane & 15;
    const int b = blockIdx.y;
    const int s0 = blockIdx.x * 64;
    const bf16s* vb = v + (size_t)b * 128 * DD;

    f32x4 accre[8];
#pragma unroll
    for (int j = 0; j < 8; j++) accre[j] = (f32x4){0.f, 0.f, 0.f, 0.f};

    auto stage = [&](int buf, int kt) {
#pragma unroll
        for (int j = 0; j < 2; j++) {
            int ch = j * 256 + tid;
            int row = ch >> 2, kc = (ch & 3) * 8;
            __builtin_amdgcn_global_load_lds(
                (AS1 const void*)(vb + (size_t)row * DD + kt + kc),
                (AS3 void*)(Bs[buf] + (size_t)(j * 256 + wave * 64) * 8), 16, 0, 0);
        }
    };
    auto compute = [&](int buf) {
        bf16x8 afr = *(const bf16x8*)(Bs[buf] + (s0 + wave * 16 + lr) * 32 + quad * 8);
#pragma unroll
        for (int j = 0; j < 8; j++) {
            bf16x8 b1 = *(const bf16x8*)(Bs[buf] + (j * 16 + lr) * 32 + quad * 8);
            accre[j] = __builtin_amdgcn_mfma_f32_16x16x32_bf16(afr, b1, accre[j], 0, 0, 0);
        }
    };

    const int nt = DD >> 5;   // 8
    stage(0, 0);
    stage(1, 1 << 5);
    int cur = 0, nxt = 2;
    for (int t = 0; t < nt; t++) {
        if (t + 2 < nt) { stage(nxt, (t + 2) << 5); PIPE_WAIT(4); }
        else if (t + 1 < nt) PIPE_WAIT(2);
        else PIPE_WAIT(0);
        compute(cur);
        PIPE_BAR();
        cur = (cur == 2) ? 0 : cur + 1;
        nxt = (nxt == 2) ? 0 : nxt + 1;
    }

    const float isq = 0.35355339059327373f;   // 1/sqrt(8)
    float ph_r[4], ph_c[8];
#pragma unroll
    for (int r = 0; r < 4; r++) ph_r[r] = phi[s0 + wave * 16 + quad * 4 + r];
#pragma unroll
    for (int j = 0; j < 8; j++) ph_c[j] = phi[j * 16 + lr];

#pragma unroll
    for (int r = 0; r < 4; r++) {
        float vv[8];
        float mx = -1e30f;
#pragma unroll
        for (int j = 0; j < 8; j++) {
            float re = accre[j][r];
            vv[j] = re * re * isq + __cosf(ph_c[j] - ph_r[r]);
            mx = fmaxf(mx, vv[j]);
        }
#pragma unroll
        for (int off = 1; off <= 8; off <<= 1) mx = fmaxf(mx, __shfl_xor(mx, off, 64));
        float sm = 0.f;
#pragma unroll
        for (int j = 0; j < 8; j++) { vv[j] = __expf(vv[j] - mx); sm += vv[j]; }
#pragma unroll
        for (int off = 1; off <= 8; off <<= 1) sm += __shfl_xor(sm, off, 64);
        float inv = 1.f / sm;
        int srow = b * 128 + s0 + wave * 16 + quad * 4 + r;
#pragma unroll
        for (int j = 0; j < 8; j++) {
            float o = vv[j] * inv;
            attn[(size_t)srow * 128 + j * 16 + lr] = o;
            attn_bf[(size_t)srow * 128 + j * 16 + lr] = f2bf(o);
        }
    }
}

// ---------------------------------------------------------------------------
extern "C" void kernel_launch(void* const* d_in, const int* in_sizes, int n_in,
                              void* d_out, int out_size, void* d_ws, size_t ws_size,
                              hipStream_t stream) {
    const float* X     = (const float*)d_in[0];
    const float* Wi    = (const float*)d_in[1];
    const float* bi    = (const float*)d_in[2];
    const float* Wv    = (const float*)d_in[3];
    const float* bv    = (const float*)d_in[4];
    const float* Wo    = (const float*)d_in[5];
    const float* bo    = (const float*)d_in[6];
    const float* phi   = (const float*)d_in[8];

    float* y    = (float*)d_out;
    float* attn = y + (size_t)MM * EE;

    bf16s* Xb   = (bf16s*)d_ws;                      // 16384*1024
    bf16s* Vwt  = Xb  + (size_t)MM * EE;             // [1024 e][16384 g] (X@WvWo)^T
    bf16s* v    = Vwt + (size_t)MM * EE;             // 16384*256 product states
    bf16s* abf  = v   + (size_t)MM * DD;             // 128*128*128
    bf16s* Wvb  = abf + (size_t)BB * SS * SS;        // 1024*1024 bf16(Wv)
    bf16s* Wot  = Wvb + (size_t)EE * EE;             // 1024*1024 Wo^T
    bf16s* Wvot = Wot + (size_t)EE * EE;             // 1024*1024 (Wv@Wo)^T
    float* Wit  = (float*)(Wvot + (size_t)EE * EE);  // 8*1024 fp32
    float* bvo  = Wit + 8 * 1024;                    // 1024 fp32
    float* bvop = bvo + 1024;                        // 16*1024 fp32 partials

    wtrans_kernel<<<32, 256, 0, stream>>>(Wi, Wit);
    encode_kernel<<<MM / 16, 256, 0, stream>>>(X, Wit, bi, Xb, v);
    transpose_conv_kernel<<<dim3(32, 32), 256, 0, stream>>>(Wo, Wot, EE, EE);
    cvt_kernel<<<1024, 256, 0, stream>>>(Wv, Wvb);
    bvo_part_kernel<<<256, 256, 0, stream>>>(bv, Wo, bvop);
    bvo_reduce_kernel<<<4, 256, 0, stream>>>(bvop, bo, bvo);
    // Wvot[a][b] = (Wv@Wo)[b][a] :  A=Wot, Bt=Wvb  (M=N=K=1024)
    mfma_gemm<true><<<64, 256, 0, stream>>>(
        Wot, Wvb, nullptr, Wvot, EE, EE, EE, EE, /*nm*/8, /*nn*/8, 0, 0, 0);
    // attn: real Gram of v + phase term + softmax (unitary cancels)
    attn_kernel<<<dim3(2, BB), 256, 0, stream>>>(v, phi, attn, abf);
    // Vwt[e][g] = Wvot[e][:] . Xb[g][:]  — 256^2-tile counted-vmcnt GEMM
    gemm256_kernel<<<256, 512, 128 * 1024, stream>>>(
        Wvot, Xb, Vwt, EE, MM, EE, /*nm*/4, /*nn*/64);
    // y_b = attn_b @ Vw_b + bvo   (B from merged Vwt: ldB=16384, batch off 128)
    mfma_gemm<false><<<1024, 256, 0, stream>>>(
        abf, Vwt, bvo, y, SS, EE, SS, MM, /*nm*/1, /*nn*/8,
        (long long)SS * SS, (long long)SS, (long long)SS * EE);
}

// Round 13
// 246.298 us; speedup vs baseline: 1.5571x; 1.0087x over previous
//
#include <hip/hip_runtime.h>
#include <hip/hip_bf16.h>

#define BB 128
#define SS 128
#define EE 1024
#define NQ 8
#define DD 256
#define LL 4
#define MM (BB*SS)

typedef unsigned short bf16s;
typedef __attribute__((ext_vector_type(8))) short bf16x8;
typedef __attribute__((ext_vector_type(4))) float f32x4;

#define AS1 __attribute__((address_space(1)))
#define AS3 __attribute__((address_space(3)))

__device__ __forceinline__ unsigned short f2bf(float x) {
    unsigned u = __float_as_uint(x);
    u += 0x7fffu + ((u >> 16) & 1u);
    return (unsigned short)(u >> 16);
}

// pipeline helpers: counted vmcnt (T4) + raw barrier, sched fences (#18)
#define PIPE_WAIT(N) do { \
    asm volatile("s_waitcnt vmcnt(" #N ")" ::: "memory"); \
    __builtin_amdgcn_sched_barrier(0); \
    __builtin_amdgcn_s_barrier(); \
    __builtin_amdgcn_sched_barrier(0); } while (0)
#define PIPE_BAR() do { \
    __builtin_amdgcn_sched_barrier(0); \
    __builtin_amdgcn_s_barrier(); } while (0)

// ---------------------------------------------------------------------------
// fp32 RxC -> bf16 CxR transpose-convert (weights)
// ---------------------------------------------------------------------------
__global__ __launch_bounds__(256) void transpose_conv_kernel(
    const float* __restrict__ in, bf16s* __restrict__ out, int R, int C)
{
    __shared__ float t[32][33];
    int bx = blockIdx.x * 32, by = blockIdx.y * 32;
    int lx = threadIdx.x & 31, ly = threadIdx.x >> 5;
#pragma unroll
    for (int i = 0; i < 32; i += 8)
        t[ly + i][lx] = in[(size_t)(by + ly + i) * C + bx + lx];
    __syncthreads();
#pragma unroll
    for (int i = 0; i < 32; i += 8)
        out[(size_t)(bx + ly + i) * R + by + lx] = f2bf(t[lx][ly + i]);
}

// ---------------------------------------------------------------------------
// fp32 -> bf16 straight convert (Wv), float4 vectorized
// ---------------------------------------------------------------------------
__global__ __launch_bounds__(256) void cvt_kernel(
    const float* __restrict__ in, bf16s* __restrict__ out)
{
    int g = blockIdx.x * 256 + threadIdx.x;      // float4 index
    f32x4 x = ((const f32x4*)in)[g];
    ushort4 o;
    o.x = f2bf(x[0]); o.y = f2bf(x[1]); o.z = f2bf(x[2]); o.w = f2bf(x[3]);
    ((ushort4*)out)[g] = o;
}

// ---------------------------------------------------------------------------
// bvo = bv@Wo + bo, two parallel stages.
// ---------------------------------------------------------------------------
__global__ __launch_bounds__(256) void bvo_part_kernel(
    const float* __restrict__ bv, const float* __restrict__ Wo,
    float* __restrict__ part)
{
    __shared__ float red[4][64];
    int lane = threadIdx.x & 63, w = threadIdx.x >> 6;
    int eb = blockIdx.x & 15, kb = blockIdx.x >> 4;
    int e = eb * 64 + lane;
    int k0 = kb * 64 + w * 16;
    float acc = 0.f;
#pragma unroll
    for (int i = 0; i < 16; i++)
        acc += bv[k0 + i] * Wo[(size_t)(k0 + i) * EE + e];
    red[w][lane] = acc;
    __syncthreads();
    if (w == 0)
        part[kb * EE + e] = red[0][lane] + red[1][lane] + red[2][lane] + red[3][lane];
}

__global__ __launch_bounds__(256) void bvo_reduce_kernel(
    const float* __restrict__ part, const float* __restrict__ bo,
    float* __restrict__ bvo)
{
    int e = blockIdx.x * 256 + threadIdx.x;
    float s = bo[e];
#pragma unroll
    for (int kb = 0; kb < 16; kb++) s += part[kb * EE + e];
    bvo[e] = s;
}

// ---------------------------------------------------------------------------
// Wi[1024][8] -> Wit[8][1024] fp32
// ---------------------------------------------------------------------------
__global__ __launch_bounds__(256) void wtrans_kernel(
    const float* __restrict__ Wi, float* __restrict__ Wit)
{
    int g = blockIdx.x * 256 + threadIdx.x;   // 0..8191
    int k = g >> 3, j = g & 7;
    Wit[j * 1024 + k] = Wi[g];
}

// ---------------------------------------------------------------------------
// encode v3: the lane->k map (k4 = t*64+lane) is row-invariant, so each
// lane's 128 W floats are hoisted into VGPRs ONCE per wave. Row loop has
// only 9 VMEM instrs (4 X loads, 4 Xb stores, 1 v store), zero table reads.
// 4 rows/wave, manual 1-row-ahead X prefetch overlaps the serial tail.
// ---------------------------------------------------------------------------
__global__ __launch_bounds__(256) void encode_kernel(
    const float* __restrict__ X, const float* __restrict__ Wit,
    const float* __restrict__ bi,
    bf16s* __restrict__ Xb, bf16s* __restrict__ v)
{
    const int lane = threadIdx.x & 63;
    const int wid  = threadIdx.x >> 6;
    const int row0 = blockIdx.x * 16 + wid * 4;

    // per-lane W slice: wreg[j][t] = Wit[j][(t*64+lane)*4 ..]
    f32x4 wreg[8][4];
#pragma unroll
    for (int j = 0; j < 8; j++)
#pragma unroll
        for (int t = 0; t < 4; t++)
            wreg[j][t] = ((const f32x4*)(Wit + j * 1024))[t * 64 + lane];

    float bis[8];
#pragma unroll
    for (int j = 0; j < 8; j++) bis[j] = bi[j];

    f32x4 xa0, xa1, xa2, xa3, xn0, xn1, xn2, xn3;
    {
        const f32x4* xr = (const f32x4*)(X + (size_t)row0 * EE);
        xa0 = xr[0 * 64 + lane]; xa1 = xr[1 * 64 + lane];
        xa2 = xr[2 * 64 + lane]; xa3 = xr[3 * 64 + lane];
    }

#pragma unroll
    for (int rr = 0; rr < 4; rr++) {
        const int row = row0 + rr;
        if (rr < 3) {
            const f32x4* xn = (const f32x4*)(X + (size_t)(row + 1) * EE);
            xn0 = xn[0 * 64 + lane]; xn1 = xn[1 * 64 + lane];
            xn2 = xn[2 * 64 + lane]; xn3 = xn[3 * 64 + lane];
        }

        ushort4* xbr4 = (ushort4*)(Xb + (size_t)row * EE);
        float acc[8];
#pragma unroll
        for (int j = 0; j < 8; j++) acc[j] = 0.f;

        f32x4 xs[4] = {xa0, xa1, xa2, xa3};
#pragma unroll
        for (int t = 0; t < 4; t++) {
            f32x4 x = xs[t];
            ushort4 xb;
            xb.x = f2bf(x[0]); xb.y = f2bf(x[1]);
            xb.z = f2bf(x[2]); xb.w = f2bf(x[3]);
            xbr4[t * 64 + lane] = xb;
#pragma unroll
            for (int j = 0; j < 8; j++) {
                f32x4 w = wreg[j][t];
                acc[j] += x[0]*w[0] + x[1]*w[1] + x[2]*w[2] + x[3]*w[3];
            }
        }

        float qin[8];
#pragma unroll
        for (int j = 0; j < 8; j++) {
            float s = acc[j];
#pragma unroll
            for (int off = 32; off >= 1; off >>= 1) s += __shfl_xor(s, off, 64);
            qin[j] = s + bis[j];
        }

        float cs[8], sn[8];
#pragma unroll
        for (int q = 0; q < 8; q++) __sincosf(0.5f * qin[q], &sn[q], &cs[q]);

        float common = 1.f;
#pragma unroll
        for (int b = 2; b < 8; b++) {
            int q = 7 - b;
            common *= ((lane >> (b - 2)) & 1) ? sn[q] : cs[q];
        }
        float a0 = common * cs[6] * cs[7];
        float a1 = common * cs[6] * sn[7];
        float a2 = common * sn[6] * cs[7];
        float a3 = common * sn[6] * sn[7];
        ushort4 vo;
        vo.x = f2bf(a0); vo.y = f2bf(a1); vo.z = f2bf(a2); vo.w = f2bf(a3);
        ((ushort4*)(v + (size_t)row * DD))[lane] = vo;

        xa0 = xn0; xa1 = xn1; xa2 = xn2; xa3 = xn3;
    }
}

// ---------------------------------------------------------------------------
// gemm256: C[M][N] = A[M][K] @ Bt[N][K]^T, bf16 out. 256x256 tile, 512 thr
// (8 waves 2Mx4N, wave tile 128x64), BK=32, 4 LDS K-slots (128 KB dynamic),
// ONE barrier + counted vmcnt(4) per K-tile, prefetch distance 2.
// T2 swizzle via pre-swizzled global source (rule #21).
// Work order: m FASTEST (w = n_t*nm + m_t) so the nm blocks sharing one
// B-panel are consecutive -> same XCD chunk -> B fetched once per XCD L2
// (the R2 lesson: n-fastest spread B-sharers across XCDs = 4x HBM fetch).
// ---------------------------------------------------------------------------
__global__ __launch_bounds__(512) void gemm256_kernel(
    const bf16s* __restrict__ A, const bf16s* __restrict__ Bt,
    bf16s* __restrict__ C, int M, int N, int K, int nm, int nn)
{
    extern __shared__ bf16s lds[];
    bf16s* As = lds;               // 4 slots x 8192 el (256 rows x 32 k)
    bf16s* Bs = lds + 4 * 8192;    // 4 slots x 8192 el

    const int tid  = threadIdx.x;
    const int lane = tid & 63;
    const int wid  = tid >> 6;
    const int quad = lane >> 4, lr = lane & 15;
    const int wr = wid >> 2, wc = wid & 3;   // 2x4 wave grid

    const int nwg = gridDim.x;
    const int q = nwg >> 3, r = nwg & 7;
    const int xcd = blockIdx.x & 7, idx = blockIdx.x >> 3;
    const int w = (xcd < r ? xcd * (q + 1) : r * (q + 1) + (xcd - r) * q) + idx;
    const int m_t = w % nm, n_t = w / nm;    // m fastest (B-panel L2 reuse)
    const int m0 = m_t * 256, n0 = n_t * 256;

    f32x4 acc[8][4];
#pragma unroll
    for (int i = 0; i < 8; i++)
#pragma unroll
        for (int j = 0; j < 4; j++) acc[i][j] = (f32x4){0.f, 0.f, 0.f, 0.f};

    auto stage = [&](int slot, int kt) {
#pragma unroll
        for (int l = 0; l < 2; l++) {
            int ch = l * 512 + tid;                       // 16B chunk id
            int row = ch >> 2;
            int kc = ((ch & 3) ^ (row & 3)) * 8;          // inverse-swizzled src
            __builtin_amdgcn_global_load_lds(
                (AS1 const void*)(A + (size_t)(m0 + row) * K + kt * 32 + kc),
                (AS3 void*)(As + slot * 8192 + ch * 8), 16, 0, 0);
        }
#pragma unroll
        for (int l = 0; l < 2; l++) {
            int ch = l * 512 + tid;
            int row = ch >> 2;
            int kc = ((ch & 3) ^ (row & 3)) * 8;
            __builtin_amdgcn_global_load_lds(
                (AS1 const void*)(Bt + (size_t)(n0 + row) * K + kt * 32 + kc),
                (AS3 void*)(Bs + slot * 8192 + ch * 8), 16, 0, 0);
        }
    };
    auto compute = [&](int slot) {
        bf16x8 af[8];
#pragma unroll
        for (int i = 0; i < 8; i++) {
            int rowl = wr * 128 + i * 16 + lr;
            af[i] = *(const bf16x8*)(As + slot * 8192 + rowl * 32
                                     + ((quad ^ (rowl & 3)) * 8));
        }
#pragma unroll
        for (int j = 0; j < 4; j++) {
            int rowl = wc * 64 + j * 16 + lr;
            bf16x8 bfr = *(const bf16x8*)(Bs + slot * 8192 + rowl * 32
                                          + ((quad ^ (rowl & 3)) * 8));
#pragma unroll
            for (int i = 0; i < 8; i++)
                acc[i][j] = __builtin_amdgcn_mfma_f32_16x16x32_bf16(
                    af[i], bfr, acc[i][j], 0, 0, 0);
        }
    };

    const int NT = K >> 5;   // 32
    stage(0, 0);
    stage(1, 1);
    for (int kt = 0; kt < NT; kt++) {
        if (kt + 1 < NT) PIPE_WAIT(4);
        else             PIPE_WAIT(0);
        if (kt + 2 < NT) stage((kt + 2) & 3, kt + 2);
        compute(kt & 3);
    }

#pragma unroll
    for (int i = 0; i < 8; i++) {
        int row0 = m0 + wr * 128 + i * 16 + quad * 4;
#pragma unroll
        for (int j = 0; j < 4; j++) {
            int col = n0 + wc * 64 + j * 16 + lr;
#pragma unroll
            for (int rr = 0; rr < 4; rr++)
                C[(size_t)(row0 + rr) * N + col] = f2bf(acc[i][j][rr]);
        }
    }
}

// ---------------------------------------------------------------------------
// MFMA bf16 GEMM: depth-2 (3-buffer) pipeline; bijective XCD chunking.
// Work order: w = (z * nm + m) * nn + n.  B row-stride = ldB.
// ---------------------------------------------------------------------------
template<bool OUT_BF16>
__global__ __launch_bounds__(256) void mfma_gemm(
    const bf16s* __restrict__ A, const bf16s* __restrict__ Bt,
    const float* __restrict__ bias, void* __restrict__ Cv,
    int M, int N, int K, int ldB, int nm, int nn,
    long long sA, long long sB, long long sC)
{
    __shared__ bf16s As[3][128 * 32];
    __shared__ bf16s Bs[3][128 * 32];

    const int tid  = threadIdx.x;
    const int wave = tid >> 6, lane = tid & 63;
    const int quad = lane >> 4, lr = lane & 15;
    const int wm = (wave >> 1) * 64, wn = (wave & 1) * 64;

    const int nwg = gridDim.x;
    const int q = nwg >> 3, r = nwg & 7;
    const int xcd = blockIdx.x & 7, idx = blockIdx.x >> 3;
    const int w = (xcd < r ? xcd * (q + 1) : r * (q + 1) + (xcd - r) * q) + idx;
    const int n_t = w % nn;
    const int m_t = (w / nn) % nm;
    const int z   = w / (nn * nm);
    const int m0 = m_t * 128, n0 = n_t * 128;

    A  += (size_t)z * sA;
    Bt += (size_t)z * sB;

    f32x4 acc[4][4];
#pragma unroll
    for (int i = 0; i < 4; i++)
#pragma unroll
        for (int j = 0; j < 4; j++) acc[i][j] = (f32x4){0.f, 0.f, 0.f, 0.f};

    auto stage = [&](int buf, int kt) {
#pragma unroll
        for (int j = 0; j < 2; j++) {
            int ch = j * 256 + tid;
            int row = ch >> 2, kc = (ch & 3) * 8;
            __builtin_amdgcn_global_load_lds(
                (AS1 const void*)(A + (size_t)(m0 + row) * K + kt + kc),
                (AS3 void*)(As[buf] + (size_t)(j * 256 + wave * 64) * 8), 16, 0, 0);
            __builtin_amdgcn_global_load_lds(
                (AS1 const void*)(Bt + (size_t)(n0 + row) * ldB + kt + kc),
                (AS3 void*)(Bs[buf] + (size_t)(j * 256 + wave * 64) * 8), 16, 0, 0);
        }
    };
    auto compute = [&](int buf) {
        bf16x8 af[4], bfr[4];
#pragma unroll
        for (int i = 0; i < 4; i++)
            af[i] = *(const bf16x8*)(As[buf] + (wm + i * 16 + lr) * 32 + quad * 8);
#pragma unroll
        for (int j = 0; j < 4; j++)
            bfr[j] = *(const bf16x8*)(Bs[buf] + (wn + j * 16 + lr) * 32 + quad * 8);
#pragma unroll
        for (int i = 0; i < 4; i++)
#pragma unroll
            for (int j = 0; j < 4; j++)
                acc[i][j] = __builtin_amdgcn_mfma_f32_16x16x32_bf16(
                    af[i], bfr[j], acc[i][j], 0, 0, 0);
    };

    const int nt = K >> 5;
    stage(0, 0);
    stage(1, 1 << 5);
    int cur = 0, nxt = 2;
    for (int t = 0; t < nt; t++) {
        if (t + 2 < nt) { stage(nxt, (t + 2) << 5); PIPE_WAIT(8); }
        else if (t + 1 < nt) PIPE_WAIT(4);
        else PIPE_WAIT(0);
        compute(cur);
        PIPE_BAR();
        cur = (cur == 2) ? 0 : cur + 1;
        nxt = (nxt == 2) ? 0 : nxt + 1;
    }

    float* Cf = (float*)Cv + (size_t)z * sC;
    bf16s* Cb = (bf16s*)Cv + (size_t)z * sC;
#pragma unroll
    for (int i = 0; i < 4; i++) {
        int row0 = m0 + wm + i * 16 + quad * 4;
#pragma unroll
        for (int j = 0; j < 4; j++) {
            int col = n0 + wn + j * 16 + lr;
            float bb = bias ? bias[col] : 0.f;
#pragma unroll
            for (int r = 0; r < 4; r++) {
                float v = acc[i][j][r] + bb;
                if (OUT_BF16) Cb[(size_t)(row0 + r) * N + col] = f2bf(v);
                else          Cf[(size_t)(row0 + r) * N + col] = v;
            }
        }
    }
}

// ---------------------------------------------------------------------------
// attn: G[s,t] = v_s . v_t (real; unitary cancels). K = G^2/sqrt(8) +
// cos(phi_t-phi_s); fused softmax. Depth-2 pipeline over v (K=256).
// ---------------------------------------------------------------------------
__global__ __launch_bounds__(256) void attn_kernel(
    const bf16s* __restrict__ v, const float* __restrict__ phi,
    float* __restrict__ attn, bf16s* __restrict__ attn_bf)
{
    __shared__ bf16s Bs[3][128 * 32];

    const int tid  = threadIdx.x;
    const int wave = tid >> 6, lane = tid & 63;
    const int quad = lane >> 4, lr = lane & 15;
    const int b = blockIdx.y;
    const int s0 = blockIdx.x * 64;
    const bf16s* vb = v + (size_t)b * 128 * DD;

    f32x4 accre[8];
#pragma unroll
    for (int j = 0; j < 8; j++) accre[j] = (f32x4){0.f, 0.f, 0.f, 0.f};

    auto stage = [&](int buf, int kt) {
#pragma unroll
        for (int j = 0; j < 2; j++) {
            int ch = j * 256 + tid;
            int row = ch >> 2, kc = (ch & 3) * 8;
            __builtin_amdgcn_global_load_lds(
                (AS1 const void*)(vb + (size_t)row * DD + kt + kc),
                (AS3 void*)(Bs[buf] + (size_t)(j * 256 + wave * 64) * 8), 16, 0, 0);
        }
    };
    auto compute = [&](int buf) {
        bf16x8 afr = *(const bf16x8*)(Bs[buf] + (s0 + wave * 16 + lr) * 32 + quad * 8);
#pragma unroll
        for (int j = 0; j < 8; j++) {
            bf16x8 b1 = *(const bf16x8*)(Bs[buf] + (j * 16 + lr) * 32 + quad * 8);
            accre[j] = __builtin_amdgcn_mfma_f32_16x16x32_bf16(afr, b1, accre[j], 0, 0, 0);
        }
    };

    const int nt = DD >> 5;   // 8
    stage(0, 0);
    stage(1, 1 << 5);
    int cur = 0, nxt = 2;
    for (int t = 0; t < nt; t++) {
        if (t + 2 < nt) { stage(nxt, (t + 2) << 5); PIPE_WAIT(4); }
        else if (t + 1 < nt) PIPE_WAIT(2);
        else PIPE_WAIT(0);
        compute(cur);
        PIPE_BAR();
        cur = (cur == 2) ? 0 : cur + 1;
        nxt = (nxt == 2) ? 0 : nxt + 1;
    }

    const float isq = 0.35355339059327373f;   // 1/sqrt(8)
    float ph_r[4], ph_c[8];
#pragma unroll
    for (int r = 0; r < 4; r++) ph_r[r] = phi[s0 + wave * 16 + quad * 4 + r];
#pragma unroll
    for (int j = 0; j < 8; j++) ph_c[j] = phi[j * 16 + lr];

#pragma unroll
    for (int r = 0; r < 4; r++) {
        float vv[8];
        float mx = -1e30f;
#pragma unroll
        for (int j = 0; j < 8; j++) {
            float re = accre[j][r];
            vv[j] = re * re * isq + __cosf(ph_c[j] - ph_r[r]);
            mx = fmaxf(mx, vv[j]);
        }
#pragma unroll
        for (int off = 1; off <= 8; off <<= 1) mx = fmaxf(mx, __shfl_xor(mx, off, 64));
        float sm = 0.f;
#pragma unroll
        for (int j = 0; j < 8; j++) { vv[j] = __expf(vv[j] - mx); sm += vv[j]; }
#pragma unroll
        for (int off = 1; off <= 8; off <<= 1) sm += __shfl_xor(sm, off, 64);
        float inv = 1.f / sm;
        int srow = b * 128 + s0 + wave * 16 + quad * 4 + r;
#pragma unroll
        for (int j = 0; j < 8; j++) {
            float o = vv[j] * inv;
            attn[(size_t)srow * 128 + j * 16 + lr] = o;
            attn_bf[(size_t)srow * 128 + j * 16 + lr] = f2bf(o);
        }
    }
}

// ---------------------------------------------------------------------------
extern "C" void kernel_launch(void* const* d_in, const int* in_sizes, int n_in,
                              void* d_out, int out_size, void* d_ws, size_t ws_size,
                              hipStream_t stream) {
    const float* X     = (const float*)d_in[0];
    const float* Wi    = (const float*)d_in[1];
    const float* bi    = (const float*)d_in[2];
    const float* Wv    = (const float*)d_in[3];
    const float* bv    = (const float*)d_in[4];
    const float* Wo    = (const float*)d_in[5];
    const float* bo    = (const float*)d_in[6];
    const float* phi   = (const float*)d_in[8];

    float* y    = (float*)d_out;
    float* attn = y + (size_t)MM * EE;

    bf16s* Xb   = (bf16s*)d_ws;                      // 16384*1024
    bf16s* Vwt  = Xb  + (size_t)MM * EE;             // [1024 e][16384 g] (X@WvWo)^T
    bf16s* v    = Vwt + (size_t)MM * EE;             // 16384*256 product states
    bf16s* abf  = v   + (size_t)MM * DD;             // 128*128*128
    bf16s* Wvb  = abf + (size_t)BB * SS * SS;        // 1024*1024 bf16(Wv)
    bf16s* Wot  = Wvb + (size_t)EE * EE;             // 1024*1024 Wo^T
    bf16s* Wvot = Wot + (size_t)EE * EE;             // 1024*1024 (Wv@Wo)^T
    float* Wit  = (float*)(Wvot + (size_t)EE * EE);  // 8*1024 fp32
    float* bvo  = Wit + 8 * 1024;                    // 1024 fp32
    float* bvop = bvo + 1024;                        // 16*1024 fp32 partials

    wtrans_kernel<<<32, 256, 0, stream>>>(Wi, Wit);
    encode_kernel<<<MM / 16, 256, 0, stream>>>(X, Wit, bi, Xb, v);
    transpose_conv_kernel<<<dim3(32, 32), 256, 0, stream>>>(Wo, Wot, EE, EE);
    cvt_kernel<<<1024, 256, 0, stream>>>(Wv, Wvb);
    bvo_part_kernel<<<256, 256, 0, stream>>>(bv, Wo, bvop);
    bvo_reduce_kernel<<<4, 256, 0, stream>>>(bvop, bo, bvo);
    // Wvot[a][b] = (Wv@Wo)[b][a] :  A=Wot, Bt=Wvb  (M=N=K=1024)
    mfma_gemm<true><<<64, 256, 0, stream>>>(
        Wot, Wvb, nullptr, Wvot, EE, EE, EE, EE, /*nm*/8, /*nn*/8, 0, 0, 0);
    // attn: real Gram of v + phase term + softmax (unitary cancels)
    attn_kernel<<<dim3(2, BB), 256, 0, stream>>>(v, phi, attn, abf);
    // Vwt[e][g] = Wvot[e][:] . Xb[g][:]  — 256^2-tile counted-vmcnt GEMM
    gemm256_kernel<<<256, 512, 128 * 1024, stream>>>(
        Wvot, Xb, Vwt, EE, MM, EE, /*nm*/4, /*nn*/64);
    // y_b = attn_b @ Vw_b + bvo   (B from merged Vwt: ldB=16384, batch off 128)
    mfma_gemm<false><<<1024, 256, 0, stream>>>(
        abf, Vwt, bvo, y, SS, EE, SS, MM, /*nm*/1, /*nn*/8,
        (long long)SS * SS, (long long)SS, (long long)SS * EE);
}